// Round 7
// baseline (957.380 us; speedup 1.0000x reference)
//
#include <hip/hip_runtime.h>
#include <hip/hip_fp16.h>
#include <math.h>

#define HID 128
#define EPS 1e-5f
#define BK 64          // dst nodes per bucket
#define MAXNBK 2048    // supports n <= 131072

// ---------------- bucketed graph preprocessing ----------------
// btmp entry: (src << 6) | (dst & 63)  -- src < 2^26 required (n=1e5 ok)

__global__ __launch_bounds__(256) void k_bhist(const int* __restrict__ dst, int* __restrict__ bcount,
                                               int e, int nbk) {
    __shared__ int hist[MAXNBK];
    for (int i = threadIdx.x; i < nbk; i += 256) hist[i] = 0;
    __syncthreads();
    int base = blockIdx.x * 4096;
    int end = min(base + 4096, e);
    for (int i = base + threadIdx.x; i < end; i += 256) atomicAdd(&hist[dst[i] >> 6], 1);
    __syncthreads();
    for (int i = threadIdx.x; i < nbk; i += 256) {
        int c = hist[i];
        if (c) atomicAdd(&bcount[i * 16], c);
    }
}

__global__ __launch_bounds__(1024) void k_bscan(const int* __restrict__ bcount, int* __restrict__ boffs,
                                                int* __restrict__ bcur, int nbk, int e) {
    __shared__ int lds[1024];
    int tid = threadIdx.x;
    int i0 = 2 * tid, i1 = 2 * tid + 1;
    int a = (i0 < nbk) ? bcount[i0 * 16] : 0;
    int b = (i1 < nbk) ? bcount[i1 * 16] : 0;
    lds[tid] = a + b;
    __syncthreads();
    for (int off = 1; off < 1024; off <<= 1) {
        int v = (tid >= off) ? lds[tid - off] : 0;
        __syncthreads();
        lds[tid] += v;
        __syncthreads();
    }
    int excl = lds[tid] - (a + b);
    if (i0 < nbk) { boffs[i0] = excl;     bcur[i0 * 16] = excl; }
    if (i1 < nbk) { boffs[i1] = excl + a; bcur[i1 * 16] = excl + a; }
    if (tid == 1023) boffs[nbk] = e;
}

__global__ __launch_bounds__(1024) void k_bscatter(const int* __restrict__ src, const int* __restrict__ dst,
                                                   int* __restrict__ bcur, int* __restrict__ btmp,
                                                   int e, int nbk) {
    __shared__ int hist[MAXNBK];
    int tid = threadIdx.x;
    for (int i = tid; i < nbk; i += 1024) hist[i] = 0;
    __syncthreads();
    int per = (e + gridDim.x - 1) / gridDim.x;
    int base = blockIdx.x * per;
    int end = min(base + per, e);
    for (int i = base + tid; i < end; i += 1024) atomicAdd(&hist[dst[i] >> 6], 1);
    __syncthreads();
    for (int i = tid; i < nbk; i += 1024) {
        int c = hist[i];
        hist[i] = c ? atomicAdd(&bcur[i * 16], c) : 0;
    }
    __syncthreads();
    for (int i = base + tid; i < end; i += 1024) {
        int d = dst[i];
        int pos = atomicAdd(&hist[d >> 6], 1);          // LDS int atomic (native)
        btmp[pos] = (src[i] << 6) | (d & 63);
    }
}

// per-bucket counting sort: btmp -> csr (dst-sorted src ids) + offs + dinv (int LDS atomics only)
__global__ __launch_bounds__(256) void k_bsort(const int* __restrict__ btmp, const int* __restrict__ boffs,
                                               int* __restrict__ csr, int* __restrict__ offs,
                                               float* __restrict__ dinv, int n, int etot) {
    __shared__ int cnt[BK];
    __shared__ int cur[BK];
    int b = blockIdx.x, tid = threadIdx.x;
    if (tid < BK) cnt[tid] = 0;
    __syncthreads();
    int e0 = boffs[b], e1 = boffs[b + 1];
    for (int i = e0 + tid; i < e1; i += 256) atomicAdd(&cnt[btmp[i] & 63], 1);
    __syncthreads();
    if (tid == 0) {
        int run = 0;
        for (int d = 0; d < BK; ++d) { cur[d] = run; run += cnt[d]; }
    }
    __syncthreads();
    if (tid < BK) {
        int node = b * BK + tid;
        if (node < n) {
            offs[node] = e0 + cur[tid];
            dinv[node] = rsqrtf((float)(cnt[tid] + 1));  // +1 self-loop
        }
    }
    if (b == 0 && tid == 0) offs[n] = etot;
    __syncthreads();
    for (int i = e0 + tid; i < e1; i += 256) {
        int p = btmp[i];
        int pos = e0 + atomicAdd(&cur[p & 63], 1);
        csr[pos] = p >> 6;
    }
}

// ---------------- embed: h = relu(x @ We + be), x is [N,2] ----------------

__global__ void k_embed(const float* __restrict__ x, const float* __restrict__ We,
                        const float* __restrict__ be, float* __restrict__ h, int n) {
    int i = blockIdx.x * 256 + threadIdx.x;
    if (i >= n * HID) return;
    int node = i >> 7, j = i & 127;
    float v = x[2 * node] * We[j] + x[2 * node + 1] * We[HID + j] + be[j];
    h[i] = fmaxf(v, 0.f);
}

// ---------------- GEMM (plain, layer 1): th = fp16(dinv * (h @ W)) ----------

__global__ __launch_bounds__(256) void k_gemm128(const float* __restrict__ h, const float* __restrict__ W,
                                                 const float* __restrict__ dinv,
                                                 __half2* __restrict__ th, int n) {
    __shared__ float hs[128][66];
    __shared__ float ws[128][64];
    int tid = threadIdx.x;
    int nb = blockIdx.x * 64;
    const float4* h4 = (const float4*)h;
#pragma unroll
    for (int r = 0; r < 8; ++r) {
        int idx = r * 256 + tid;
        int ni = idx >> 5;
        int k4 = idx & 31;
        int node = nb + ni;
        float4 v = make_float4(0.f, 0.f, 0.f, 0.f);
        if (node < n) v = h4[(size_t)node * 32 + k4];
        hs[k4 * 4 + 0][ni] = v.x; hs[k4 * 4 + 1][ni] = v.y;
        hs[k4 * 4 + 2][ni] = v.z; hs[k4 * 4 + 3][ni] = v.w;
    }
    int fg = tid & 15, ng = tid >> 4;
    const float4* w4 = (const float4*)W;
    for (int c = 0; c < 2; ++c) {
        if (c) __syncthreads();
#pragma unroll
        for (int r = 0; r < 8; ++r) {
            int idx = r * 256 + tid;
            int k = idx >> 4, f4 = idx & 15;
            *((float4*)&ws[k][f4 * 4]) = w4[k * 32 + c * 16 + f4];
        }
        __syncthreads();
        float acc[4][4] = {{0.f}};
#pragma unroll 8
        for (int k = 0; k < 128; ++k) {
            float2 a0 = *((const float2*)&hs[k][ng * 4]);
            float2 a1 = *((const float2*)&hs[k][ng * 4 + 2]);
            float4 w = *((const float4*)&ws[k][fg * 4]);
            float av[4] = {a0.x, a0.y, a1.x, a1.y};
            float wv[4] = {w.x, w.y, w.z, w.w};
#pragma unroll
            for (int i = 0; i < 4; ++i)
#pragma unroll
                for (int j = 0; j < 4; ++j)
                    acc[i][j] += av[i] * wv[j];
        }
#pragma unroll
        for (int i = 0; i < 4; ++i) {
            int node = nb + ng * 4 + i;
            if (node < n) {
                float dv = dinv[node];
                union { __half2 hh[2]; float2 f; } pk;
                pk.hh[0] = __floats2half2_rn(acc[i][0] * dv, acc[i][1] * dv);
                pk.hh[1] = __floats2half2_rn(acc[i][2] * dv, acc[i][3] * dv);
                ((float2*)th)[((size_t)node * 128 + c * 64 + fg * 4) >> 2] = pk.f;
            }
        }
    }
}

// ---------------- GEMM fused with BN-apply+ReLU+residual (layers 2,3) -----------------
// h_new[i] = relu(agg[i]*A + C) + h_old[i]  computed in staging, written in-place to h,
// staged to LDS, then th = fp16(dinv * (h_new @ W)).

__global__ __launch_bounds__(256) void k_gemm128f(const float* __restrict__ agg, float* __restrict__ h,
                                                  const float* __restrict__ A, const float* __restrict__ Cc,
                                                  const float* __restrict__ W, const float* __restrict__ dinv,
                                                  __half2* __restrict__ th, int n) {
    __shared__ float hs[128][66];
    __shared__ float ws[128][64];
    __shared__ float As[128], Cs[128];
    int tid = threadIdx.x;
    int nb = blockIdx.x * 64;
    if (tid < 128) { As[tid] = A[tid]; Cs[tid] = Cc[tid]; }
    __syncthreads();
    const float4* a4p = (const float4*)agg;
    float4* h4 = (float4*)h;
#pragma unroll
    for (int r = 0; r < 8; ++r) {
        int idx = r * 256 + tid;
        int ni = idx >> 5;
        int k4 = idx & 31;
        int node = nb + ni;
        float4 v = make_float4(0.f, 0.f, 0.f, 0.f);
        if (node < n) {
            float4 a = a4p[(size_t)node * 32 + k4];
            float4 ho = h4[(size_t)node * 32 + k4];
            float4 aa = *((const float4*)&As[k4 * 4]);
            float4 cc = *((const float4*)&Cs[k4 * 4]);
            v.x = fmaxf(a.x * aa.x + cc.x, 0.f) + ho.x;
            v.y = fmaxf(a.y * aa.y + cc.y, 0.f) + ho.y;
            v.z = fmaxf(a.z * aa.z + cc.z, 0.f) + ho.z;
            v.w = fmaxf(a.w * aa.w + cc.w, 0.f) + ho.w;
            h4[(size_t)node * 32 + k4] = v;   // in-place: each element owned by one thread
        }
        hs[k4 * 4 + 0][ni] = v.x; hs[k4 * 4 + 1][ni] = v.y;
        hs[k4 * 4 + 2][ni] = v.z; hs[k4 * 4 + 3][ni] = v.w;
    }
    int fg = tid & 15, ng = tid >> 4;
    const float4* w4 = (const float4*)W;
    for (int c = 0; c < 2; ++c) {
        if (c) __syncthreads();
#pragma unroll
        for (int r = 0; r < 8; ++r) {
            int idx = r * 256 + tid;
            int k = idx >> 4, f4 = idx & 15;
            *((float4*)&ws[k][f4 * 4]) = w4[k * 32 + c * 16 + f4];
        }
        __syncthreads();
        float acc[4][4] = {{0.f}};
#pragma unroll 8
        for (int k = 0; k < 128; ++k) {
            float2 a0 = *((const float2*)&hs[k][ng * 4]);
            float2 a1 = *((const float2*)&hs[k][ng * 4 + 2]);
            float4 w = *((const float4*)&ws[k][fg * 4]);
            float av[4] = {a0.x, a0.y, a1.x, a1.y};
            float wv[4] = {w.x, w.y, w.z, w.w};
#pragma unroll
            for (int i = 0; i < 4; ++i)
#pragma unroll
                for (int j = 0; j < 4; ++j)
                    acc[i][j] += av[i] * wv[j];
        }
#pragma unroll
        for (int i = 0; i < 4; ++i) {
            int node = nb + ng * 4 + i;
            if (node < n) {
                float dv = dinv[node];
                union { __half2 hh[2]; float2 f; } pk;
                pk.hh[0] = __floats2half2_rn(acc[i][0] * dv, acc[i][1] * dv);
                pk.hh[1] = __floats2half2_rn(acc[i][2] * dv, acc[i][3] * dv);
                ((float2*)th)[((size_t)node * 128 + c * 64 + fg * 4) >> 2] = pk.f;
            }
        }
    }
}

// ---------------- aggregation + fused BN stats ---------------------------------------
// Grid-stride over 4-node groups, 4096 blocks (occupancy fix: 1024 blocks halved wave TLP).

__global__ __launch_bounds__(256) void k_agg(const __half2* __restrict__ t, const int* __restrict__ offs,
                                             const int* __restrict__ csr, const float* __restrict__ dinv,
                                             const float* __restrict__ bias, float* __restrict__ out,
                                             float* __restrict__ S, float* __restrict__ SS, int n) {
    __shared__ float ls[4][128];
    __shared__ float lss[4][128];
    int tid = threadIdx.x;
    int lane = tid & 63, w = tid >> 6;
    float2 b = ((const float2*)bias)[lane];
    float sx = 0.f, sy = 0.f, qx = 0.f, qy = 0.f;
    int ngrp = (n + 3) >> 2;
    for (int grp = blockIdx.x; grp < ngrp; grp += gridDim.x) {
        int node = grp * 4 + w;
        if (node < n) {
            float2 vf = __half22float2(t[(size_t)node * 64 + lane]);
            float ax = vf.x, ay = vf.y;
            int e0 = offs[node], e1 = offs[node + 1];
            int e = e0;
            for (; e + 8 <= e1; e += 8) {
                int s0 = csr[e + 0], s1 = csr[e + 1], s2 = csr[e + 2], s3 = csr[e + 3];
                int s4 = csr[e + 4], s5 = csr[e + 5], s6 = csr[e + 6], s7 = csr[e + 7];
                float2 u0 = __half22float2(t[(size_t)s0 * 64 + lane]);
                float2 u1 = __half22float2(t[(size_t)s1 * 64 + lane]);
                float2 u2 = __half22float2(t[(size_t)s2 * 64 + lane]);
                float2 u3 = __half22float2(t[(size_t)s3 * 64 + lane]);
                float2 u4 = __half22float2(t[(size_t)s4 * 64 + lane]);
                float2 u5 = __half22float2(t[(size_t)s5 * 64 + lane]);
                float2 u6 = __half22float2(t[(size_t)s6 * 64 + lane]);
                float2 u7 = __half22float2(t[(size_t)s7 * 64 + lane]);
                ax += ((u0.x + u1.x) + (u2.x + u3.x)) + ((u4.x + u5.x) + (u6.x + u7.x));
                ay += ((u0.y + u1.y) + (u2.y + u3.y)) + ((u4.y + u5.y) + (u6.y + u7.y));
            }
            if (e + 4 <= e1) {
                int s0 = csr[e + 0], s1 = csr[e + 1], s2 = csr[e + 2], s3 = csr[e + 3];
                float2 u0 = __half22float2(t[(size_t)s0 * 64 + lane]);
                float2 u1 = __half22float2(t[(size_t)s1 * 64 + lane]);
                float2 u2 = __half22float2(t[(size_t)s2 * 64 + lane]);
                float2 u3 = __half22float2(t[(size_t)s3 * 64 + lane]);
                ax += (u0.x + u1.x) + (u2.x + u3.x);
                ay += (u0.y + u1.y) + (u2.y + u3.y);
                e += 4;
            }
            for (; e < e1; ++e) {
                float2 u = __half22float2(t[(size_t)csr[e] * 64 + lane]);
                ax += u.x; ay += u.y;
            }
            float di = dinv[node];
            float vx = ax * di + b.x, vy = ay * di + b.y;
            ((float2*)out)[(size_t)node * 64 + lane] = make_float2(vx, vy);
            sx += vx; sy += vy; qx += vx * vx; qy += vy * vy;
        }
    }
    ls[w][2 * lane] = sx;  ls[w][2 * lane + 1] = sy;
    lss[w][2 * lane] = qx; lss[w][2 * lane + 1] = qy;
    __syncthreads();
    if (tid < 128) {
        float s = ls[0][tid] + ls[1][tid] + ls[2][tid] + ls[3][tid];
        float q = lss[0][tid] + lss[1][tid] + lss[2][tid] + lss[3][tid];
        atomicAdd(&S[tid], s);
        atomicAdd(&SS[tid], q);
    }
}

// ---------------- BN ----------------

__global__ void k_bn_stats32(const float* __restrict__ v, float* __restrict__ S,
                             float* __restrict__ SS, int n) {
    int j = threadIdx.x & 31, sub = threadIdx.x >> 5;
    int per = (n + gridDim.x - 1) / gridDim.x;
    int start = blockIdx.x * per;
    int end = min(start + per, n);
    float s = 0.f, ss = 0.f;
    for (int i = start + sub; i < end; i += 4) {
        float x = v[(size_t)i * 32 + j];
        s += x; ss += x * x;
    }
    atomicAdd(&S[j], s);
    atomicAdd(&SS[j], ss);
}

__global__ void k_bn_finalize(const float* __restrict__ S, const float* __restrict__ SS,
                              const float* __restrict__ g, const float* __restrict__ bt,
                              float* __restrict__ A, float* __restrict__ C, int n, int hid) {
    int j = threadIdx.x;
    if (j >= hid) return;
    float mu = S[j] / (float)n;
    float var = SS[j] / (float)n - mu * mu;
    float inv = rsqrtf(var + EPS);
    A[j] = g[j] * inv;
    C[j] = bt[j] - mu * g[j] * inv;
}

// ---------------- head GEMM fused with BN-apply+ReLU+residual (reads agg3, h2) -------
// tf = (relu(agg*A+C)+h) @ Wf1 + bf1   (h NOT written back -- h3 dead after this)

__global__ __launch_bounds__(256) void k_gemmff(const float* __restrict__ agg, const float* __restrict__ h,
                                                const float* __restrict__ A, const float* __restrict__ Cc,
                                                const float* __restrict__ W, const float* __restrict__ bias,
                                                float* __restrict__ out, int n) {
    __shared__ float hs[128][66];
    __shared__ float ws[128][32];
    __shared__ float As[128], Cs[128];
    int tid = threadIdx.x;
    int nb = blockIdx.x * 64;
    if (tid < 128) { As[tid] = A[tid]; Cs[tid] = Cc[tid]; }
    __syncthreads();
    const float4* a4p = (const float4*)agg;
    const float4* h4 = (const float4*)h;
#pragma unroll
    for (int r = 0; r < 8; ++r) {
        int idx = r * 256 + tid;
        int ni = idx >> 5, k4 = idx & 31;
        int node = nb + ni;
        float4 v = make_float4(0.f, 0.f, 0.f, 0.f);
        if (node < n) {
            float4 a = a4p[(size_t)node * 32 + k4];
            float4 ho = h4[(size_t)node * 32 + k4];
            float4 aa = *((const float4*)&As[k4 * 4]);
            float4 cc = *((const float4*)&Cs[k4 * 4]);
            v.x = fmaxf(a.x * aa.x + cc.x, 0.f) + ho.x;
            v.y = fmaxf(a.y * aa.y + cc.y, 0.f) + ho.y;
            v.z = fmaxf(a.z * aa.z + cc.z, 0.f) + ho.z;
            v.w = fmaxf(a.w * aa.w + cc.w, 0.f) + ho.w;
        }
        hs[k4 * 4 + 0][ni] = v.x; hs[k4 * 4 + 1][ni] = v.y;
        hs[k4 * 4 + 2][ni] = v.z; hs[k4 * 4 + 3][ni] = v.w;
    }
    const float4* w4 = (const float4*)W;
#pragma unroll
    for (int r = 0; r < 4; ++r) {
        int idx = r * 256 + tid;
        int k = idx >> 3, f4 = idx & 7;
        *((float4*)&ws[k][f4 * 4]) = w4[k * 8 + f4];
    }
    __syncthreads();
    int fg = tid & 7, ng = tid >> 3;
    float acc[2][4] = {{0.f}};
#pragma unroll 8
    for (int k = 0; k < 128; ++k) {
        float2 a = *((const float2*)&hs[k][ng * 2]);
        float4 w = *((const float4*)&ws[k][fg * 4]);
        acc[0][0] += a.x * w.x; acc[0][1] += a.x * w.y; acc[0][2] += a.x * w.z; acc[0][3] += a.x * w.w;
        acc[1][0] += a.y * w.x; acc[1][1] += a.y * w.y; acc[1][2] += a.y * w.z; acc[1][3] += a.y * w.w;
    }
    float4 bb = *((const float4*)&bias[fg * 4]);
#pragma unroll
    for (int i = 0; i < 2; ++i) {
        int node = nb + ng * 2 + i;
        if (node < n)
            *((float4*)&out[(size_t)node * 32 + fg * 4]) =
                make_float4(acc[i][0] + bb.x, acc[i][1] + bb.y, acc[i][2] + bb.z, acc[i][3] + bb.w);
    }
}

// ---------------- final: out = tanh(relu(bn(tf)) @ Wf2 + bf2) ----------------

__global__ void k_final(const float* __restrict__ tf, const float* __restrict__ A,
                        const float* __restrict__ C, const float* __restrict__ Wf2,
                        const float* __restrict__ bf2, float* __restrict__ out, int n) {
    int node = blockIdx.x * 256 + threadIdx.x;
    if (node >= n) return;
    float o0 = bf2[0], o1 = bf2[1];
    const float4* t4 = (const float4*)(tf + (size_t)node * 32);
#pragma unroll
    for (int q = 0; q < 8; ++q) {
        float4 v = t4[q];
        float vv[4] = {v.x, v.y, v.z, v.w};
#pragma unroll
        for (int r = 0; r < 4; ++r) {
            int j = q * 4 + r;
            float f = fmaxf(vv[r] * A[j] + C[j], 0.f);
            o0 += f * Wf2[2 * j];
            o1 += f * Wf2[2 * j + 1];
        }
    }
    out[2 * node] = tanhf(o0);
    out[2 * node + 1] = tanhf(o1);
}

// ---------------- launch ----------------

extern "C" void kernel_launch(void* const* d_in, const int* in_sizes, int n_in,
                              void* d_out, int out_size, void* d_ws, size_t ws_size,
                              hipStream_t stream) {
    const float* x   = (const float*)d_in[0];
    const int*   ei  = (const int*)d_in[1];
    const float* We  = (const float*)d_in[2];
    const float* be  = (const float*)d_in[3];
    const float* W1  = (const float*)d_in[4];
    const float* b1  = (const float*)d_in[5];
    const float* g1  = (const float*)d_in[6];
    const float* bt1 = (const float*)d_in[7];
    const float* W2  = (const float*)d_in[8];
    const float* b2  = (const float*)d_in[9];
    const float* g2  = (const float*)d_in[10];
    const float* bt2 = (const float*)d_in[11];
    const float* W3  = (const float*)d_in[12];
    const float* b3  = (const float*)d_in[13];
    const float* g3  = (const float*)d_in[14];
    const float* bt3 = (const float*)d_in[15];
    const float* Wf1 = (const float*)d_in[16];
    const float* bf1 = (const float*)d_in[17];
    const float* gf  = (const float*)d_in[18];
    const float* btf = (const float*)d_in[19];
    const float* Wf2 = (const float*)d_in[20];
    const float* bf2 = (const float*)d_in[21];
    float* out = (float*)d_out;

    const int n = in_sizes[0] / 2;      // x is [N,2]
    const int e = in_sizes[1] / 2;      // edge_index is [2,E]
    const int* srcp = ei;
    const int* dstp = ei + e;
    const int nbk = (n + BK - 1) / BK;

    char* p = (char*)d_ws;
    auto alloc = [&](size_t bytes) { void* r = (void*)p; p += (bytes + 255) & ~(size_t)255; return r; };
    int*     bcount = (int*)alloc((size_t)nbk * 16 * 4);
    int*     boffs  = (int*)alloc((size_t)(nbk + 1) * 4);
    int*     bcur   = (int*)alloc((size_t)nbk * 16 * 4);
    int*     btmp   = (int*)alloc((size_t)e * 4);
    int*     csr    = (int*)alloc((size_t)e * 4);
    int*     offs   = (int*)alloc((size_t)(n + 1) * 4);
    float*   dinv   = (float*)alloc((size_t)n * 4);
    float*   h      = (float*)alloc((size_t)n * HID * 4);
    __half2* th     = (__half2*)alloc((size_t)n * HID * 2);
    float*   agg    = (float*)alloc((size_t)n * HID * 4);
    float*   tf     = (float*)alloc((size_t)n * 32 * 4);
    float*   bnS    = (float*)alloc(HID * 4);
    float*   bnSS   = (float*)alloc(HID * 4);
    float*   bnA    = (float*)alloc(HID * 4);
    float*   bnC    = (float*)alloc(HID * 4);

    hipMemsetAsync(bcount, 0, (size_t)nbk * 16 * 4, stream);
    k_bhist<<<(e + 4095) / 4096, 256, 0, stream>>>(dstp, bcount, e, nbk);
    k_bscan<<<1, 1024, 0, stream>>>(bcount, boffs, bcur, nbk, e);
    k_bscatter<<<256, 1024, 0, stream>>>(srcp, dstp, bcur, btmp, e, nbk);
    k_bsort<<<nbk, 256, 0, stream>>>(btmp, boffs, csr, offs, dinv, n, e);
    k_embed<<<(n * HID + 255) / 256, 256, 0, stream>>>(x, We, be, h, n);

    // layer 1
    k_gemm128<<<(n + 63) / 64, 256, 0, stream>>>(h, W1, dinv, th, n);
    hipMemsetAsync(bnS, 0, HID * 4, stream);
    hipMemsetAsync(bnSS, 0, HID * 4, stream);
    k_agg<<<4096, 256, 0, stream>>>(th, offs, csr, dinv, b1, agg, bnS, bnSS, n);
    k_bn_finalize<<<1, 128, 0, stream>>>(bnS, bnSS, g1, bt1, bnA, bnC, n, 128);

    // layer 2 (gemm fused with layer-1 bn-apply+relu+residual)
    k_gemm128f<<<(n + 63) / 64, 256, 0, stream>>>(agg, h, bnA, bnC, W2, dinv, th, n);
    hipMemsetAsync(bnS, 0, HID * 4, stream);
    hipMemsetAsync(bnSS, 0, HID * 4, stream);
    k_agg<<<4096, 256, 0, stream>>>(th, offs, csr, dinv, b2, agg, bnS, bnSS, n);
    k_bn_finalize<<<1, 128, 0, stream>>>(bnS, bnSS, g2, bt2, bnA, bnC, n, 128);

    // layer 3
    k_gemm128f<<<(n + 63) / 64, 256, 0, stream>>>(agg, h, bnA, bnC, W3, dinv, th, n);
    hipMemsetAsync(bnS, 0, HID * 4, stream);
    hipMemsetAsync(bnSS, 0, HID * 4, stream);
    k_agg<<<4096, 256, 0, stream>>>(th, offs, csr, dinv, b3, agg, bnS, bnSS, n);
    k_bn_finalize<<<1, 128, 0, stream>>>(bnS, bnSS, g3, bt3, bnA, bnC, n, 128);

    // head (gemm fused with layer-3 bn-apply+relu+residual; h3 never materialized)
    k_gemmff<<<(n + 63) / 64, 256, 0, stream>>>(agg, h, bnA, bnC, Wf1, bf1, tf, n);
    hipMemsetAsync(bnS, 0, 32 * 4, stream);
    hipMemsetAsync(bnSS, 0, 32 * 4, stream);
    k_bn_stats32<<<512, 128, 0, stream>>>(tf, bnS, bnSS, n);
    k_bn_finalize<<<1, 32, 0, stream>>>(bnS, bnSS, gf, btf, bnA, bnC, n, 32);
    k_final<<<(n + 255) / 256, 256, 0, stream>>>(tf, bnA, bnC, Wf2, bf2, out, n);
}

// Round 8
// 756.073 us; speedup vs baseline: 1.2663x; 1.2663x over previous
//
#include <hip/hip_runtime.h>
#include <hip/hip_fp16.h>
#include <math.h>

#define HID 128
#define EPS 1e-5f
#define BK 64          // dst nodes per bucket
#define MAXNBK 2048    // supports n <= 131072
#define NSTRIPE 16     // BN-stats atomic striping (breaks same-address chains)

// ---------------- bucketed graph preprocessing ----------------
// btmp entry: (src << 6) | (dst & 63)  -- src < 2^26 required (n=1e5 ok)

__global__ __launch_bounds__(256) void k_bhist(const int* __restrict__ dst, int* __restrict__ bcount,
                                               int e, int nbk) {
    __shared__ int hist[MAXNBK];
    for (int i = threadIdx.x; i < nbk; i += 256) hist[i] = 0;
    __syncthreads();
    int base = blockIdx.x * 4096;
    int end = min(base + 4096, e);
    for (int i = base + threadIdx.x; i < end; i += 256) atomicAdd(&hist[dst[i] >> 6], 1);
    __syncthreads();
    for (int i = threadIdx.x; i < nbk; i += 256) {
        int c = hist[i];
        if (c) atomicAdd(&bcount[i * 16], c);
    }
}

__global__ __launch_bounds__(1024) void k_bscan(const int* __restrict__ bcount, int* __restrict__ boffs,
                                                int* __restrict__ bcur, int nbk, int e) {
    __shared__ int lds[1024];
    int tid = threadIdx.x;
    int i0 = 2 * tid, i1 = 2 * tid + 1;
    int a = (i0 < nbk) ? bcount[i0 * 16] : 0;
    int b = (i1 < nbk) ? bcount[i1 * 16] : 0;
    lds[tid] = a + b;
    __syncthreads();
    for (int off = 1; off < 1024; off <<= 1) {
        int v = (tid >= off) ? lds[tid - off] : 0;
        __syncthreads();
        lds[tid] += v;
        __syncthreads();
    }
    int excl = lds[tid] - (a + b);
    if (i0 < nbk) { boffs[i0] = excl;     bcur[i0 * 16] = excl; }
    if (i1 < nbk) { boffs[i1] = excl + a; bcur[i1 * 16] = excl + a; }
    if (tid == 1023) boffs[nbk] = e;
}

__global__ __launch_bounds__(1024) void k_bscatter(const int* __restrict__ src, const int* __restrict__ dst,
                                                   int* __restrict__ bcur, int* __restrict__ btmp,
                                                   int e, int nbk) {
    __shared__ int hist[MAXNBK];
    int tid = threadIdx.x;
    for (int i = tid; i < nbk; i += 1024) hist[i] = 0;
    __syncthreads();
    int per = (e + gridDim.x - 1) / gridDim.x;
    int base = blockIdx.x * per;
    int end = min(base + per, e);
    for (int i = base + tid; i < end; i += 1024) atomicAdd(&hist[dst[i] >> 6], 1);
    __syncthreads();
    for (int i = tid; i < nbk; i += 1024) {
        int c = hist[i];
        hist[i] = c ? atomicAdd(&bcur[i * 16], c) : 0;
    }
    __syncthreads();
    for (int i = base + tid; i < end; i += 1024) {
        int d = dst[i];
        int pos = atomicAdd(&hist[d >> 6], 1);          // LDS int atomic (native)
        btmp[pos] = (src[i] << 6) | (d & 63);
    }
}

// per-bucket counting sort: btmp -> csr (dst-sorted src ids) + offs + dinv (int LDS atomics only)
__global__ __launch_bounds__(256) void k_bsort(const int* __restrict__ btmp, const int* __restrict__ boffs,
                                               int* __restrict__ csr, int* __restrict__ offs,
                                               float* __restrict__ dinv, int n, int etot) {
    __shared__ int cnt[BK];
    __shared__ int cur[BK];
    int b = blockIdx.x, tid = threadIdx.x;
    if (tid < BK) cnt[tid] = 0;
    __syncthreads();
    int e0 = boffs[b], e1 = boffs[b + 1];
    for (int i = e0 + tid; i < e1; i += 256) atomicAdd(&cnt[btmp[i] & 63], 1);
    __syncthreads();
    if (tid == 0) {
        int run = 0;
        for (int d = 0; d < BK; ++d) { cur[d] = run; run += cnt[d]; }
    }
    __syncthreads();
    if (tid < BK) {
        int node = b * BK + tid;
        if (node < n) {
            offs[node] = e0 + cur[tid];
            dinv[node] = rsqrtf((float)(cnt[tid] + 1));  // +1 self-loop
        }
    }
    if (b == 0 && tid == 0) offs[n] = etot;
    __syncthreads();
    for (int i = e0 + tid; i < e1; i += 256) {
        int p = btmp[i];
        int pos = e0 + atomicAdd(&cur[p & 63], 1);
        csr[pos] = p >> 6;
    }
}

// ---------------- embed: h = relu(x @ We + be), x is [N,2] ----------------

__global__ void k_embed(const float* __restrict__ x, const float* __restrict__ We,
                        const float* __restrict__ be, float* __restrict__ h, int n) {
    int i = blockIdx.x * 256 + threadIdx.x;
    if (i >= n * HID) return;
    int node = i >> 7, j = i & 127;
    float v = x[2 * node] * We[j] + x[2 * node + 1] * We[HID + j] + be[j];
    h[i] = fmaxf(v, 0.f);
}

// ---------------- GEMM (plain, layer 1): th = fp16(dinv * (h @ W)) ----------

__global__ __launch_bounds__(256) void k_gemm128(const float* __restrict__ h, const float* __restrict__ W,
                                                 const float* __restrict__ dinv,
                                                 __half2* __restrict__ th, int n) {
    __shared__ float hs[128][66];
    __shared__ float ws[128][64];
    int tid = threadIdx.x;
    int nb = blockIdx.x * 64;
    const float4* h4 = (const float4*)h;
#pragma unroll
    for (int r = 0; r < 8; ++r) {
        int idx = r * 256 + tid;
        int ni = idx >> 5;
        int k4 = idx & 31;
        int node = nb + ni;
        float4 v = make_float4(0.f, 0.f, 0.f, 0.f);
        if (node < n) v = h4[(size_t)node * 32 + k4];
        hs[k4 * 4 + 0][ni] = v.x; hs[k4 * 4 + 1][ni] = v.y;
        hs[k4 * 4 + 2][ni] = v.z; hs[k4 * 4 + 3][ni] = v.w;
    }
    int fg = tid & 15, ng = tid >> 4;
    const float4* w4 = (const float4*)W;
    for (int c = 0; c < 2; ++c) {
        if (c) __syncthreads();
#pragma unroll
        for (int r = 0; r < 8; ++r) {
            int idx = r * 256 + tid;
            int k = idx >> 4, f4 = idx & 15;
            *((float4*)&ws[k][f4 * 4]) = w4[k * 32 + c * 16 + f4];
        }
        __syncthreads();
        float acc[4][4] = {{0.f}};
#pragma unroll 8
        for (int k = 0; k < 128; ++k) {
            float2 a0 = *((const float2*)&hs[k][ng * 4]);
            float2 a1 = *((const float2*)&hs[k][ng * 4 + 2]);
            float4 w = *((const float4*)&ws[k][fg * 4]);
            float av[4] = {a0.x, a0.y, a1.x, a1.y};
            float wv[4] = {w.x, w.y, w.z, w.w};
#pragma unroll
            for (int i = 0; i < 4; ++i)
#pragma unroll
                for (int j = 0; j < 4; ++j)
                    acc[i][j] += av[i] * wv[j];
        }
#pragma unroll
        for (int i = 0; i < 4; ++i) {
            int node = nb + ng * 4 + i;
            if (node < n) {
                float dv = dinv[node];
                union { __half2 hh[2]; float2 f; } pk;
                pk.hh[0] = __floats2half2_rn(acc[i][0] * dv, acc[i][1] * dv);
                pk.hh[1] = __floats2half2_rn(acc[i][2] * dv, acc[i][3] * dv);
                ((float2*)th)[((size_t)node * 128 + c * 64 + fg * 4) >> 2] = pk.f;
            }
        }
    }
}

// ---------------- GEMM fused with BN-apply+ReLU+residual (layers 2,3) -----------------

__global__ __launch_bounds__(256) void k_gemm128f(const float* __restrict__ agg, float* __restrict__ h,
                                                  const float* __restrict__ A, const float* __restrict__ Cc,
                                                  const float* __restrict__ W, const float* __restrict__ dinv,
                                                  __half2* __restrict__ th, int n) {
    __shared__ float hs[128][66];
    __shared__ float ws[128][64];
    __shared__ float As[128], Cs[128];
    int tid = threadIdx.x;
    int nb = blockIdx.x * 64;
    if (tid < 128) { As[tid] = A[tid]; Cs[tid] = Cc[tid]; }
    __syncthreads();
    const float4* a4p = (const float4*)agg;
    float4* h4 = (float4*)h;
#pragma unroll
    for (int r = 0; r < 8; ++r) {
        int idx = r * 256 + tid;
        int ni = idx >> 5;
        int k4 = idx & 31;
        int node = nb + ni;
        float4 v = make_float4(0.f, 0.f, 0.f, 0.f);
        if (node < n) {
            float4 a = a4p[(size_t)node * 32 + k4];
            float4 ho = h4[(size_t)node * 32 + k4];
            float4 aa = *((const float4*)&As[k4 * 4]);
            float4 cc = *((const float4*)&Cs[k4 * 4]);
            v.x = fmaxf(a.x * aa.x + cc.x, 0.f) + ho.x;
            v.y = fmaxf(a.y * aa.y + cc.y, 0.f) + ho.y;
            v.z = fmaxf(a.z * aa.z + cc.z, 0.f) + ho.z;
            v.w = fmaxf(a.w * aa.w + cc.w, 0.f) + ho.w;
            h4[(size_t)node * 32 + k4] = v;   // in-place: each element owned by one thread
        }
        hs[k4 * 4 + 0][ni] = v.x; hs[k4 * 4 + 1][ni] = v.y;
        hs[k4 * 4 + 2][ni] = v.z; hs[k4 * 4 + 3][ni] = v.w;
    }
    int fg = tid & 15, ng = tid >> 4;
    const float4* w4 = (const float4*)W;
    for (int c = 0; c < 2; ++c) {
        if (c) __syncthreads();
#pragma unroll
        for (int r = 0; r < 8; ++r) {
            int idx = r * 256 + tid;
            int k = idx >> 4, f4 = idx & 15;
            *((float4*)&ws[k][f4 * 4]) = w4[k * 32 + c * 16 + f4];
        }
        __syncthreads();
        float acc[4][4] = {{0.f}};
#pragma unroll 8
        for (int k = 0; k < 128; ++k) {
            float2 a0 = *((const float2*)&hs[k][ng * 4]);
            float2 a1 = *((const float2*)&hs[k][ng * 4 + 2]);
            float4 w = *((const float4*)&ws[k][fg * 4]);
            float av[4] = {a0.x, a0.y, a1.x, a1.y};
            float wv[4] = {w.x, w.y, w.z, w.w};
#pragma unroll
            for (int i = 0; i < 4; ++i)
#pragma unroll
                for (int j = 0; j < 4; ++j)
                    acc[i][j] += av[i] * wv[j];
        }
#pragma unroll
        for (int i = 0; i < 4; ++i) {
            int node = nb + ng * 4 + i;
            if (node < n) {
                float dv = dinv[node];
                union { __half2 hh[2]; float2 f; } pk;
                pk.hh[0] = __floats2half2_rn(acc[i][0] * dv, acc[i][1] * dv);
                pk.hh[1] = __floats2half2_rn(acc[i][2] * dv, acc[i][3] * dv);
                ((float2*)th)[((size_t)node * 128 + c * 64 + fg * 4) >> 2] = pk.f;
            }
        }
    }
}

// ---------------- aggregation + fused BN stats ---------------------------------------
// Dual-edge gather: lane l loads 8 B (4 features) of edge (e + (l>>5)); one wave-instr
// covers TWO edge rows -> halves vector-memory instruction count (gather is issue-bound).
// Sub-accumulators folded via shfl at the end. BN-stats atomics striped NSTRIPE ways
// to break the same-address serialization chain (~10 ns/op, chain = grid/NSTRIPE).

__global__ __launch_bounds__(256) void k_agg(const __half2* __restrict__ t, const int* __restrict__ offs,
                                             const int* __restrict__ csr, const float* __restrict__ dinv,
                                             const float* __restrict__ bias, float* __restrict__ out,
                                             float* __restrict__ S, float* __restrict__ SS, int n) {
    __shared__ float ls[4][128];
    __shared__ float lss[4][128];
    int tid = threadIdx.x;
    int lane = tid & 63, w = tid >> 6;
    int sub = lane >> 5, fl = lane & 31;          // fl: feature chunk (features 4fl..4fl+3)
    const uint2* t4 = (const uint2*)t;            // half4 rows: 32 chunks of 8 B
    float4 bb = ((const float4*)bias)[fl];
    float s0 = 0.f, s1 = 0.f, s2 = 0.f, s3 = 0.f;
    float q0 = 0.f, q1 = 0.f, q2 = 0.f, q3 = 0.f;
    float selfm = (sub == 0) ? 1.f : 0.f;
    int ngrp = (n + 3) >> 2;
    for (int grp = blockIdx.x; grp < ngrp; grp += gridDim.x) {
        int node = grp * 4 + w;                   // wave-uniform
        if (node < n) {
            // self row (both subs read same lines -> coalesced into one transaction set)
            uint2 rv = t4[(size_t)node * 32 + fl];
            float2 f0 = __half22float2(*(__half2*)&rv.x);
            float2 f1 = __half22float2(*(__half2*)&rv.y);
            float a0 = f0.x * selfm, a1 = f0.y * selfm, a2 = f1.x * selfm, a3 = f1.y * selfm;
            int e0 = offs[node], e1 = offs[node + 1];
            for (int e = e0; e < e1; e += 8) {
                int i0 = e + sub, i1 = e + 2 + sub, i2 = e + 4 + sub, i3 = e + 6 + sub;
                int c0 = csr[min(i0, e1 - 1)];
                int c1 = csr[min(i1, e1 - 1)];
                int c2 = csr[min(i2, e1 - 1)];
                int c3 = csr[min(i3, e1 - 1)];
                uint2 r0 = t4[(size_t)c0 * 32 + fl];
                uint2 r1 = t4[(size_t)c1 * 32 + fl];
                uint2 r2 = t4[(size_t)c2 * 32 + fl];
                uint2 r3 = t4[(size_t)c3 * 32 + fl];
                float m0 = (i0 < e1) ? 1.f : 0.f;
                float m1 = (i1 < e1) ? 1.f : 0.f;
                float m2 = (i2 < e1) ? 1.f : 0.f;
                float m3 = (i3 < e1) ? 1.f : 0.f;
                float2 g0 = __half22float2(*(__half2*)&r0.x), g1 = __half22float2(*(__half2*)&r0.y);
                a0 += m0 * g0.x; a1 += m0 * g0.y; a2 += m0 * g1.x; a3 += m0 * g1.y;
                g0 = __half22float2(*(__half2*)&r1.x); g1 = __half22float2(*(__half2*)&r1.y);
                a0 += m1 * g0.x; a1 += m1 * g0.y; a2 += m1 * g1.x; a3 += m1 * g1.y;
                g0 = __half22float2(*(__half2*)&r2.x); g1 = __half22float2(*(__half2*)&r2.y);
                a0 += m2 * g0.x; a1 += m2 * g0.y; a2 += m2 * g1.x; a3 += m2 * g1.y;
                g0 = __half22float2(*(__half2*)&r3.x); g1 = __half22float2(*(__half2*)&r3.y);
                a0 += m3 * g0.x; a1 += m3 * g0.y; a2 += m3 * g1.x; a3 += m3 * g1.y;
            }
            // fold sub1 into sub0
            a0 += __shfl_down(a0, 32);
            a1 += __shfl_down(a1, 32);
            a2 += __shfl_down(a2, 32);
            a3 += __shfl_down(a3, 32);
            if (sub == 0) {
                float di = dinv[node];
                float v0 = a0 * di + bb.x, v1 = a1 * di + bb.y;
                float v2 = a2 * di + bb.z, v3 = a3 * di + bb.w;
                ((float4*)out)[(size_t)node * 32 + fl] = make_float4(v0, v1, v2, v3);
                s0 += v0; s1 += v1; s2 += v2; s3 += v3;
                q0 += v0 * v0; q1 += v1 * v1; q2 += v2 * v2; q3 += v3 * v3;
            }
        }
    }
    if (sub == 0) {
        ((float4*)&ls[w][0])[fl] = make_float4(s0, s1, s2, s3);
        ((float4*)&lss[w][0])[fl] = make_float4(q0, q1, q2, q3);
    }
    __syncthreads();
    if (tid < 128) {
        float s = ls[0][tid] + ls[1][tid] + ls[2][tid] + ls[3][tid];
        float q = lss[0][tid] + lss[1][tid] + lss[2][tid] + lss[3][tid];
        int stripe = (blockIdx.x & (NSTRIPE - 1)) * 128;
        atomicAdd(&S[stripe + tid], s);
        atomicAdd(&SS[stripe + tid], q);
    }
}

// ---------------- BN ----------------

__global__ void k_bn_stats32(const float* __restrict__ v, float* __restrict__ S,
                             float* __restrict__ SS, int n) {
    int j = threadIdx.x & 31, sub = threadIdx.x >> 5;
    int per = (n + gridDim.x - 1) / gridDim.x;
    int start = blockIdx.x * per;
    int end = min(start + per, n);
    float s = 0.f, ss = 0.f;
    for (int i = start + sub; i < end; i += 4) {
        float x = v[(size_t)i * 32 + j];
        s += x; ss += x * x;
    }
    atomicAdd(&S[j], s);
    atomicAdd(&SS[j], ss);
}

// nstripe copies of hid-long partials, stride 128
__global__ void k_bn_finalize(const float* __restrict__ S, const float* __restrict__ SS,
                              const float* __restrict__ g, const float* __restrict__ bt,
                              float* __restrict__ A, float* __restrict__ C, int n, int hid, int nstripe) {
    int j = threadIdx.x;
    if (j >= hid) return;
    float s = 0.f, q = 0.f;
    for (int k = 0; k < nstripe; ++k) { s += S[k * 128 + j]; q += SS[k * 128 + j]; }
    float mu = s / (float)n;
    float var = q / (float)n - mu * mu;
    float inv = rsqrtf(var + EPS);
    A[j] = g[j] * inv;
    C[j] = bt[j] - mu * g[j] * inv;
}

// ---------------- head GEMM fused with BN-apply+ReLU+residual (reads agg3, h2) -------

__global__ __launch_bounds__(256) void k_gemmff(const float* __restrict__ agg, const float* __restrict__ h,
                                                const float* __restrict__ A, const float* __restrict__ Cc,
                                                const float* __restrict__ W, const float* __restrict__ bias,
                                                float* __restrict__ out, int n) {
    __shared__ float hs[128][66];
    __shared__ float ws[128][32];
    __shared__ float As[128], Cs[128];
    int tid = threadIdx.x;
    int nb = blockIdx.x * 64;
    if (tid < 128) { As[tid] = A[tid]; Cs[tid] = Cc[tid]; }
    __syncthreads();
    const float4* a4p = (const float4*)agg;
    const float4* h4 = (const float4*)h;
#pragma unroll
    for (int r = 0; r < 8; ++r) {
        int idx = r * 256 + tid;
        int ni = idx >> 5, k4 = idx & 31;
        int node = nb + ni;
        float4 v = make_float4(0.f, 0.f, 0.f, 0.f);
        if (node < n) {
            float4 a = a4p[(size_t)node * 32 + k4];
            float4 ho = h4[(size_t)node * 32 + k4];
            float4 aa = *((const float4*)&As[k4 * 4]);
            float4 cc = *((const float4*)&Cs[k4 * 4]);
            v.x = fmaxf(a.x * aa.x + cc.x, 0.f) + ho.x;
            v.y = fmaxf(a.y * aa.y + cc.y, 0.f) + ho.y;
            v.z = fmaxf(a.z * aa.z + cc.z, 0.f) + ho.z;
            v.w = fmaxf(a.w * aa.w + cc.w, 0.f) + ho.w;
        }
        hs[k4 * 4 + 0][ni] = v.x; hs[k4 * 4 + 1][ni] = v.y;
        hs[k4 * 4 + 2][ni] = v.z; hs[k4 * 4 + 3][ni] = v.w;
    }
    const float4* w4 = (const float4*)W;
#pragma unroll
    for (int r = 0; r < 4; ++r) {
        int idx = r * 256 + tid;
        int k = idx >> 3, f4 = idx & 7;
        *((float4*)&ws[k][f4 * 4]) = w4[k * 8 + f4];
    }
    __syncthreads();
    int fg = tid & 7, ng = tid >> 3;
    float acc[2][4] = {{0.f}};
#pragma unroll 8
    for (int k = 0; k < 128; ++k) {
        float2 a = *((const float2*)&hs[k][ng * 2]);
        float4 w = *((const float4*)&ws[k][fg * 4]);
        acc[0][0] += a.x * w.x; acc[0][1] += a.x * w.y; acc[0][2] += a.x * w.z; acc[0][3] += a.x * w.w;
        acc[1][0] += a.y * w.x; acc[1][1] += a.y * w.y; acc[1][2] += a.y * w.z; acc[1][3] += a.y * w.w;
    }
    float4 bb = *((const float4*)&bias[fg * 4]);
#pragma unroll
    for (int i = 0; i < 2; ++i) {
        int node = nb + ng * 2 + i;
        if (node < n)
            *((float4*)&out[(size_t)node * 32 + fg * 4]) =
                make_float4(acc[i][0] + bb.x, acc[i][1] + bb.y, acc[i][2] + bb.z, acc[i][3] + bb.w);
    }
}

// ---------------- final: out = tanh(relu(bn(tf)) @ Wf2 + bf2) ----------------

__global__ void k_final(const float* __restrict__ tf, const float* __restrict__ A,
                        const float* __restrict__ C, const float* __restrict__ Wf2,
                        const float* __restrict__ bf2, float* __restrict__ out, int n) {
    int node = blockIdx.x * 256 + threadIdx.x;
    if (node >= n) return;
    float o0 = bf2[0], o1 = bf2[1];
    const float4* t4 = (const float4*)(tf + (size_t)node * 32);
#pragma unroll
    for (int q = 0; q < 8; ++q) {
        float4 v = t4[q];
        float vv[4] = {v.x, v.y, v.z, v.w};
#pragma unroll
        for (int r = 0; r < 4; ++r) {
            int j = q * 4 + r;
            float f = fmaxf(vv[r] * A[j] + C[j], 0.f);
            o0 += f * Wf2[2 * j];
            o1 += f * Wf2[2 * j + 1];
        }
    }
    out[2 * node] = tanhf(o0);
    out[2 * node + 1] = tanhf(o1);
}

// ---------------- launch ----------------

extern "C" void kernel_launch(void* const* d_in, const int* in_sizes, int n_in,
                              void* d_out, int out_size, void* d_ws, size_t ws_size,
                              hipStream_t stream) {
    const float* x   = (const float*)d_in[0];
    const int*   ei  = (const int*)d_in[1];
    const float* We  = (const float*)d_in[2];
    const float* be  = (const float*)d_in[3];
    const float* W1  = (const float*)d_in[4];
    const float* b1  = (const float*)d_in[5];
    const float* g1  = (const float*)d_in[6];
    const float* bt1 = (const float*)d_in[7];
    const float* W2  = (const float*)d_in[8];
    const float* b2  = (const float*)d_in[9];
    const float* g2  = (const float*)d_in[10];
    const float* bt2 = (const float*)d_in[11];
    const float* W3  = (const float*)d_in[12];
    const float* b3  = (const float*)d_in[13];
    const float* g3  = (const float*)d_in[14];
    const float* bt3 = (const float*)d_in[15];
    const float* Wf1 = (const float*)d_in[16];
    const float* bf1 = (const float*)d_in[17];
    const float* gf  = (const float*)d_in[18];
    const float* btf = (const float*)d_in[19];
    const float* Wf2 = (const float*)d_in[20];
    const float* bf2 = (const float*)d_in[21];
    float* out = (float*)d_out;

    const int n = in_sizes[0] / 2;      // x is [N,2]
    const int e = in_sizes[1] / 2;      // edge_index is [2,E]
    const int* srcp = ei;
    const int* dstp = ei + e;
    const int nbk = (n + BK - 1) / BK;

    char* p = (char*)d_ws;
    auto alloc = [&](size_t bytes) { void* r = (void*)p; p += (bytes + 255) & ~(size_t)255; return r; };
    int*     bcount = (int*)alloc((size_t)nbk * 16 * 4);
    int*     boffs  = (int*)alloc((size_t)(nbk + 1) * 4);
    int*     bcur   = (int*)alloc((size_t)nbk * 16 * 4);
    int*     btmp   = (int*)alloc((size_t)e * 4);
    int*     csr    = (int*)alloc((size_t)e * 4);
    int*     offs   = (int*)alloc((size_t)(n + 1) * 4);
    float*   dinv   = (float*)alloc((size_t)n * 4);
    float*   h      = (float*)alloc((size_t)n * HID * 4);
    __half2* th     = (__half2*)alloc((size_t)n * HID * 2);
    float*   agg    = (float*)alloc((size_t)n * HID * 4);
    float*   tf     = (float*)alloc((size_t)n * 32 * 4);
    float*   bnS    = (float*)alloc(NSTRIPE * 128 * 4);
    float*   bnSS   = (float*)alloc(NSTRIPE * 128 * 4);
    float*   bnA    = (float*)alloc(HID * 4);
    float*   bnC    = (float*)alloc(HID * 4);

    hipMemsetAsync(bcount, 0, (size_t)nbk * 16 * 4, stream);
    k_bhist<<<(e + 4095) / 4096, 256, 0, stream>>>(dstp, bcount, e, nbk);
    k_bscan<<<1, 1024, 0, stream>>>(bcount, boffs, bcur, nbk, e);
    k_bscatter<<<256, 1024, 0, stream>>>(srcp, dstp, bcur, btmp, e, nbk);
    k_bsort<<<nbk, 256, 0, stream>>>(btmp, boffs, csr, offs, dinv, n, e);
    k_embed<<<(n * HID + 255) / 256, 256, 0, stream>>>(x, We, be, h, n);

    // layer 1
    k_gemm128<<<(n + 63) / 64, 256, 0, stream>>>(h, W1, dinv, th, n);
    hipMemsetAsync(bnS, 0, NSTRIPE * 128 * 4, stream);
    hipMemsetAsync(bnSS, 0, NSTRIPE * 128 * 4, stream);
    k_agg<<<4096, 256, 0, stream>>>(th, offs, csr, dinv, b1, agg, bnS, bnSS, n);
    k_bn_finalize<<<1, 128, 0, stream>>>(bnS, bnSS, g1, bt1, bnA, bnC, n, 128, NSTRIPE);

    // layer 2 (gemm fused with layer-1 bn-apply+relu+residual)
    k_gemm128f<<<(n + 63) / 64, 256, 0, stream>>>(agg, h, bnA, bnC, W2, dinv, th, n);
    hipMemsetAsync(bnS, 0, NSTRIPE * 128 * 4, stream);
    hipMemsetAsync(bnSS, 0, NSTRIPE * 128 * 4, stream);
    k_agg<<<4096, 256, 0, stream>>>(th, offs, csr, dinv, b2, agg, bnS, bnSS, n);
    k_bn_finalize<<<1, 128, 0, stream>>>(bnS, bnSS, g2, bt2, bnA, bnC, n, 128, NSTRIPE);

    // layer 3
    k_gemm128f<<<(n + 63) / 64, 256, 0, stream>>>(agg, h, bnA, bnC, W3, dinv, th, n);
    hipMemsetAsync(bnS, 0, NSTRIPE * 128 * 4, stream);
    hipMemsetAsync(bnSS, 0, NSTRIPE * 128 * 4, stream);
    k_agg<<<4096, 256, 0, stream>>>(th, offs, csr, dinv, b3, agg, bnS, bnSS, n);
    k_bn_finalize<<<1, 128, 0, stream>>>(bnS, bnSS, g3, bt3, bnA, bnC, n, 128, NSTRIPE);

    // head (gemm fused with layer-3 bn-apply+relu+residual; h3 never materialized)
    k_gemmff<<<(n + 63) / 64, 256, 0, stream>>>(agg, h, bnA, bnC, Wf1, bf1, tf, n);
    hipMemsetAsync(bnS, 0, 128 * 4, stream);
    hipMemsetAsync(bnSS, 0, 128 * 4, stream);
    k_bn_stats32<<<512, 128, 0, stream>>>(tf, bnS, bnSS, n);
    k_bn_finalize<<<1, 32, 0, stream>>>(bnS, bnSS, gf, btf, bnA, bnC, n, 32, 1);
    k_final<<<(n + 255) / 256, 256, 0, stream>>>(tf, bnA, bnC, Wf2, bf2, out, n);
}

// Round 9
// 676.811 us; speedup vs baseline: 1.4145x; 1.1171x over previous
//
#include <hip/hip_runtime.h>
#include <hip/hip_fp16.h>
#include <math.h>

#define HID 128
#define EPS 1e-5f
#define BK 64          // dst nodes per bucket
#define MAXNBK 2048    // supports n <= 131072
#define NSTRIPE 16     // BN-stats atomic striping (breaks same-address chains)

// ---------------- bucketed graph preprocessing ----------------
// btmp entry: (src << 6) | (dst & 63)  -- src < 2^26 required (n=1e5 ok)

__global__ __launch_bounds__(256) void k_bhist(const int* __restrict__ dst, int* __restrict__ bcount,
                                               int e, int nbk) {
    __shared__ int hist[MAXNBK];
    for (int i = threadIdx.x; i < nbk; i += 256) hist[i] = 0;
    __syncthreads();
    int base = blockIdx.x * 4096;
    int end = min(base + 4096, e);
    for (int i = base + threadIdx.x; i < end; i += 256) atomicAdd(&hist[dst[i] >> 6], 1);
    __syncthreads();
    for (int i = threadIdx.x; i < nbk; i += 256) {
        int c = hist[i];
        if (c) atomicAdd(&bcount[i * 16], c);
    }
}

__global__ __launch_bounds__(1024) void k_bscan(const int* __restrict__ bcount, int* __restrict__ boffs,
                                                int* __restrict__ bcur, int nbk, int e) {
    __shared__ int lds[1024];
    int tid = threadIdx.x;
    int i0 = 2 * tid, i1 = 2 * tid + 1;
    int a = (i0 < nbk) ? bcount[i0 * 16] : 0;
    int b = (i1 < nbk) ? bcount[i1 * 16] : 0;
    lds[tid] = a + b;
    __syncthreads();
    for (int off = 1; off < 1024; off <<= 1) {
        int v = (tid >= off) ? lds[tid - off] : 0;
        __syncthreads();
        lds[tid] += v;
        __syncthreads();
    }
    int excl = lds[tid] - (a + b);
    if (i0 < nbk) { boffs[i0] = excl;     bcur[i0 * 16] = excl; }
    if (i1 < nbk) { boffs[i1] = excl + a; bcur[i1 * 16] = excl + a; }
    if (tid == 1023) boffs[nbk] = e;
}

__global__ __launch_bounds__(1024) void k_bscatter(const int* __restrict__ src, const int* __restrict__ dst,
                                                   int* __restrict__ bcur, int* __restrict__ btmp,
                                                   int e, int nbk) {
    __shared__ int hist[MAXNBK];
    int tid = threadIdx.x;
    for (int i = tid; i < nbk; i += 1024) hist[i] = 0;
    __syncthreads();
    int per = (e + gridDim.x - 1) / gridDim.x;
    int base = blockIdx.x * per;
    int end = min(base + per, e);
    for (int i = base + tid; i < end; i += 1024) atomicAdd(&hist[dst[i] >> 6], 1);
    __syncthreads();
    for (int i = tid; i < nbk; i += 1024) {
        int c = hist[i];
        hist[i] = c ? atomicAdd(&bcur[i * 16], c) : 0;
    }
    __syncthreads();
    for (int i = base + tid; i < end; i += 1024) {
        int d = dst[i];
        int pos = atomicAdd(&hist[d >> 6], 1);          // LDS int atomic (native)
        btmp[pos] = (src[i] << 6) | (d & 63);
    }
}

// per-bucket counting sort: btmp -> csr (dst-sorted src ids) + offs + dinv (int LDS atomics only)
__global__ __launch_bounds__(256) void k_bsort(const int* __restrict__ btmp, const int* __restrict__ boffs,
                                               int* __restrict__ csr, int* __restrict__ offs,
                                               float* __restrict__ dinv, int n, int etot) {
    __shared__ int cnt[BK];
    __shared__ int cur[BK];
    int b = blockIdx.x, tid = threadIdx.x;
    if (tid < BK) cnt[tid] = 0;
    __syncthreads();
    int e0 = boffs[b], e1 = boffs[b + 1];
    for (int i = e0 + tid; i < e1; i += 256) atomicAdd(&cnt[btmp[i] & 63], 1);
    __syncthreads();
    if (tid == 0) {
        int run = 0;
        for (int d = 0; d < BK; ++d) { cur[d] = run; run += cnt[d]; }
    }
    __syncthreads();
    if (tid < BK) {
        int node = b * BK + tid;
        if (node < n) {
            offs[node] = e0 + cur[tid];
            dinv[node] = rsqrtf((float)(cnt[tid] + 1));  // +1 self-loop
        }
    }
    if (b == 0 && tid == 0) offs[n] = etot;
    __syncthreads();
    for (int i = e0 + tid; i < e1; i += 256) {
        int p = btmp[i];
        int pos = e0 + atomicAdd(&cur[p & 63], 1);
        csr[pos] = p >> 6;
    }
}

// ---------------- embed: h = relu(x @ We + be), x is [N,2] ----------------

__global__ void k_embed(const float* __restrict__ x, const float* __restrict__ We,
                        const float* __restrict__ be, float* __restrict__ h, int n) {
    int i = blockIdx.x * 256 + threadIdx.x;
    if (i >= n * HID) return;
    int node = i >> 7, j = i & 127;
    float v = x[2 * node] * We[j] + x[2 * node + 1] * We[HID + j] + be[j];
    h[i] = fmaxf(v, 0.f);
}

// ---------------- GEMM (plain, layer 1): th = fp16(dinv * (h @ W)) ----------

__global__ __launch_bounds__(256) void k_gemm128(const float* __restrict__ h, const float* __restrict__ W,
                                                 const float* __restrict__ dinv,
                                                 __half2* __restrict__ th, int n) {
    __shared__ float hs[128][66];
    __shared__ float ws[128][64];
    int tid = threadIdx.x;
    int nb = blockIdx.x * 64;
    const float4* h4 = (const float4*)h;
#pragma unroll
    for (int r = 0; r < 8; ++r) {
        int idx = r * 256 + tid;
        int ni = idx >> 5;
        int k4 = idx & 31;
        int node = nb + ni;
        float4 v = make_float4(0.f, 0.f, 0.f, 0.f);
        if (node < n) v = h4[(size_t)node * 32 + k4];
        hs[k4 * 4 + 0][ni] = v.x; hs[k4 * 4 + 1][ni] = v.y;
        hs[k4 * 4 + 2][ni] = v.z; hs[k4 * 4 + 3][ni] = v.w;
    }
    int fg = tid & 15, ng = tid >> 4;
    const float4* w4 = (const float4*)W;
    for (int c = 0; c < 2; ++c) {
        if (c) __syncthreads();
#pragma unroll
        for (int r = 0; r < 8; ++r) {
            int idx = r * 256 + tid;
            int k = idx >> 4, f4 = idx & 15;
            *((float4*)&ws[k][f4 * 4]) = w4[k * 32 + c * 16 + f4];
        }
        __syncthreads();
        float acc[4][4] = {{0.f}};
#pragma unroll 8
        for (int k = 0; k < 128; ++k) {
            float2 a0 = *((const float2*)&hs[k][ng * 4]);
            float2 a1 = *((const float2*)&hs[k][ng * 4 + 2]);
            float4 w = *((const float4*)&ws[k][fg * 4]);
            float av[4] = {a0.x, a0.y, a1.x, a1.y};
            float wv[4] = {w.x, w.y, w.z, w.w};
#pragma unroll
            for (int i = 0; i < 4; ++i)
#pragma unroll
                for (int j = 0; j < 4; ++j)
                    acc[i][j] += av[i] * wv[j];
        }
#pragma unroll
        for (int i = 0; i < 4; ++i) {
            int node = nb + ng * 4 + i;
            if (node < n) {
                float dv = dinv[node];
                union { __half2 hh[2]; float2 f; } pk;
                pk.hh[0] = __floats2half2_rn(acc[i][0] * dv, acc[i][1] * dv);
                pk.hh[1] = __floats2half2_rn(acc[i][2] * dv, acc[i][3] * dv);
                ((float2*)th)[((size_t)node * 128 + c * 64 + fg * 4) >> 2] = pk.f;
            }
        }
    }
}

// ---------------- GEMM fused with BN-apply+ReLU+residual (layers 2,3) -----------------

__global__ __launch_bounds__(256) void k_gemm128f(const float* __restrict__ agg, float* __restrict__ h,
                                                  const float* __restrict__ A, const float* __restrict__ Cc,
                                                  const float* __restrict__ W, const float* __restrict__ dinv,
                                                  __half2* __restrict__ th, int n) {
    __shared__ float hs[128][66];
    __shared__ float ws[128][64];
    __shared__ float As[128], Cs[128];
    int tid = threadIdx.x;
    int nb = blockIdx.x * 64;
    if (tid < 128) { As[tid] = A[tid]; Cs[tid] = Cc[tid]; }
    __syncthreads();
    const float4* a4p = (const float4*)agg;
    float4* h4 = (float4*)h;
#pragma unroll
    for (int r = 0; r < 8; ++r) {
        int idx = r * 256 + tid;
        int ni = idx >> 5;
        int k4 = idx & 31;
        int node = nb + ni;
        float4 v = make_float4(0.f, 0.f, 0.f, 0.f);
        if (node < n) {
            float4 a = a4p[(size_t)node * 32 + k4];
            float4 ho = h4[(size_t)node * 32 + k4];
            float4 aa = *((const float4*)&As[k4 * 4]);
            float4 cc = *((const float4*)&Cs[k4 * 4]);
            v.x = fmaxf(a.x * aa.x + cc.x, 0.f) + ho.x;
            v.y = fmaxf(a.y * aa.y + cc.y, 0.f) + ho.y;
            v.z = fmaxf(a.z * aa.z + cc.z, 0.f) + ho.z;
            v.w = fmaxf(a.w * aa.w + cc.w, 0.f) + ho.w;
            h4[(size_t)node * 32 + k4] = v;   // in-place: each element owned by one thread
        }
        hs[k4 * 4 + 0][ni] = v.x; hs[k4 * 4 + 1][ni] = v.y;
        hs[k4 * 4 + 2][ni] = v.z; hs[k4 * 4 + 3][ni] = v.w;
    }
    int fg = tid & 15, ng = tid >> 4;
    const float4* w4 = (const float4*)W;
    for (int c = 0; c < 2; ++c) {
        if (c) __syncthreads();
#pragma unroll
        for (int r = 0; r < 8; ++r) {
            int idx = r * 256 + tid;
            int k = idx >> 4, f4 = idx & 15;
            *((float4*)&ws[k][f4 * 4]) = w4[k * 32 + c * 16 + f4];
        }
        __syncthreads();
        float acc[4][4] = {{0.f}};
#pragma unroll 8
        for (int k = 0; k < 128; ++k) {
            float2 a0 = *((const float2*)&hs[k][ng * 4]);
            float2 a1 = *((const float2*)&hs[k][ng * 4 + 2]);
            float4 w = *((const float4*)&ws[k][fg * 4]);
            float av[4] = {a0.x, a0.y, a1.x, a1.y};
            float wv[4] = {w.x, w.y, w.z, w.w};
#pragma unroll
            for (int i = 0; i < 4; ++i)
#pragma unroll
                for (int j = 0; j < 4; ++j)
                    acc[i][j] += av[i] * wv[j];
        }
#pragma unroll
        for (int i = 0; i < 4; ++i) {
            int node = nb + ng * 4 + i;
            if (node < n) {
                float dv = dinv[node];
                union { __half2 hh[2]; float2 f; } pk;
                pk.hh[0] = __floats2half2_rn(acc[i][0] * dv, acc[i][1] * dv);
                pk.hh[1] = __floats2half2_rn(acc[i][2] * dv, acc[i][3] * dv);
                ((float2*)th)[((size_t)node * 128 + c * 64 + fg * 4) >> 2] = pk.f;
            }
        }
    }
}

// ---------------- aggregation + fused BN stats ---------------------------------------
// Dual-edge gather: lane l loads 8 B (4 features) of edge (e + (l>>5)); one wave-instr
// covers TWO edge rows. Sub-accumulators folded via shfl. BN-stats atomics striped.

__global__ __launch_bounds__(256) void k_agg(const __half2* __restrict__ t, const int* __restrict__ offs,
                                             const int* __restrict__ csr, const float* __restrict__ dinv,
                                             const float* __restrict__ bias, float* __restrict__ out,
                                             float* __restrict__ S, float* __restrict__ SS, int n) {
    __shared__ float ls[4][128];
    __shared__ float lss[4][128];
    int tid = threadIdx.x;
    int lane = tid & 63, w = tid >> 6;
    int sub = lane >> 5, fl = lane & 31;          // fl: feature chunk (features 4fl..4fl+3)
    const uint2* t4 = (const uint2*)t;            // half4 rows: 32 chunks of 8 B
    float4 bb = ((const float4*)bias)[fl];
    float s0 = 0.f, s1 = 0.f, s2 = 0.f, s3 = 0.f;
    float q0 = 0.f, q1 = 0.f, q2 = 0.f, q3 = 0.f;
    float selfm = (sub == 0) ? 1.f : 0.f;
    int ngrp = (n + 3) >> 2;
    for (int grp = blockIdx.x; grp < ngrp; grp += gridDim.x) {
        int node = grp * 4 + w;                   // wave-uniform
        if (node < n) {
            uint2 rv = t4[(size_t)node * 32 + fl];
            float2 f0 = __half22float2(*(__half2*)&rv.x);
            float2 f1 = __half22float2(*(__half2*)&rv.y);
            float a0 = f0.x * selfm, a1 = f0.y * selfm, a2 = f1.x * selfm, a3 = f1.y * selfm;
            int e0 = offs[node], e1 = offs[node + 1];
            for (int e = e0; e < e1; e += 8) {
                int i0 = e + sub, i1 = e + 2 + sub, i2 = e + 4 + sub, i3 = e + 6 + sub;
                int c0 = csr[min(i0, e1 - 1)];
                int c1 = csr[min(i1, e1 - 1)];
                int c2 = csr[min(i2, e1 - 1)];
                int c3 = csr[min(i3, e1 - 1)];
                uint2 r0 = t4[(size_t)c0 * 32 + fl];
                uint2 r1 = t4[(size_t)c1 * 32 + fl];
                uint2 r2 = t4[(size_t)c2 * 32 + fl];
                uint2 r3 = t4[(size_t)c3 * 32 + fl];
                float m0 = (i0 < e1) ? 1.f : 0.f;
                float m1 = (i1 < e1) ? 1.f : 0.f;
                float m2 = (i2 < e1) ? 1.f : 0.f;
                float m3 = (i3 < e1) ? 1.f : 0.f;
                float2 g0 = __half22float2(*(__half2*)&r0.x), g1 = __half22float2(*(__half2*)&r0.y);
                a0 += m0 * g0.x; a1 += m0 * g0.y; a2 += m0 * g1.x; a3 += m0 * g1.y;
                g0 = __half22float2(*(__half2*)&r1.x); g1 = __half22float2(*(__half2*)&r1.y);
                a0 += m1 * g0.x; a1 += m1 * g0.y; a2 += m1 * g1.x; a3 += m1 * g1.y;
                g0 = __half22float2(*(__half2*)&r2.x); g1 = __half22float2(*(__half2*)&r2.y);
                a0 += m2 * g0.x; a1 += m2 * g0.y; a2 += m2 * g1.x; a3 += m2 * g1.y;
                g0 = __half22float2(*(__half2*)&r3.x); g1 = __half22float2(*(__half2*)&r3.y);
                a0 += m3 * g0.x; a1 += m3 * g0.y; a2 += m3 * g1.x; a3 += m3 * g1.y;
            }
            a0 += __shfl_down(a0, 32);
            a1 += __shfl_down(a1, 32);
            a2 += __shfl_down(a2, 32);
            a3 += __shfl_down(a3, 32);
            if (sub == 0) {
                float di = dinv[node];
                float v0 = a0 * di + bb.x, v1 = a1 * di + bb.y;
                float v2 = a2 * di + bb.z, v3 = a3 * di + bb.w;
                ((float4*)out)[(size_t)node * 32 + fl] = make_float4(v0, v1, v2, v3);
                s0 += v0; s1 += v1; s2 += v2; s3 += v3;
                q0 += v0 * v0; q1 += v1 * v1; q2 += v2 * v2; q3 += v3 * v3;
            }
        }
    }
    if (sub == 0) {
        ((float4*)&ls[w][0])[fl] = make_float4(s0, s1, s2, s3);
        ((float4*)&lss[w][0])[fl] = make_float4(q0, q1, q2, q3);
    }
    __syncthreads();
    if (tid < 128) {
        float s = ls[0][tid] + ls[1][tid] + ls[2][tid] + ls[3][tid];
        float q = lss[0][tid] + lss[1][tid] + lss[2][tid] + lss[3][tid];
        int stripe = (blockIdx.x & (NSTRIPE - 1)) * 128;
        atomicAdd(&S[stripe + tid], s);
        atomicAdd(&SS[stripe + tid], q);
    }
}

// ---------------- BN finalize (nstripe copies, stride 128) ----------------

__global__ void k_bn_finalize(const float* __restrict__ S, const float* __restrict__ SS,
                              const float* __restrict__ g, const float* __restrict__ bt,
                              float* __restrict__ A, float* __restrict__ C, int n, int hid, int nstripe) {
    int j = threadIdx.x;
    if (j >= hid) return;
    float s = 0.f, q = 0.f;
    for (int k = 0; k < nstripe; ++k) { s += S[k * 128 + j]; q += SS[k * 128 + j]; }
    float mu = s / (float)n;
    float var = q / (float)n - mu * mu;
    float inv = rsqrtf(var + EPS);
    A[j] = g[j] * inv;
    C[j] = bt[j] - mu * g[j] * inv;
}

// ---------------- head GEMM fused with BN-apply+ReLU+residual AND head-BN stats -------
// tf = (relu(agg*A+C)+h) @ Wf1 + bf1; per-block Sum/SumSq over tf's 32 feats -> striped atomics.

__global__ __launch_bounds__(256) void k_gemmff(const float* __restrict__ agg, const float* __restrict__ h,
                                                const float* __restrict__ A, const float* __restrict__ Cc,
                                                const float* __restrict__ W, const float* __restrict__ bias,
                                                float* __restrict__ out,
                                                float* __restrict__ S, float* __restrict__ SS, int n) {
    __shared__ float hs[128][66];
    __shared__ float ws[128][32];
    __shared__ float As[128], Cs[128];
    int tid = threadIdx.x;
    int nb = blockIdx.x * 64;
    if (tid < 128) { As[tid] = A[tid]; Cs[tid] = Cc[tid]; }
    __syncthreads();
    const float4* a4p = (const float4*)agg;
    const float4* h4 = (const float4*)h;
#pragma unroll
    for (int r = 0; r < 8; ++r) {
        int idx = r * 256 + tid;
        int ni = idx >> 5, k4 = idx & 31;
        int node = nb + ni;
        float4 v = make_float4(0.f, 0.f, 0.f, 0.f);
        if (node < n) {
            float4 a = a4p[(size_t)node * 32 + k4];
            float4 ho = h4[(size_t)node * 32 + k4];
            float4 aa = *((const float4*)&As[k4 * 4]);
            float4 cc = *((const float4*)&Cs[k4 * 4]);
            v.x = fmaxf(a.x * aa.x + cc.x, 0.f) + ho.x;
            v.y = fmaxf(a.y * aa.y + cc.y, 0.f) + ho.y;
            v.z = fmaxf(a.z * aa.z + cc.z, 0.f) + ho.z;
            v.w = fmaxf(a.w * aa.w + cc.w, 0.f) + ho.w;
        }
        hs[k4 * 4 + 0][ni] = v.x; hs[k4 * 4 + 1][ni] = v.y;
        hs[k4 * 4 + 2][ni] = v.z; hs[k4 * 4 + 3][ni] = v.w;
    }
    const float4* w4 = (const float4*)W;
#pragma unroll
    for (int r = 0; r < 4; ++r) {
        int idx = r * 256 + tid;
        int k = idx >> 3, f4 = idx & 7;
        *((float4*)&ws[k][f4 * 4]) = w4[k * 8 + f4];
    }
    __syncthreads();
    int fg = tid & 7, ng = tid >> 3;
    float acc[2][4] = {{0.f}};
#pragma unroll 8
    for (int k = 0; k < 128; ++k) {
        float2 a = *((const float2*)&hs[k][ng * 2]);
        float4 w = *((const float4*)&ws[k][fg * 4]);
        acc[0][0] += a.x * w.x; acc[0][1] += a.x * w.y; acc[0][2] += a.x * w.z; acc[0][3] += a.x * w.w;
        acc[1][0] += a.y * w.x; acc[1][1] += a.y * w.y; acc[1][2] += a.y * w.z; acc[1][3] += a.y * w.w;
    }
    float4 bb = *((const float4*)&bias[fg * 4]);
    float ps0 = 0.f, ps1 = 0.f, ps2 = 0.f, ps3 = 0.f;
    float pq0 = 0.f, pq1 = 0.f, pq2 = 0.f, pq3 = 0.f;
#pragma unroll
    for (int i = 0; i < 2; ++i) {
        int node = nb + ng * 2 + i;
        if (node < n) {
            float v0 = acc[i][0] + bb.x, v1 = acc[i][1] + bb.y;
            float v2 = acc[i][2] + bb.z, v3 = acc[i][3] + bb.w;
            *((float4*)&out[(size_t)node * 32 + fg * 4]) = make_float4(v0, v1, v2, v3);
            ps0 += v0; ps1 += v1; ps2 += v2; ps3 += v3;
            pq0 += v0 * v0; pq1 += v1 * v1; pq2 += v2 * v2; pq3 += v3 * v3;
        }
    }
    // fused BN stats: reuse ws as reduction scratch (all reads of ws done)
    __syncthreads();
    float* rs = &ws[0][0];    // [32][32]: rs[ng][feat]
    float* rq = &ws[32][0];   // [32][32]
    rs[ng * 32 + fg * 4 + 0] = ps0; rs[ng * 32 + fg * 4 + 1] = ps1;
    rs[ng * 32 + fg * 4 + 2] = ps2; rs[ng * 32 + fg * 4 + 3] = ps3;
    rq[ng * 32 + fg * 4 + 0] = pq0; rq[ng * 32 + fg * 4 + 1] = pq1;
    rq[ng * 32 + fg * 4 + 2] = pq2; rq[ng * 32 + fg * 4 + 3] = pq3;
    __syncthreads();
    if (tid < 32) {
        float s = 0.f, q = 0.f;
#pragma unroll 8
        for (int g = 0; g < 32; ++g) { s += rs[g * 32 + tid]; q += rq[g * 32 + tid]; }
        int stripe = (blockIdx.x & (NSTRIPE - 1)) * 128;
        atomicAdd(&S[stripe + tid], s);
        atomicAdd(&SS[stripe + tid], q);
    }
}

// ---------------- final: out = tanh(relu(bn(tf)) @ Wf2 + bf2) ----------------

__global__ void k_final(const float* __restrict__ tf, const float* __restrict__ A,
                        const float* __restrict__ C, const float* __restrict__ Wf2,
                        const float* __restrict__ bf2, float* __restrict__ out, int n) {
    int node = blockIdx.x * 256 + threadIdx.x;
    if (node >= n) return;
    float o0 = bf2[0], o1 = bf2[1];
    const float4* t4 = (const float4*)(tf + (size_t)node * 32);
#pragma unroll
    for (int q = 0; q < 8; ++q) {
        float4 v = t4[q];
        float vv[4] = {v.x, v.y, v.z, v.w};
#pragma unroll
        for (int r = 0; r < 4; ++r) {
            int j = q * 4 + r;
            float f = fmaxf(vv[r] * A[j] + C[j], 0.f);
            o0 += f * Wf2[2 * j];
            o1 += f * Wf2[2 * j + 1];
        }
    }
    out[2 * node] = tanhf(o0);
    out[2 * node + 1] = tanhf(o1);
}

// ---------------- launch ----------------

extern "C" void kernel_launch(void* const* d_in, const int* in_sizes, int n_in,
                              void* d_out, int out_size, void* d_ws, size_t ws_size,
                              hipStream_t stream) {
    const float* x   = (const float*)d_in[0];
    const int*   ei  = (const int*)d_in[1];
    const float* We  = (const float*)d_in[2];
    const float* be  = (const float*)d_in[3];
    const float* W1  = (const float*)d_in[4];
    const float* b1  = (const float*)d_in[5];
    const float* g1  = (const float*)d_in[6];
    const float* bt1 = (const float*)d_in[7];
    const float* W2  = (const float*)d_in[8];
    const float* b2  = (const float*)d_in[9];
    const float* g2  = (const float*)d_in[10];
    const float* bt2 = (const float*)d_in[11];
    const float* W3  = (const float*)d_in[12];
    const float* b3  = (const float*)d_in[13];
    const float* g3  = (const float*)d_in[14];
    const float* bt3 = (const float*)d_in[15];
    const float* Wf1 = (const float*)d_in[16];
    const float* bf1 = (const float*)d_in[17];
    const float* gf  = (const float*)d_in[18];
    const float* btf = (const float*)d_in[19];
    const float* Wf2 = (const float*)d_in[20];
    const float* bf2 = (const float*)d_in[21];
    float* out = (float*)d_out;

    const int n = in_sizes[0] / 2;      // x is [N,2]
    const int e = in_sizes[1] / 2;      // edge_index is [2,E]
    const int* srcp = ei;
    const int* dstp = ei + e;
    const int nbk = (n + BK - 1) / BK;

    char* p = (char*)d_ws;
    auto alloc = [&](size_t bytes) { void* r = (void*)p; p += (bytes + 255) & ~(size_t)255; return r; };
    int*     bcount = (int*)alloc((size_t)nbk * 16 * 4);
    int*     boffs  = (int*)alloc((size_t)(nbk + 1) * 4);
    int*     bcur   = (int*)alloc((size_t)nbk * 16 * 4);
    int*     btmp   = (int*)alloc((size_t)e * 4);
    int*     csr    = (int*)alloc((size_t)e * 4);
    int*     offs   = (int*)alloc((size_t)(n + 1) * 4);
    float*   dinv   = (float*)alloc((size_t)n * 4);
    float*   h      = (float*)alloc((size_t)n * HID * 4);
    __half2* th     = (__half2*)alloc((size_t)n * HID * 2);
    float*   agg    = (float*)alloc((size_t)n * HID * 4);
    float*   tf     = (float*)alloc((size_t)n * 32 * 4);
    float*   bnS    = (float*)alloc(NSTRIPE * 128 * 4);
    float*   bnSS   = (float*)alloc(NSTRIPE * 128 * 4);
    float*   bnA    = (float*)alloc(HID * 4);
    float*   bnC    = (float*)alloc(HID * 4);

    hipMemsetAsync(bcount, 0, (size_t)nbk * 16 * 4, stream);
    k_bhist<<<(e + 4095) / 4096, 256, 0, stream>>>(dstp, bcount, e, nbk);
    k_bscan<<<1, 1024, 0, stream>>>(bcount, boffs, bcur, nbk, e);
    k_bscatter<<<256, 1024, 0, stream>>>(srcp, dstp, bcur, btmp, e, nbk);
    k_bsort<<<nbk, 256, 0, stream>>>(btmp, boffs, csr, offs, dinv, n, e);
    k_embed<<<(n * HID + 255) / 256, 256, 0, stream>>>(x, We, be, h, n);

    // layer 1
    k_gemm128<<<(n + 63) / 64, 256, 0, stream>>>(h, W1, dinv, th, n);
    hipMemsetAsync(bnS, 0, NSTRIPE * 128 * 4, stream);
    hipMemsetAsync(bnSS, 0, NSTRIPE * 128 * 4, stream);
    k_agg<<<4096, 256, 0, stream>>>(th, offs, csr, dinv, b1, agg, bnS, bnSS, n);
    k_bn_finalize<<<1, 128, 0, stream>>>(bnS, bnSS, g1, bt1, bnA, bnC, n, 128, NSTRIPE);

    // layer 2 (gemm fused with layer-1 bn-apply+relu+residual)
    k_gemm128f<<<(n + 63) / 64, 256, 0, stream>>>(agg, h, bnA, bnC, W2, dinv, th, n);
    hipMemsetAsync(bnS, 0, NSTRIPE * 128 * 4, stream);
    hipMemsetAsync(bnSS, 0, NSTRIPE * 128 * 4, stream);
    k_agg<<<4096, 256, 0, stream>>>(th, offs, csr, dinv, b2, agg, bnS, bnSS, n);
    k_bn_finalize<<<1, 128, 0, stream>>>(bnS, bnSS, g2, bt2, bnA, bnC, n, 128, NSTRIPE);

    // layer 3
    k_gemm128f<<<(n + 63) / 64, 256, 0, stream>>>(agg, h, bnA, bnC, W3, dinv, th, n);
    hipMemsetAsync(bnS, 0, NSTRIPE * 128 * 4, stream);
    hipMemsetAsync(bnSS, 0, NSTRIPE * 128 * 4, stream);
    k_agg<<<4096, 256, 0, stream>>>(th, offs, csr, dinv, b3, agg, bnS, bnSS, n);
    k_bn_finalize<<<1, 128, 0, stream>>>(bnS, bnSS, g3, bt3, bnA, bnC, n, 128, NSTRIPE);

    // head (gemm fused with layer-3 bn-apply+relu+residual AND head-BN stats)
    hipMemsetAsync(bnS, 0, NSTRIPE * 128 * 4, stream);
    hipMemsetAsync(bnSS, 0, NSTRIPE * 128 * 4, stream);
    k_gemmff<<<(n + 63) / 64, 256, 0, stream>>>(agg, h, bnA, bnC, Wf1, bf1, tf, bnS, bnSS, n);
    k_bn_finalize<<<1, 32, 0, stream>>>(bnS, bnSS, gf, btf, bnA, bnC, n, 32, NSTRIPE);
    k_final<<<(n + 255) / 256, 256, 0, stream>>>(tf, bnA, bnC, Wf2, bf2, out, n);
}

// Round 10
// 566.016 us; speedup vs baseline: 1.6914x; 1.1957x over previous
//
#include <hip/hip_runtime.h>
#include <hip/hip_fp16.h>
#include <math.h>

#define HID 128
#define EPS 1e-5f
#define BK 64          // dst nodes per bucket
#define MAXNBK 2048    // supports n <= 131072
#define NSTRIPE 16     // BN-stats atomic striping
#define PADK 136       // fp16 LDS row stride (128 + 8 halves): 68 words %32 = 4 -> conflict-free

typedef _Float16 half8 __attribute__((ext_vector_type(8)));
typedef float f32x4 __attribute__((ext_vector_type(4)));

// ---------------- bucketed graph preprocessing ----------------
// btmp entry: (src << 6) | (dst & 63)

__global__ __launch_bounds__(256) void k_bhist(const int* __restrict__ dst, int* __restrict__ bcount,
                                               int e, int nbk) {
    __shared__ int hist[MAXNBK];
    for (int i = threadIdx.x; i < nbk; i += 256) hist[i] = 0;
    __syncthreads();
    int base = blockIdx.x * 4096;
    int end = min(base + 4096, e);
    for (int i = base + threadIdx.x; i < end; i += 256) atomicAdd(&hist[dst[i] >> 6], 1);
    __syncthreads();
    for (int i = threadIdx.x; i < nbk; i += 256) {
        int c = hist[i];
        if (c) atomicAdd(&bcount[i * 16], c);
    }
}

__global__ __launch_bounds__(1024) void k_bscan(const int* __restrict__ bcount, int* __restrict__ boffs,
                                                int* __restrict__ bcur, int nbk, int e) {
    __shared__ int lds[1024];
    int tid = threadIdx.x;
    int i0 = 2 * tid, i1 = 2 * tid + 1;
    int a = (i0 < nbk) ? bcount[i0 * 16] : 0;
    int b = (i1 < nbk) ? bcount[i1 * 16] : 0;
    lds[tid] = a + b;
    __syncthreads();
    for (int off = 1; off < 1024; off <<= 1) {
        int v = (tid >= off) ? lds[tid - off] : 0;
        __syncthreads();
        lds[tid] += v;
        __syncthreads();
    }
    int excl = lds[tid] - (a + b);
    if (i0 < nbk) { boffs[i0] = excl;     bcur[i0 * 16] = excl; }
    if (i1 < nbk) { boffs[i1] = excl + a; bcur[i1 * 16] = excl + a; }
    if (tid == 1023) boffs[nbk] = e;
}

__global__ __launch_bounds__(1024) void k_bscatter(const int* __restrict__ src, const int* __restrict__ dst,
                                                   int* __restrict__ bcur, int* __restrict__ btmp,
                                                   int e, int nbk) {
    __shared__ int hist[MAXNBK];
    int tid = threadIdx.x;
    for (int i = tid; i < nbk; i += 1024) hist[i] = 0;
    __syncthreads();
    int per = (e + gridDim.x - 1) / gridDim.x;
    int base = blockIdx.x * per;
    int end = min(base + per, e);
    for (int i = base + tid; i < end; i += 1024) atomicAdd(&hist[dst[i] >> 6], 1);
    __syncthreads();
    for (int i = tid; i < nbk; i += 1024) {
        int c = hist[i];
        hist[i] = c ? atomicAdd(&bcur[i * 16], c) : 0;
    }
    __syncthreads();
    for (int i = base + tid; i < end; i += 1024) {
        int d = dst[i];
        int pos = atomicAdd(&hist[d >> 6], 1);          // LDS int atomic (native)
        btmp[pos] = (src[i] << 6) | (d & 63);
    }
}

__global__ __launch_bounds__(256) void k_bsort(const int* __restrict__ btmp, const int* __restrict__ boffs,
                                               int* __restrict__ csr, int* __restrict__ offs,
                                               float* __restrict__ dinv, int n, int etot) {
    __shared__ int cnt[BK];
    __shared__ int cur[BK];
    int b = blockIdx.x, tid = threadIdx.x;
    if (tid < BK) cnt[tid] = 0;
    __syncthreads();
    int e0 = boffs[b], e1 = boffs[b + 1];
    for (int i = e0 + tid; i < e1; i += 256) atomicAdd(&cnt[btmp[i] & 63], 1);
    __syncthreads();
    if (tid == 0) {
        int run = 0;
        for (int d = 0; d < BK; ++d) { cur[d] = run; run += cnt[d]; }
    }
    __syncthreads();
    if (tid < BK) {
        int node = b * BK + tid;
        if (node < n) {
            offs[node] = e0 + cur[tid];
            dinv[node] = rsqrtf((float)(cnt[tid] + 1));  // +1 self-loop
        }
    }
    if (b == 0 && tid == 0) offs[n] = etot;
    __syncthreads();
    for (int i = e0 + tid; i < e1; i += 256) {
        int p = btmp[i];
        int pos = e0 + atomicAdd(&cur[p & 63], 1);
        csr[pos] = p >> 6;
    }
}

// ---------------- weight transpose to fp16 (done once; consumed by MFMA B-staging) ----

__global__ void k_prepw(const float* __restrict__ W, _Float16* __restrict__ Wt) {
    int idx = blockIdx.x * 256 + threadIdx.x;   // 128*128
    int k = idx >> 7, nn = idx & 127;
    Wt[nn * 128 + k] = (_Float16)W[k * 128 + nn];
}

__global__ void k_prepwf(const float* __restrict__ W, _Float16* __restrict__ Wt) {
    int idx = blockIdx.x * 256 + threadIdx.x;   // 128*32
    int k = idx >> 5, nn = idx & 31;
    Wt[nn * 128 + k] = (_Float16)W[k * 32 + nn];
}

// ---------------- embed: h = relu(x @ We + be), x is [N,2] ----------------

__global__ void k_embed(const float* __restrict__ x, const float* __restrict__ We,
                        const float* __restrict__ be, float* __restrict__ h, int n) {
    int i = blockIdx.x * 256 + threadIdx.x;
    if (i >= n * HID) return;
    int node = i >> 7, j = i & 127;
    float v = x[2 * node] * We[j] + x[2 * node + 1] * We[HID + j] + be[j];
    h[i] = fmaxf(v, 0.f);
}

// ---------------- MFMA GEMM, layer 1: th = fp16(dinv * (h @ W)) -----------------------
// 64 nodes/block. Wave w: m-strip of 16 nodes, all 8 n-tiles, K = 4 chunks of 32.
// Frag layouts (gfx950 16x16x32): A[m=lane&15][k=quad*8+j]; D: col=lane&15,row=quad*4+reg.

__global__ __launch_bounds__(256) void k_mm1(const float* __restrict__ h, const _Float16* __restrict__ Wt,
                                             const float* __restrict__ dinv, __half2* __restrict__ th, int n) {
    __shared__ __attribute__((aligned(16))) _Float16 Ah[64][PADK];
    __shared__ __attribute__((aligned(16))) _Float16 Bh[128][PADK];
    int tid = threadIdx.x;
    int nb = blockIdx.x * 64;
    const float4* h4 = (const float4*)h;
#pragma unroll
    for (int r = 0; r < 8; ++r) {
        int idx = r * 256 + tid;
        int ni = idx >> 5, k4 = idx & 31;
        int node = nb + ni;
        float4 v = make_float4(0.f, 0.f, 0.f, 0.f);
        if (node < n) v = h4[(size_t)node * 32 + k4];
        union { __half2 h2[2]; uint2 u; } pk;
        pk.h2[0] = __floats2half2_rn(v.x, v.y);
        pk.h2[1] = __floats2half2_rn(v.z, v.w);
        *(uint2*)&Ah[ni][k4 * 4] = pk.u;
    }
    const uint4* wt4 = (const uint4*)Wt;
#pragma unroll
    for (int r = 0; r < 8; ++r) {
        int idx = r * 256 + tid;
        int row = idx >> 4, ch = idx & 15;
        *(uint4*)&Bh[row][ch * 8] = wt4[row * 16 + ch];
    }
    __syncthreads();
    int lane = tid & 63, w = tid >> 6;
    int mrow = lane & 15, quad = lane >> 4;
    f32x4 acc[8];
#pragma unroll
    for (int t = 0; t < 8; ++t) acc[t] = (f32x4){0.f, 0.f, 0.f, 0.f};
#pragma unroll
    for (int kc = 0; kc < 4; ++kc) {
        half8 av = *(half8*)&Ah[w * 16 + mrow][kc * 32 + quad * 8];
#pragma unroll
        for (int t = 0; t < 8; ++t) {
            half8 bv = *(half8*)&Bh[t * 16 + mrow][kc * 32 + quad * 8];
            acc[t] = __builtin_amdgcn_mfma_f32_16x16x32_f16(av, bv, acc[t], 0, 0, 0);
        }
    }
    float dv[4];
#pragma unroll
    for (int r = 0; r < 4; ++r) {
        int node = nb + w * 16 + quad * 4 + r;
        dv[r] = (node < n) ? dinv[node] : 0.f;
    }
    __syncthreads();   // Ah reads done; reuse as output repack tile
#pragma unroll
    for (int t = 0; t < 8; ++t)
#pragma unroll
        for (int r = 0; r < 4; ++r)
            Ah[w * 16 + quad * 4 + r][t * 16 + mrow] = (_Float16)(acc[t][r] * dv[r]);
    __syncthreads();
#pragma unroll
    for (int it = 0; it < 4; ++it) {
        int idx = it * 256 + tid;
        int row = idx >> 4, ch = idx & 15;
        int node = nb + row;
        if (node < n)
            ((uint4*)th)[(size_t)node * 16 + ch] = *(uint4*)&Ah[row][ch * 8];
    }
}

// ---------------- MFMA GEMM fused with BN-apply+ReLU+residual (layers 2,3) ------------
// h_new = relu(agg*A+C)+h_old (written back fp32), staged fp16 -> MFMA -> th.

__global__ __launch_bounds__(256) void k_mmf(const float* __restrict__ agg, float* __restrict__ h,
                                             const float* __restrict__ A, const float* __restrict__ Cc,
                                             const _Float16* __restrict__ Wt, const float* __restrict__ dinv,
                                             __half2* __restrict__ th, int n) {
    __shared__ __attribute__((aligned(16))) _Float16 Ah[64][PADK];
    __shared__ __attribute__((aligned(16))) _Float16 Bh[128][PADK];
    __shared__ float As[128], Cs[128];
    int tid = threadIdx.x;
    int nb = blockIdx.x * 64;
    if (tid < 128) { As[tid] = A[tid]; Cs[tid] = Cc[tid]; }
    __syncthreads();
    const float4* a4p = (const float4*)agg;
    float4* h4 = (float4*)h;
#pragma unroll
    for (int r = 0; r < 8; ++r) {
        int idx = r * 256 + tid;
        int ni = idx >> 5, k4 = idx & 31;
        int node = nb + ni;
        float4 v = make_float4(0.f, 0.f, 0.f, 0.f);
        if (node < n) {
            float4 a = a4p[(size_t)node * 32 + k4];
            float4 ho = h4[(size_t)node * 32 + k4];
            float4 aa = *((const float4*)&As[k4 * 4]);
            float4 cc = *((const float4*)&Cs[k4 * 4]);
            v.x = fmaxf(a.x * aa.x + cc.x, 0.f) + ho.x;
            v.y = fmaxf(a.y * aa.y + cc.y, 0.f) + ho.y;
            v.z = fmaxf(a.z * aa.z + cc.z, 0.f) + ho.z;
            v.w = fmaxf(a.w * aa.w + cc.w, 0.f) + ho.w;
            h4[(size_t)node * 32 + k4] = v;   // in-place: element owned by one thread
        }
        union { __half2 h2[2]; uint2 u; } pk;
        pk.h2[0] = __floats2half2_rn(v.x, v.y);
        pk.h2[1] = __floats2half2_rn(v.z, v.w);
        *(uint2*)&Ah[ni][k4 * 4] = pk.u;
    }
    const uint4* wt4 = (const uint4*)Wt;
#pragma unroll
    for (int r = 0; r < 8; ++r) {
        int idx = r * 256 + tid;
        int row = idx >> 4, ch = idx & 15;
        *(uint4*)&Bh[row][ch * 8] = wt4[row * 16 + ch];
    }
    __syncthreads();
    int lane = tid & 63, w = tid >> 6;
    int mrow = lane & 15, quad = lane >> 4;
    f32x4 acc[8];
#pragma unroll
    for (int t = 0; t < 8; ++t) acc[t] = (f32x4){0.f, 0.f, 0.f, 0.f};
#pragma unroll
    for (int kc = 0; kc < 4; ++kc) {
        half8 av = *(half8*)&Ah[w * 16 + mrow][kc * 32 + quad * 8];
#pragma unroll
        for (int t = 0; t < 8; ++t) {
            half8 bv = *(half8*)&Bh[t * 16 + mrow][kc * 32 + quad * 8];
            acc[t] = __builtin_amdgcn_mfma_f32_16x16x32_f16(av, bv, acc[t], 0, 0, 0);
        }
    }
    float dv[4];
#pragma unroll
    for (int r = 0; r < 4; ++r) {
        int node = nb + w * 16 + quad * 4 + r;
        dv[r] = (node < n) ? dinv[node] : 0.f;
    }
    __syncthreads();
#pragma unroll
    for (int t = 0; t < 8; ++t)
#pragma unroll
        for (int r = 0; r < 4; ++r)
            Ah[w * 16 + quad * 4 + r][t * 16 + mrow] = (_Float16)(acc[t][r] * dv[r]);
    __syncthreads();
#pragma unroll
    for (int it = 0; it < 4; ++it) {
        int idx = it * 256 + tid;
        int row = idx >> 4, ch = idx & 15;
        int node = nb + row;
        if (node < n)
            ((uint4*)th)[(size_t)node * 16 + ch] = *(uint4*)&Ah[row][ch * 8];
    }
}

// ---------------- MFMA head GEMM: BN-apply+ReLU+residual -> @Wf1+bf1 -> tf + stats ----

__global__ __launch_bounds__(256) void k_mmh(const float* __restrict__ agg, const float* __restrict__ h,
                                             const float* __restrict__ A, const float* __restrict__ Cc,
                                             const _Float16* __restrict__ Wt, const float* __restrict__ bias,
                                             float* __restrict__ tf,
                                             float* __restrict__ S, float* __restrict__ SS, int n) {
    __shared__ __attribute__((aligned(16))) _Float16 Ah[64][PADK];
    __shared__ __attribute__((aligned(16))) _Float16 Bh[32][PADK];
    __shared__ float Ds[64][36];
    __shared__ float As[128], Cs[128];
    __shared__ float sredS[4][8][4], sredQ[4][8][4];
    int tid = threadIdx.x;
    int nb = blockIdx.x * 64;
    if (tid < 128) { As[tid] = A[tid]; Cs[tid] = Cc[tid]; }
    __syncthreads();
    const float4* a4p = (const float4*)agg;
    const float4* h4 = (const float4*)h;
#pragma unroll
    for (int r = 0; r < 8; ++r) {
        int idx = r * 256 + tid;
        int ni = idx >> 5, k4 = idx & 31;
        int node = nb + ni;
        float4 v = make_float4(0.f, 0.f, 0.f, 0.f);
        if (node < n) {
            float4 a = a4p[(size_t)node * 32 + k4];
            float4 ho = h4[(size_t)node * 32 + k4];
            float4 aa = *((const float4*)&As[k4 * 4]);
            float4 cc = *((const float4*)&Cs[k4 * 4]);
            v.x = fmaxf(a.x * aa.x + cc.x, 0.f) + ho.x;
            v.y = fmaxf(a.y * aa.y + cc.y, 0.f) + ho.y;
            v.z = fmaxf(a.z * aa.z + cc.z, 0.f) + ho.z;
            v.w = fmaxf(a.w * aa.w + cc.w, 0.f) + ho.w;
        }
        union { __half2 h2[2]; uint2 u; } pk;
        pk.h2[0] = __floats2half2_rn(v.x, v.y);
        pk.h2[1] = __floats2half2_rn(v.z, v.w);
        *(uint2*)&Ah[ni][k4 * 4] = pk.u;
    }
    const uint4* wt4 = (const uint4*)Wt;
#pragma unroll
    for (int r = 0; r < 2; ++r) {
        int idx = r * 256 + tid;
        int row = idx >> 4, ch = idx & 15;
        *(uint4*)&Bh[row][ch * 8] = wt4[row * 16 + ch];
    }
    __syncthreads();
    int lane = tid & 63, w = tid >> 6;
    int mrow = lane & 15, quad = lane >> 4;
    f32x4 acc[2];
    acc[0] = (f32x4){0.f, 0.f, 0.f, 0.f};
    acc[1] = (f32x4){0.f, 0.f, 0.f, 0.f};
#pragma unroll
    for (int kc = 0; kc < 4; ++kc) {
        half8 av = *(half8*)&Ah[w * 16 + mrow][kc * 32 + quad * 8];
#pragma unroll
        for (int t = 0; t < 2; ++t) {
            half8 bv = *(half8*)&Bh[t * 16 + mrow][kc * 32 + quad * 8];
            acc[t] = __builtin_amdgcn_mfma_f32_16x16x32_f16(av, bv, acc[t], 0, 0, 0);
        }
    }
#pragma unroll
    for (int t = 0; t < 2; ++t)
#pragma unroll
        for (int r = 0; r < 4; ++r)
            Ds[w * 16 + quad * 4 + r][t * 16 + mrow] = acc[t][r];
    __syncthreads();
    // readout + bias + stats: 2 iters, thread covers rows idx>>3, feats (idx&7)*4..+3
    float ps0 = 0.f, ps1 = 0.f, ps2 = 0.f, ps3 = 0.f;
    float pq0 = 0.f, pq1 = 0.f, pq2 = 0.f, pq3 = 0.f;
    int c4 = tid & 7;
    float4 bb = ((const float4*)bias)[c4];
#pragma unroll
    for (int it = 0; it < 2; ++it) {
        int idx = it * 256 + tid;
        int row = idx >> 3;
        int node = nb + row;
        if (node < n) {
            float v0 = Ds[row][c4 * 4 + 0] + bb.x;
            float v1 = Ds[row][c4 * 4 + 1] + bb.y;
            float v2 = Ds[row][c4 * 4 + 2] + bb.z;
            float v3 = Ds[row][c4 * 4 + 3] + bb.w;
            *((float4*)&tf[(size_t)node * 32 + c4 * 4]) = make_float4(v0, v1, v2, v3);
            ps0 += v0; ps1 += v1; ps2 += v2; ps3 += v3;
            pq0 += v0 * v0; pq1 += v1 * v1; pq2 += v2 * v2; pq3 += v3 * v3;
        }
    }
#pragma unroll
    for (int off = 8; off < 64; off <<= 1) {
        ps0 += __shfl_down(ps0, off); ps1 += __shfl_down(ps1, off);
        ps2 += __shfl_down(ps2, off); ps3 += __shfl_down(ps3, off);
        pq0 += __shfl_down(pq0, off); pq1 += __shfl_down(pq1, off);
        pq2 += __shfl_down(pq2, off); pq3 += __shfl_down(pq3, off);
    }
    if (lane < 8) {
        sredS[w][lane][0] = ps0; sredS[w][lane][1] = ps1; sredS[w][lane][2] = ps2; sredS[w][lane][3] = ps3;
        sredQ[w][lane][0] = pq0; sredQ[w][lane][1] = pq1; sredQ[w][lane][2] = pq2; sredQ[w][lane][3] = pq3;
    }
    __syncthreads();
    if (tid < 32) {
        int cc4 = tid >> 2, j = tid & 3;
        float s = sredS[0][cc4][j] + sredS[1][cc4][j] + sredS[2][cc4][j] + sredS[3][cc4][j];
        float q = sredQ[0][cc4][j] + sredQ[1][cc4][j] + sredQ[2][cc4][j] + sredQ[3][cc4][j];
        int stripe = (blockIdx.x & (NSTRIPE - 1)) * 128;
        atomicAdd(&S[stripe + tid], s);
        atomicAdd(&SS[stripe + tid], q);
    }
}

// ---------------- aggregation + fused BN stats (unchanged from R8) --------------------

__global__ __launch_bounds__(256) void k_agg(const __half2* __restrict__ t, const int* __restrict__ offs,
                                             const int* __restrict__ csr, const float* __restrict__ dinv,
                                             const float* __restrict__ bias, float* __restrict__ out,
                                             float* __restrict__ S, float* __restrict__ SS, int n) {
    __shared__ float ls[4][128];
    __shared__ float lss[4][128];
    int tid = threadIdx.x;
    int lane = tid & 63, w = tid >> 6;
    int sub = lane >> 5, fl = lane & 31;
    const uint2* t4 = (const uint2*)t;
    float4 bb = ((const float4*)bias)[fl];
    float s0 = 0.f, s1 = 0.f, s2 = 0.f, s3 = 0.f;
    float q0 = 0.f, q1 = 0.f, q2 = 0.f, q3 = 0.f;
    float selfm = (sub == 0) ? 1.f : 0.f;
    int ngrp = (n + 3) >> 2;
    for (int grp = blockIdx.x; grp < ngrp; grp += gridDim.x) {
        int node = grp * 4 + w;
        if (node < n) {
            uint2 rv = t4[(size_t)node * 32 + fl];
            float2 f0 = __half22float2(*(__half2*)&rv.x);
            float2 f1 = __half22float2(*(__half2*)&rv.y);
            float a0 = f0.x * selfm, a1 = f0.y * selfm, a2 = f1.x * selfm, a3 = f1.y * selfm;
            int e0 = offs[node], e1 = offs[node + 1];
            for (int e = e0; e < e1; e += 8) {
                int i0 = e + sub, i1 = e + 2 + sub, i2 = e + 4 + sub, i3 = e + 6 + sub;
                int c0 = csr[min(i0, e1 - 1)];
                int c1 = csr[min(i1, e1 - 1)];
                int c2 = csr[min(i2, e1 - 1)];
                int c3 = csr[min(i3, e1 - 1)];
                uint2 r0 = t4[(size_t)c0 * 32 + fl];
                uint2 r1 = t4[(size_t)c1 * 32 + fl];
                uint2 r2 = t4[(size_t)c2 * 32 + fl];
                uint2 r3 = t4[(size_t)c3 * 32 + fl];
                float m0 = (i0 < e1) ? 1.f : 0.f;
                float m1 = (i1 < e1) ? 1.f : 0.f;
                float m2 = (i2 < e1) ? 1.f : 0.f;
                float m3 = (i3 < e1) ? 1.f : 0.f;
                float2 g0 = __half22float2(*(__half2*)&r0.x), g1 = __half22float2(*(__half2*)&r0.y);
                a0 += m0 * g0.x; a1 += m0 * g0.y; a2 += m0 * g1.x; a3 += m0 * g1.y;
                g0 = __half22float2(*(__half2*)&r1.x); g1 = __half22float2(*(__half2*)&r1.y);
                a0 += m1 * g0.x; a1 += m1 * g0.y; a2 += m1 * g1.x; a3 += m1 * g1.y;
                g0 = __half22float2(*(__half2*)&r2.x); g1 = __half22float2(*(__half2*)&r2.y);
                a0 += m2 * g0.x; a1 += m2 * g0.y; a2 += m2 * g1.x; a3 += m2 * g1.y;
                g0 = __half22float2(*(__half2*)&r3.x); g1 = __half22float2(*(__half2*)&r3.y);
                a0 += m3 * g0.x; a1 += m3 * g0.y; a2 += m3 * g1.x; a3 += m3 * g1.y;
            }
            a0 += __shfl_down(a0, 32);
            a1 += __shfl_down(a1, 32);
            a2 += __shfl_down(a2, 32);
            a3 += __shfl_down(a3, 32);
            if (sub == 0) {
                float di = dinv[node];
                float v0 = a0 * di + bb.x, v1 = a1 * di + bb.y;
                float v2 = a2 * di + bb.z, v3 = a3 * di + bb.w;
                ((float4*)out)[(size_t)node * 32 + fl] = make_float4(v0, v1, v2, v3);
                s0 += v0; s1 += v1; s2 += v2; s3 += v3;
                q0 += v0 * v0; q1 += v1 * v1; q2 += v2 * v2; q3 += v3 * v3;
            }
        }
    }
    if (sub == 0) {
        ((float4*)&ls[w][0])[fl] = make_float4(s0, s1, s2, s3);
        ((float4*)&lss[w][0])[fl] = make_float4(q0, q1, q2, q3);
    }
    __syncthreads();
    if (tid < 128) {
        float s = ls[0][tid] + ls[1][tid] + ls[2][tid] + ls[3][tid];
        float q = lss[0][tid] + lss[1][tid] + lss[2][tid] + lss[3][tid];
        int stripe = (blockIdx.x & (NSTRIPE - 1)) * 128;
        atomicAdd(&S[stripe + tid], s);
        atomicAdd(&SS[stripe + tid], q);
    }
}

// ---------------- BN finalize (nstripe copies, stride 128) ----------------

__global__ void k_bn_finalize(const float* __restrict__ S, const float* __restrict__ SS,
                              const float* __restrict__ g, const float* __restrict__ bt,
                              float* __restrict__ A, float* __restrict__ C, int n, int hid, int nstripe) {
    int j = threadIdx.x;
    if (j >= hid) return;
    float s = 0.f, q = 0.f;
    for (int k = 0; k < nstripe; ++k) { s += S[k * 128 + j]; q += SS[k * 128 + j]; }
    float mu = s / (float)n;
    float var = q / (float)n - mu * mu;
    float inv = rsqrtf(var + EPS);
    A[j] = g[j] * inv;
    C[j] = bt[j] - mu * g[j] * inv;
}

// ---------------- final: out = tanh(relu(bn(tf)) @ Wf2 + bf2) ----------------

__global__ void k_final(const float* __restrict__ tf, const float* __restrict__ A,
                        const float* __restrict__ C, const float* __restrict__ Wf2,
                        const float* __restrict__ bf2, float* __restrict__ out, int n) {
    int node = blockIdx.x * 256 + threadIdx.x;
    if (node >= n) return;
    float o0 = bf2[0], o1 = bf2[1];
    const float4* t4 = (const float4*)(tf + (size_t)node * 32);
#pragma unroll
    for (int q = 0; q < 8; ++q) {
        float4 v = t4[q];
        float vv[4] = {v.x, v.y, v.z, v.w};
#pragma unroll
        for (int r = 0; r < 4; ++r) {
            int j = q * 4 + r;
            float f = fmaxf(vv[r] * A[j] + C[j], 0.f);
            o0 += f * Wf2[2 * j];
            o1 += f * Wf2[2 * j + 1];
        }
    }
    out[2 * node] = tanhf(o0);
    out[2 * node + 1] = tanhf(o1);
}

// ---------------- launch ----------------

extern "C" void kernel_launch(void* const* d_in, const int* in_sizes, int n_in,
                              void* d_out, int out_size, void* d_ws, size_t ws_size,
                              hipStream_t stream) {
    const float* x   = (const float*)d_in[0];
    const int*   ei  = (const int*)d_in[1];
    const float* We  = (const float*)d_in[2];
    const float* be  = (const float*)d_in[3];
    const float* W1  = (const float*)d_in[4];
    const float* b1  = (const float*)d_in[5];
    const float* g1  = (const float*)d_in[6];
    const float* bt1 = (const float*)d_in[7];
    const float* W2  = (const float*)d_in[8];
    const float* b2  = (const float*)d_in[9];
    const float* g2  = (const float*)d_in[10];
    const float* bt2 = (const float*)d_in[11];
    const float* W3  = (const float*)d_in[12];
    const float* b3  = (const float*)d_in[13];
    const float* g3  = (const float*)d_in[14];
    const float* bt3 = (const float*)d_in[15];
    const float* Wf1 = (const float*)d_in[16];
    const float* bf1 = (const float*)d_in[17];
    const float* gf  = (const float*)d_in[18];
    const float* btf = (const float*)d_in[19];
    const float* Wf2 = (const float*)d_in[20];
    const float* bf2 = (const float*)d_in[21];
    float* out = (float*)d_out;

    const int n = in_sizes[0] / 2;      // x is [N,2]
    const int e = in_sizes[1] / 2;      // edge_index is [2,E]
    const int* srcp = ei;
    const int* dstp = ei + e;
    const int nbk = (n + BK - 1) / BK;

    char* p = (char*)d_ws;
    auto alloc = [&](size_t bytes) { void* r = (void*)p; p += (bytes + 255) & ~(size_t)255; return r; };
    int*       bcount = (int*)alloc((size_t)nbk * 16 * 4);
    int*       boffs  = (int*)alloc((size_t)(nbk + 1) * 4);
    int*       bcur   = (int*)alloc((size_t)nbk * 16 * 4);
    int*       btmp   = (int*)alloc((size_t)e * 4);
    int*       csr    = (int*)alloc((size_t)e * 4);
    int*       offs   = (int*)alloc((size_t)(n + 1) * 4);
    float*     dinv   = (float*)alloc((size_t)n * 4);
    float*     h      = (float*)alloc((size_t)n * HID * 4);
    __half2*   th     = (__half2*)alloc((size_t)n * HID * 2);
    float*     agg    = (float*)alloc((size_t)n * HID * 4);
    float*     tf     = (float*)alloc((size_t)n * 32 * 4);
    float*     bnS    = (float*)alloc(NSTRIPE * 128 * 4);
    float*     bnSS   = (float*)alloc(NSTRIPE * 128 * 4);
    float*     bnA    = (float*)alloc(HID * 4);
    float*     bnC    = (float*)alloc(HID * 4);
    _Float16*  wt1    = (_Float16*)alloc(128 * 128 * 2);
    _Float16*  wt2    = (_Float16*)alloc(128 * 128 * 2);
    _Float16*  wt3    = (_Float16*)alloc(128 * 128 * 2);
    _Float16*  wtf    = (_Float16*)alloc(32 * 128 * 2);

    hipMemsetAsync(bcount, 0, (size_t)nbk * 16 * 4, stream);
    k_bhist<<<(e + 4095) / 4096, 256, 0, stream>>>(dstp, bcount, e, nbk);
    k_bscan<<<1, 1024, 0, stream>>>(bcount, boffs, bcur, nbk, e);
    k_bscatter<<<256, 1024, 0, stream>>>(srcp, dstp, bcur, btmp, e, nbk);
    k_bsort<<<nbk, 256, 0, stream>>>(btmp, boffs, csr, offs, dinv, n, e);
    k_prepw<<<64, 256, 0, stream>>>(W1, wt1);
    k_prepw<<<64, 256, 0, stream>>>(W2, wt2);
    k_prepw<<<64, 256, 0, stream>>>(W3, wt3);
    k_prepwf<<<16, 256, 0, stream>>>(Wf1, wtf);
    k_embed<<<(n * HID + 255) / 256, 256, 0, stream>>>(x, We, be, h, n);

    // layer 1
    k_mm1<<<(n + 63) / 64, 256, 0, stream>>>(h, wt1, dinv, th, n);
    hipMemsetAsync(bnS, 0, NSTRIPE * 128 * 4, stream);
    hipMemsetAsync(bnSS, 0, NSTRIPE * 128 * 4, stream);
    k_agg<<<4096, 256, 0, stream>>>(th, offs, csr, dinv, b1, agg, bnS, bnSS, n);
    k_bn_finalize<<<1, 128, 0, stream>>>(bnS, bnSS, g1, bt1, bnA, bnC, n, 128, NSTRIPE);

    // layer 2
    k_mmf<<<(n + 63) / 64, 256, 0, stream>>>(agg, h, bnA, bnC, wt2, dinv, th, n);
    hipMemsetAsync(bnS, 0, NSTRIPE * 128 * 4, stream);
    hipMemsetAsync(bnSS, 0, NSTRIPE * 128 * 4, stream);
    k_agg<<<4096, 256, 0, stream>>>(th, offs, csr, dinv, b2, agg, bnS, bnSS, n);
    k_bn_finalize<<<1, 128, 0, stream>>>(bnS, bnSS, g2, bt2, bnA, bnC, n, 128, NSTRIPE);

    // layer 3
    k_mmf<<<(n + 63) / 64, 256, 0, stream>>>(agg, h, bnA, bnC, wt3, dinv, th, n);
    hipMemsetAsync(bnS, 0, NSTRIPE * 128 * 4, stream);
    hipMemsetAsync(bnSS, 0, NSTRIPE * 128 * 4, stream);
    k_agg<<<4096, 256, 0, stream>>>(th, offs, csr, dinv, b3, agg, bnS, bnSS, n);
    k_bn_finalize<<<1, 128, 0, stream>>>(bnS, bnSS, g3, bt3, bnA, bnC, n, 128, NSTRIPE);

    // head (MFMA gemm fused with layer-3 bn-apply+relu+residual AND head-BN stats)
    hipMemsetAsync(bnS, 0, NSTRIPE * 128 * 4, stream);
    hipMemsetAsync(bnSS, 0, NSTRIPE * 128 * 4, stream);
    k_mmh<<<(n + 63) / 64, 256, 0, stream>>>(agg, h, bnA, bnC, wtf, bf1, tf, bnS, bnSS, n);
    k_bn_finalize<<<1, 32, 0, stream>>>(bnS, bnSS, gf, btf, bnA, bnC, n, 32, NSTRIPE);
    k_final<<<(n + 255) / 256, 256, 0, stream>>>(tf, bnA, bnC, Wf2, bf2, out, n);
}

// Round 11
// 533.261 us; speedup vs baseline: 1.7953x; 1.0614x over previous
//
#include <hip/hip_runtime.h>
#include <hip/hip_fp16.h>
#include <math.h>

#define HID 128
#define EPS 1e-5f
#define BK 64          // dst nodes per bucket
#define MAXNBK 2048    // supports n <= 131072
#define NSTRIPE 16     // BN-stats atomic striping
#define PADK 136       // fp16 LDS row stride: 68 words % 32 = 4 -> conflict-free MFMA frag reads

typedef _Float16 half8 __attribute__((ext_vector_type(8)));
typedef float f32x4 __attribute__((ext_vector_type(4)));

// ---------------- bucketed graph preprocessing ----------------
// btmp entry: (src << 6) | (dst & 63)

__global__ __launch_bounds__(256) void k_bhist(const int* __restrict__ dst, int* __restrict__ bcount,
                                               int e, int nbk) {
    __shared__ int hist[MAXNBK];
    for (int i = threadIdx.x; i < nbk; i += 256) hist[i] = 0;
    __syncthreads();
    int base = blockIdx.x * 4096;
    int end = min(base + 4096, e);
    for (int i = base + threadIdx.x; i < end; i += 256) atomicAdd(&hist[dst[i] >> 6], 1);
    __syncthreads();
    for (int i = threadIdx.x; i < nbk; i += 256) {
        int c = hist[i];
        if (c) atomicAdd(&bcount[i * 16], c);
    }
}

__global__ __launch_bounds__(1024) void k_bscan(const int* __restrict__ bcount, int* __restrict__ boffs,
                                                int* __restrict__ bcur, int nbk, int e) {
    __shared__ int lds[1024];
    int tid = threadIdx.x;
    int i0 = 2 * tid, i1 = 2 * tid + 1;
    int a = (i0 < nbk) ? bcount[i0 * 16] : 0;
    int b = (i1 < nbk) ? bcount[i1 * 16] : 0;
    lds[tid] = a + b;
    __syncthreads();
    for (int off = 1; off < 1024; off <<= 1) {
        int v = (tid >= off) ? lds[tid - off] : 0;
        __syncthreads();
        lds[tid] += v;
        __syncthreads();
    }
    int excl = lds[tid] - (a + b);
    if (i0 < nbk) { boffs[i0] = excl;     bcur[i0 * 16] = excl; }
    if (i1 < nbk) { boffs[i1] = excl + a; bcur[i1 * 16] = excl + a; }
    if (tid == 1023) boffs[nbk] = e;
}

__global__ __launch_bounds__(1024) void k_bscatter(const int* __restrict__ src, const int* __restrict__ dst,
                                                   int* __restrict__ bcur, int* __restrict__ btmp,
                                                   int e, int nbk) {
    __shared__ int hist[MAXNBK];
    int tid = threadIdx.x;
    for (int i = tid; i < nbk; i += 1024) hist[i] = 0;
    __syncthreads();
    int per = (e + gridDim.x - 1) / gridDim.x;
    int base = blockIdx.x * per;
    int end = min(base + per, e);
    for (int i = base + tid; i < end; i += 1024) atomicAdd(&hist[dst[i] >> 6], 1);
    __syncthreads();
    for (int i = tid; i < nbk; i += 1024) {
        int c = hist[i];
        hist[i] = c ? atomicAdd(&bcur[i * 16], c) : 0;
    }
    __syncthreads();
    for (int i = base + tid; i < end; i += 1024) {
        int d = dst[i];
        int pos = atomicAdd(&hist[d >> 6], 1);          // LDS int atomic (native)
        btmp[pos] = (src[i] << 6) | (d & 63);
    }
}

__global__ __launch_bounds__(256) void k_bsort(const int* __restrict__ btmp, const int* __restrict__ boffs,
                                               int* __restrict__ csr, int* __restrict__ offs,
                                               float* __restrict__ dinv, int n, int etot) {
    __shared__ int cnt[BK];
    __shared__ int cur[BK];
    int b = blockIdx.x, tid = threadIdx.x;
    if (tid < BK) cnt[tid] = 0;
    __syncthreads();
    int e0 = boffs[b], e1 = boffs[b + 1];
    for (int i = e0 + tid; i < e1; i += 256) atomicAdd(&cnt[btmp[i] & 63], 1);
    __syncthreads();
    if (tid == 0) {
        int run = 0;
        for (int d = 0; d < BK; ++d) { cur[d] = run; run += cnt[d]; }
    }
    __syncthreads();
    if (tid < BK) {
        int node = b * BK + tid;
        if (node < n) {
            offs[node] = e0 + cur[tid];
            dinv[node] = rsqrtf((float)(cnt[tid] + 1));  // +1 self-loop
        }
    }
    if (b == 0 && tid == 0) offs[n] = etot;
    __syncthreads();
    for (int i = e0 + tid; i < e1; i += 256) {
        int p = btmp[i];
        int pos = e0 + atomicAdd(&cur[p & 63], 1);
        csr[pos] = p >> 6;
    }
}

// ---------------- weight transpose to fp16 ----------------

__global__ void k_prepw(const float* __restrict__ W, _Float16* __restrict__ Wt) {
    int idx = blockIdx.x * 256 + threadIdx.x;   // 128*128
    int k = idx >> 7, nn = idx & 127;
    Wt[nn * 128 + k] = (_Float16)W[k * 128 + nn];
}

__global__ void k_prepwf(const float* __restrict__ W, _Float16* __restrict__ Wt) {
    int idx = blockIdx.x * 256 + threadIdx.x;   // 128*32
    int k = idx >> 5, nn = idx & 31;
    Wt[nn * 128 + k] = (_Float16)W[k * 32 + nn];
}

// ---------------- MFMA GEMM layer 1 with fused embed -----------------------------------
// h = relu(x @ We + be) computed in staging (written to global for residual use),
// th = fp16(dinv * (h @ W1)).

__global__ __launch_bounds__(256) void k_mm1(const float* __restrict__ x, const float* __restrict__ We,
                                             const float* __restrict__ be, const _Float16* __restrict__ Wt,
                                             const float* __restrict__ dinv, __half2* __restrict__ th,
                                             float* __restrict__ h, int n) {
    __shared__ __attribute__((aligned(16))) _Float16 Ah[64][PADK];
    __shared__ __attribute__((aligned(16))) _Float16 Bh[128][PADK];
    __shared__ float W0s[128], W1s[128], bes[128];
    int tid = threadIdx.x;
    int nb = blockIdx.x * 64;
    if (tid < 128) { W0s[tid] = We[tid]; W1s[tid] = We[128 + tid]; bes[tid] = be[tid]; }
    __syncthreads();
    float4* h4 = (float4*)h;
    const float2* x2 = (const float2*)x;
#pragma unroll
    for (int r = 0; r < 8; ++r) {
        int idx = r * 256 + tid;
        int ni = idx >> 5, k4 = idx & 31;
        int node = nb + ni;
        float4 v = make_float4(0.f, 0.f, 0.f, 0.f);
        if (node < n) {
            float2 xx = x2[node];
            float4 w0 = *((const float4*)&W0s[k4 * 4]);
            float4 w1 = *((const float4*)&W1s[k4 * 4]);
            float4 bb = *((const float4*)&bes[k4 * 4]);
            v.x = fmaxf(xx.x * w0.x + xx.y * w1.x + bb.x, 0.f);
            v.y = fmaxf(xx.x * w0.y + xx.y * w1.y + bb.y, 0.f);
            v.z = fmaxf(xx.x * w0.z + xx.y * w1.z + bb.z, 0.f);
            v.w = fmaxf(xx.x * w0.w + xx.y * w1.w + bb.w, 0.f);
            h4[(size_t)node * 32 + k4] = v;   // materialize h for layer-2 residual
        }
        union { __half2 h2[2]; uint2 u; } pk;
        pk.h2[0] = __floats2half2_rn(v.x, v.y);
        pk.h2[1] = __floats2half2_rn(v.z, v.w);
        *(uint2*)&Ah[ni][k4 * 4] = pk.u;
    }
    const uint4* wt4 = (const uint4*)Wt;
#pragma unroll
    for (int r = 0; r < 8; ++r) {
        int idx = r * 256 + tid;
        int row = idx >> 4, ch = idx & 15;
        *(uint4*)&Bh[row][ch * 8] = wt4[row * 16 + ch];
    }
    __syncthreads();
    int lane = tid & 63, w = tid >> 6;
    int mrow = lane & 15, quad = lane >> 4;
    f32x4 acc[8];
#pragma unroll
    for (int t = 0; t < 8; ++t) acc[t] = (f32x4){0.f, 0.f, 0.f, 0.f};
#pragma unroll
    for (int kc = 0; kc < 4; ++kc) {
        half8 av = *(half8*)&Ah[w * 16 + mrow][kc * 32 + quad * 8];
#pragma unroll
        for (int t = 0; t < 8; ++t) {
            half8 bv = *(half8*)&Bh[t * 16 + mrow][kc * 32 + quad * 8];
            acc[t] = __builtin_amdgcn_mfma_f32_16x16x32_f16(av, bv, acc[t], 0, 0, 0);
        }
    }
    float dv[4];
#pragma unroll
    for (int r = 0; r < 4; ++r) {
        int node = nb + w * 16 + quad * 4 + r;
        dv[r] = (node < n) ? dinv[node] : 0.f;
    }
    __syncthreads();   // Ah reads done; reuse as output repack tile
#pragma unroll
    for (int t = 0; t < 8; ++t)
#pragma unroll
        for (int r = 0; r < 4; ++r)
            Ah[w * 16 + quad * 4 + r][t * 16 + mrow] = (_Float16)(acc[t][r] * dv[r]);
    __syncthreads();
#pragma unroll
    for (int it = 0; it < 4; ++it) {
        int idx = it * 256 + tid;
        int row = idx >> 4, ch = idx & 15;
        int node = nb + row;
        if (node < n)
            ((uint4*)th)[(size_t)node * 16 + ch] = *(uint4*)&Ah[row][ch * 8];
    }
}

// ---------------- MFMA GEMM fused with BN-finalize+apply+ReLU+residual (layers 2,3) ----
// A,C computed in-kernel from striped stats (deletes k_bn_finalize dispatch).

__global__ __launch_bounds__(256) void k_mmf(const float* __restrict__ agg, float* __restrict__ h,
                                             const float* __restrict__ S, const float* __restrict__ SS,
                                             const float* __restrict__ g, const float* __restrict__ bt,
                                             const _Float16* __restrict__ Wt, const float* __restrict__ dinv,
                                             __half2* __restrict__ th, int n) {
    __shared__ __attribute__((aligned(16))) _Float16 Ah[64][PADK];
    __shared__ __attribute__((aligned(16))) _Float16 Bh[128][PADK];
    __shared__ float As[128], Cs[128];
    int tid = threadIdx.x;
    int nb = blockIdx.x * 64;
    if (tid < 128) {
        float s = 0.f, q = 0.f;
#pragma unroll
        for (int k = 0; k < NSTRIPE; ++k) { s += S[k * 128 + tid]; q += SS[k * 128 + tid]; }
        float mu = s / (float)n;
        float var = q / (float)n - mu * mu;
        float inv = rsqrtf(var + EPS);
        As[tid] = g[tid] * inv;
        Cs[tid] = bt[tid] - mu * g[tid] * inv;
    }
    __syncthreads();
    const float4* a4p = (const float4*)agg;
    float4* h4 = (float4*)h;
#pragma unroll
    for (int r = 0; r < 8; ++r) {
        int idx = r * 256 + tid;
        int ni = idx >> 5, k4 = idx & 31;
        int node = nb + ni;
        float4 v = make_float4(0.f, 0.f, 0.f, 0.f);
        if (node < n) {
            float4 a = a4p[(size_t)node * 32 + k4];
            float4 ho = h4[(size_t)node * 32 + k4];
            float4 aa = *((const float4*)&As[k4 * 4]);
            float4 cc = *((const float4*)&Cs[k4 * 4]);
            v.x = fmaxf(a.x * aa.x + cc.x, 0.f) + ho.x;
            v.y = fmaxf(a.y * aa.y + cc.y, 0.f) + ho.y;
            v.z = fmaxf(a.z * aa.z + cc.z, 0.f) + ho.z;
            v.w = fmaxf(a.w * aa.w + cc.w, 0.f) + ho.w;
            h4[(size_t)node * 32 + k4] = v;   // in-place: element owned by one thread
        }
        union { __half2 h2[2]; uint2 u; } pk;
        pk.h2[0] = __floats2half2_rn(v.x, v.y);
        pk.h2[1] = __floats2half2_rn(v.z, v.w);
        *(uint2*)&Ah[ni][k4 * 4] = pk.u;
    }
    const uint4* wt4 = (const uint4*)Wt;
#pragma unroll
    for (int r = 0; r < 8; ++r) {
        int idx = r * 256 + tid;
        int row = idx >> 4, ch = idx & 15;
        *(uint4*)&Bh[row][ch * 8] = wt4[row * 16 + ch];
    }
    __syncthreads();
    int lane = tid & 63, w = tid >> 6;
    int mrow = lane & 15, quad = lane >> 4;
    f32x4 acc[8];
#pragma unroll
    for (int t = 0; t < 8; ++t) acc[t] = (f32x4){0.f, 0.f, 0.f, 0.f};
#pragma unroll
    for (int kc = 0; kc < 4; ++kc) {
        half8 av = *(half8*)&Ah[w * 16 + mrow][kc * 32 + quad * 8];
#pragma unroll
        for (int t = 0; t < 8; ++t) {
            half8 bv = *(half8*)&Bh[t * 16 + mrow][kc * 32 + quad * 8];
            acc[t] = __builtin_amdgcn_mfma_f32_16x16x32_f16(av, bv, acc[t], 0, 0, 0);
        }
    }
    float dv[4];
#pragma unroll
    for (int r = 0; r < 4; ++r) {
        int node = nb + w * 16 + quad * 4 + r;
        dv[r] = (node < n) ? dinv[node] : 0.f;
    }
    __syncthreads();
#pragma unroll
    for (int t = 0; t < 8; ++t)
#pragma unroll
        for (int r = 0; r < 4; ++r)
            Ah[w * 16 + quad * 4 + r][t * 16 + mrow] = (_Float16)(acc[t][r] * dv[r]);
    __syncthreads();
#pragma unroll
    for (int it = 0; it < 4; ++it) {
        int idx = it * 256 + tid;
        int row = idx >> 4, ch = idx & 15;
        int node = nb + row;
        if (node < n)
            ((uint4*)th)[(size_t)node * 16 + ch] = *(uint4*)&Ah[row][ch * 8];
    }
}

// ---------------- MFMA head GEMM: BN-finalize+apply+ReLU+residual -> @Wf1+bf1 + stats --

__global__ __launch_bounds__(256) void k_mmh(const float* __restrict__ agg, const float* __restrict__ h,
                                             const float* __restrict__ Sin, const float* __restrict__ SSin,
                                             const float* __restrict__ g, const float* __restrict__ bt,
                                             const _Float16* __restrict__ Wt, const float* __restrict__ bias,
                                             float* __restrict__ tf,
                                             float* __restrict__ S, float* __restrict__ SS, int n) {
    __shared__ __attribute__((aligned(16))) _Float16 Ah[64][PADK];
    __shared__ __attribute__((aligned(16))) _Float16 Bh[32][PADK];
    __shared__ float Ds[64][36];
    __shared__ float As[128], Cs[128];
    __shared__ float sredS[4][8][4], sredQ[4][8][4];
    int tid = threadIdx.x;
    int nb = blockIdx.x * 64;
    if (tid < 128) {
        float s = 0.f, q = 0.f;
#pragma unroll
        for (int k = 0; k < NSTRIPE; ++k) { s += Sin[k * 128 + tid]; q += SSin[k * 128 + tid]; }
        float mu = s / (float)n;
        float var = q / (float)n - mu * mu;
        float inv = rsqrtf(var + EPS);
        As[tid] = g[tid] * inv;
        Cs[tid] = bt[tid] - mu * g[tid] * inv;
    }
    __syncthreads();
    const float4* a4p = (const float4*)agg;
    const float4* h4 = (const float4*)h;
#pragma unroll
    for (int r = 0; r < 8; ++r) {
        int idx = r * 256 + tid;
        int ni = idx >> 5, k4 = idx & 31;
        int node = nb + ni;
        float4 v = make_float4(0.f, 0.f, 0.f, 0.f);
        if (node < n) {
            float4 a = a4p[(size_t)node * 32 + k4];
            float4 ho = h4[(size_t)node * 32 + k4];
            float4 aa = *((const float4*)&As[k4 * 4]);
            float4 cc = *((const float4*)&Cs[k4 * 4]);
            v.x = fmaxf(a.x * aa.x + cc.x, 0.f) + ho.x;
            v.y = fmaxf(a.y * aa.y + cc.y, 0.f) + ho.y;
            v.z = fmaxf(a.z * aa.z + cc.z, 0.f) + ho.z;
            v.w = fmaxf(a.w * aa.w + cc.w, 0.f) + ho.w;
        }
        union { __half2 h2[2]; uint2 u; } pk;
        pk.h2[0] = __floats2half2_rn(v.x, v.y);
        pk.h2[1] = __floats2half2_rn(v.z, v.w);
        *(uint2*)&Ah[ni][k4 * 4] = pk.u;
    }
    const uint4* wt4 = (const uint4*)Wt;
#pragma unroll
    for (int r = 0; r < 2; ++r) {
        int idx = r * 256 + tid;
        int row = idx >> 4, ch = idx & 15;
        *(uint4*)&Bh[row][ch * 8] = wt4[row * 16 + ch];
    }
    __syncthreads();
    int lane = tid & 63, w = tid >> 6;
    int mrow = lane & 15, quad = lane >> 4;
    f32x4 acc[2];
    acc[0] = (f32x4){0.f, 0.f, 0.f, 0.f};
    acc[1] = (f32x4){0.f, 0.f, 0.f, 0.f};
#pragma unroll
    for (int kc = 0; kc < 4; ++kc) {
        half8 av = *(half8*)&Ah[w * 16 + mrow][kc * 32 + quad * 8];
#pragma unroll
        for (int t = 0; t < 2; ++t) {
            half8 bv = *(half8*)&Bh[t * 16 + mrow][kc * 32 + quad * 8];
            acc[t] = __builtin_amdgcn_mfma_f32_16x16x32_f16(av, bv, acc[t], 0, 0, 0);
        }
    }
#pragma unroll
    for (int t = 0; t < 2; ++t)
#pragma unroll
        for (int r = 0; r < 4; ++r)
            Ds[w * 16 + quad * 4 + r][t * 16 + mrow] = acc[t][r];
    __syncthreads();
    float ps0 = 0.f, ps1 = 0.f, ps2 = 0.f, ps3 = 0.f;
    float pq0 = 0.f, pq1 = 0.f, pq2 = 0.f, pq3 = 0.f;
    int c4 = tid & 7;
    float4 bb = ((const float4*)bias)[c4];
#pragma unroll
    for (int it = 0; it < 2; ++it) {
        int idx = it * 256 + tid;
        int row = idx >> 3;
        int node = nb + row;
        if (node < n) {
            float v0 = Ds[row][c4 * 4 + 0] + bb.x;
            float v1 = Ds[row][c4 * 4 + 1] + bb.y;
            float v2 = Ds[row][c4 * 4 + 2] + bb.z;
            float v3 = Ds[row][c4 * 4 + 3] + bb.w;
            *((float4*)&tf[(size_t)node * 32 + c4 * 4]) = make_float4(v0, v1, v2, v3);
            ps0 += v0; ps1 += v1; ps2 += v2; ps3 += v3;
            pq0 += v0 * v0; pq1 += v1 * v1; pq2 += v2 * v2; pq3 += v3 * v3;
        }
    }
#pragma unroll
    for (int off = 8; off < 64; off <<= 1) {
        ps0 += __shfl_down(ps0, off); ps1 += __shfl_down(ps1, off);
        ps2 += __shfl_down(ps2, off); ps3 += __shfl_down(ps3, off);
        pq0 += __shfl_down(pq0, off); pq1 += __shfl_down(pq1, off);
        pq2 += __shfl_down(pq2, off); pq3 += __shfl_down(pq3, off);
    }
    if (lane < 8) {
        sredS[w][lane][0] = ps0; sredS[w][lane][1] = ps1; sredS[w][lane][2] = ps2; sredS[w][lane][3] = ps3;
        sredQ[w][lane][0] = pq0; sredQ[w][lane][1] = pq1; sredQ[w][lane][2] = pq2; sredQ[w][lane][3] = pq3;
    }
    __syncthreads();
    if (tid < 32) {
        int cc4 = tid >> 2, j = tid & 3;
        float s = sredS[0][cc4][j] + sredS[1][cc4][j] + sredS[2][cc4][j] + sredS[3][cc4][j];
        float q = sredQ[0][cc4][j] + sredQ[1][cc4][j] + sredQ[2][cc4][j] + sredQ[3][cc4][j];
        int stripe = (blockIdx.x & (NSTRIPE - 1)) * 128;
        atomicAdd(&S[stripe + tid], s);
        atomicAdd(&SS[stripe + tid], q);
    }
}

// ---------------- aggregation + fused BN stats ----------------------------------------
// Quad-edge gather: lane l loads 16 B (8 feats) of edge (e + 4*j + (l>>4)); one load instr
// covers FOUR edge rows (gather is issue-rate-bound: R7->R8 evidence). Fold via 2 shfls.

__global__ __launch_bounds__(256) void k_agg(const __half2* __restrict__ t, const int* __restrict__ offs,
                                             const int* __restrict__ csr, const float* __restrict__ dinv,
                                             const float* __restrict__ bias, float* __restrict__ out,
                                             float* __restrict__ S, float* __restrict__ SS, int n) {
    __shared__ float ls[4][128];
    __shared__ float lss[4][128];
    int tid = threadIdx.x;
    int lane = tid & 63, w = tid >> 6;
    int sub = lane >> 4, fl = lane & 15;      // fl: feature chunk of 8 (16 B)
    const uint4* t8 = (const uint4*)t;        // row = 16 uint4 chunks
    float4 bb0 = ((const float4*)bias)[fl * 2];
    float4 bb1 = ((const float4*)bias)[fl * 2 + 1];
    float st[8] = {0.f, 0.f, 0.f, 0.f, 0.f, 0.f, 0.f, 0.f};
    float qt[8] = {0.f, 0.f, 0.f, 0.f, 0.f, 0.f, 0.f, 0.f};
    float selfm = (sub == 0) ? 1.f : 0.f;
    int ngrp = (n + 3) >> 2;
    for (int grp = blockIdx.x; grp < ngrp; grp += gridDim.x) {
        int node = grp * 4 + w;               // wave-uniform
        if (node < n) {
            float a[8];
            {
                uint4 rv = t8[(size_t)node * 16 + fl];
                float2 f0 = __half22float2(*(__half2*)&rv.x);
                float2 f1 = __half22float2(*(__half2*)&rv.y);
                float2 f2 = __half22float2(*(__half2*)&rv.z);
                float2 f3 = __half22float2(*(__half2*)&rv.w);
                a[0] = f0.x * selfm; a[1] = f0.y * selfm; a[2] = f1.x * selfm; a[3] = f1.y * selfm;
                a[4] = f2.x * selfm; a[5] = f2.y * selfm; a[6] = f3.x * selfm; a[7] = f3.y * selfm;
            }
            int e0 = offs[node], e1 = offs[node + 1];
            for (int e = e0; e < e1; e += 16) {
                int i0 = e + sub, i1 = e + 4 + sub, i2 = e + 8 + sub, i3 = e + 12 + sub;
                int c0 = csr[min(i0, e1 - 1)];
                int c1 = csr[min(i1, e1 - 1)];
                int c2 = csr[min(i2, e1 - 1)];
                int c3 = csr[min(i3, e1 - 1)];
                uint4 r0 = t8[(size_t)c0 * 16 + fl];
                uint4 r1 = t8[(size_t)c1 * 16 + fl];
                uint4 r2 = t8[(size_t)c2 * 16 + fl];
                uint4 r3 = t8[(size_t)c3 * 16 + fl];
                float m0 = (i0 < e1) ? 1.f : 0.f;
                float m1 = (i1 < e1) ? 1.f : 0.f;
                float m2 = (i2 < e1) ? 1.f : 0.f;
                float m3 = (i3 < e1) ? 1.f : 0.f;
                float2 g0, g1, g2, g3;
                g0 = __half22float2(*(__half2*)&r0.x); g1 = __half22float2(*(__half2*)&r0.y);
                g2 = __half22float2(*(__half2*)&r0.z); g3 = __half22float2(*(__half2*)&r0.w);
                a[0] += m0 * g0.x; a[1] += m0 * g0.y; a[2] += m0 * g1.x; a[3] += m0 * g1.y;
                a[4] += m0 * g2.x; a[5] += m0 * g2.y; a[6] += m0 * g3.x; a[7] += m0 * g3.y;
                g0 = __half22float2(*(__half2*)&r1.x); g1 = __half22float2(*(__half2*)&r1.y);
                g2 = __half22float2(*(__half2*)&r1.z); g3 = __half22float2(*(__half2*)&r1.w);
                a[0] += m1 * g0.x; a[1] += m1 * g0.y; a[2] += m1 * g1.x; a[3] += m1 * g1.y;
                a[4] += m1 * g2.x; a[5] += m1 * g2.y; a[6] += m1 * g3.x; a[7] += m1 * g3.y;
                g0 = __half22float2(*(__half2*)&r2.x); g1 = __half22float2(*(__half2*)&r2.y);
                g2 = __half22float2(*(__half2*)&r2.z); g3 = __half22float2(*(__half2*)&r2.w);
                a[0] += m2 * g0.x; a[1] += m2 * g0.y; a[2] += m2 * g1.x; a[3] += m2 * g1.y;
                a[4] += m2 * g2.x; a[5] += m2 * g2.y; a[6] += m2 * g3.x; a[7] += m2 * g3.y;
                g0 = __half22float2(*(__half2*)&r3.x); g1 = __half22float2(*(__half2*)&r3.y);
                g2 = __half22float2(*(__half2*)&r3.z); g3 = __half22float2(*(__half2*)&r3.w);
                a[0] += m3 * g0.x; a[1] += m3 * g0.y; a[2] += m3 * g1.x; a[3] += m3 * g1.y;
                a[4] += m3 * g2.x; a[5] += m3 * g2.y; a[6] += m3 * g3.x; a[7] += m3 * g3.y;
            }
#pragma unroll
            for (int j = 0; j < 8; ++j) {
                a[j] += __shfl_down(a[j], 16);
                a[j] += __shfl_down(a[j], 32);
            }
            if (sub == 0) {
                float di = dinv[node];
                float v0 = a[0] * di + bb0.x, v1 = a[1] * di + bb0.y;
                float v2 = a[2] * di + bb0.z, v3 = a[3] * di + bb0.w;
                float v4 = a[4] * di + bb1.x, v5 = a[5] * di + bb1.y;
                float v6 = a[6] * di + bb1.z, v7 = a[7] * di + bb1.w;
                ((float4*)out)[(size_t)node * 32 + fl * 2] = make_float4(v0, v1, v2, v3);
                ((float4*)out)[(size_t)node * 32 + fl * 2 + 1] = make_float4(v4, v5, v6, v7);
                st[0] += v0; st[1] += v1; st[2] += v2; st[3] += v3;
                st[4] += v4; st[5] += v5; st[6] += v6; st[7] += v7;
                qt[0] += v0 * v0; qt[1] += v1 * v1; qt[2] += v2 * v2; qt[3] += v3 * v3;
                qt[4] += v4 * v4; qt[5] += v5 * v5; qt[6] += v6 * v6; qt[7] += v7 * v7;
            }
        }
    }
    if (sub == 0) {
        *(float4*)&ls[w][fl * 8] = make_float4(st[0], st[1], st[2], st[3]);
        *(float4*)&ls[w][fl * 8 + 4] = make_float4(st[4], st[5], st[6], st[7]);
        *(float4*)&lss[w][fl * 8] = make_float4(qt[0], qt[1], qt[2], qt[3]);
        *(float4*)&lss[w][fl * 8 + 4] = make_float4(qt[4], qt[5], qt[6], qt[7]);
    }
    __syncthreads();
    if (tid < 128) {
        float s = ls[0][tid] + ls[1][tid] + ls[2][tid] + ls[3][tid];
        float q = lss[0][tid] + lss[1][tid] + lss[2][tid] + lss[3][tid];
        int stripe = (blockIdx.x & (NSTRIPE - 1)) * 128;
        atomicAdd(&S[stripe + tid], s);
        atomicAdd(&SS[stripe + tid], q);
    }
}

// ---------------- final: out = tanh(relu(bn(tf)) @ Wf2 + bf2), BN-finalize fused -------

__global__ __launch_bounds__(256) void k_final(const float* __restrict__ tf,
                                               const float* __restrict__ S, const float* __restrict__ SS,
                                               const float* __restrict__ gf, const float* __restrict__ btf,
                                               const float* __restrict__ Wf2, const float* __restrict__ bf2,
                                               float* __restrict__ out, int n) {
    __shared__ float Af[32], Cf[32];
    int tid = threadIdx.x;
    if (tid < 32) {
        float s = 0.f, q = 0.f;
#pragma unroll
        for (int k = 0; k < NSTRIPE; ++k) { s += S[k * 128 + tid]; q += SS[k * 128 + tid]; }
        float mu = s / (float)n;
        float var = q / (float)n - mu * mu;
        float inv = rsqrtf(var + EPS);
        Af[tid] = gf[tid] * inv;
        Cf[tid] = btf[tid] - mu * gf[tid] * inv;
    }
    __syncthreads();
    int node = blockIdx.x * 256 + tid;
    if (node >= n) return;
    float o0 = bf2[0], o1 = bf2[1];
    const float4* t4 = (const float4*)(tf + (size_t)node * 32);
#pragma unroll
    for (int q = 0; q < 8; ++q) {
        float4 v = t4[q];
        float vv[4] = {v.x, v.y, v.z, v.w};
#pragma unroll
        for (int r = 0; r < 4; ++r) {
            int j = q * 4 + r;
            float f = fmaxf(vv[r] * Af[j] + Cf[j], 0.f);
            o0 += f * Wf2[2 * j];
            o1 += f * Wf2[2 * j + 1];
        }
    }
    out[2 * node] = tanhf(o0);
    out[2 * node + 1] = tanhf(o1);
}

// ---------------- launch ----------------

extern "C" void kernel_launch(void* const* d_in, const int* in_sizes, int n_in,
                              void* d_out, int out_size, void* d_ws, size_t ws_size,
                              hipStream_t stream) {
    const float* x   = (const float*)d_in[0];
    const int*   ei  = (const int*)d_in[1];
    const float* We  = (const float*)d_in[2];
    const float* be  = (const float*)d_in[3];
    const float* W1  = (const float*)d_in[4];
    const float* b1  = (const float*)d_in[5];
    const float* g1  = (const float*)d_in[6];
    const float* bt1 = (const float*)d_in[7];
    const float* W2  = (const float*)d_in[8];
    const float* b2  = (const float*)d_in[9];
    const float* g2  = (const float*)d_in[10];
    const float* bt2 = (const float*)d_in[11];
    const float* W3  = (const float*)d_in[12];
    const float* b3  = (const float*)d_in[13];
    const float* g3  = (const float*)d_in[14];
    const float* bt3 = (const float*)d_in[15];
    const float* Wf1 = (const float*)d_in[16];
    const float* bf1 = (const float*)d_in[17];
    const float* gf  = (const float*)d_in[18];
    const float* btf = (const float*)d_in[19];
    const float* Wf2 = (const float*)d_in[20];
    const float* bf2 = (const float*)d_in[21];
    float* out = (float*)d_out;

    const int n = in_sizes[0] / 2;      // x is [N,2]
    const int e = in_sizes[1] / 2;      // edge_index is [2,E]
    const int* srcp = ei;
    const int* dstp = ei + e;
    const int nbk = (n + BK - 1) / BK;

    char* p = (char*)d_ws;
    auto alloc = [&](size_t bytes) { void* r = (void*)p; p += (bytes + 255) & ~(size_t)255; return r; };
    int*       bcount = (int*)alloc((size_t)nbk * 16 * 4);
    int*       boffs  = (int*)alloc((size_t)(nbk + 1) * 4);
    int*       bcur   = (int*)alloc((size_t)nbk * 16 * 4);
    int*       btmp   = (int*)alloc((size_t)e * 4);
    int*       csr    = (int*)alloc((size_t)e * 4);
    int*       offs   = (int*)alloc((size_t)(n + 1) * 4);
    float*     dinv   = (float*)alloc((size_t)n * 4);
    float*     h      = (float*)alloc((size_t)n * HID * 4);
    __half2*   th     = (__half2*)alloc((size_t)n * HID * 2);
    float*     agg    = (float*)alloc((size_t)n * HID * 4);
    float*     tf     = (float*)alloc((size_t)n * 32 * 4);
    float*     bnAll  = (float*)alloc(8 * NSTRIPE * 128 * 4);   // S0..S2,SH | SS0..SS2,SSH
    _Float16*  wt1    = (_Float16*)alloc(128 * 128 * 2);
    _Float16*  wt2    = (_Float16*)alloc(128 * 128 * 2);
    _Float16*  wt3    = (_Float16*)alloc(128 * 128 * 2);
    _Float16*  wtf    = (_Float16*)alloc(32 * 128 * 2);

    float* S0 = bnAll;             float* SS0 = bnAll + 4 * NSTRIPE * 128;
    float* S1 = S0 + NSTRIPE*128;  float* SS1 = SS0 + NSTRIPE*128;
    float* S2 = S1 + NSTRIPE*128;  float* SS2 = SS1 + NSTRIPE*128;
    float* SH = S2 + NSTRIPE*128;  float* SSH = SS2 + NSTRIPE*128;

    hipMemsetAsync(bcount, 0, (size_t)nbk * 16 * 4, stream);
    hipMemsetAsync(bnAll, 0, 8 * NSTRIPE * 128 * 4, stream);
    k_bhist<<<(e + 4095) / 4096, 256, 0, stream>>>(dstp, bcount, e, nbk);
    k_bscan<<<1, 1024, 0, stream>>>(bcount, boffs, bcur, nbk, e);
    k_bscatter<<<256, 1024, 0, stream>>>(srcp, dstp, bcur, btmp, e, nbk);
    k_bsort<<<nbk, 256, 0, stream>>>(btmp, boffs, csr, offs, dinv, n, e);
    k_prepw<<<64, 256, 0, stream>>>(W1, wt1);
    k_prepw<<<64, 256, 0, stream>>>(W2, wt2);
    k_prepw<<<64, 256, 0, stream>>>(W3, wt3);
    k_prepwf<<<16, 256, 0, stream>>>(Wf1, wtf);

    // layer 1 (embed fused into GEMM staging)
    k_mm1<<<(n + 63) / 64, 256, 0, stream>>>(x, We, be, wt1, dinv, th, h, n);
    k_agg<<<4096, 256, 0, stream>>>(th, offs, csr, dinv, b1, agg, S0, SS0, n);

    // layer 2 (BN1 finalize+apply+relu+residual fused into GEMM)
    k_mmf<<<(n + 63) / 64, 256, 0, stream>>>(agg, h, S0, SS0, g1, bt1, wt2, dinv, th, n);
    k_agg<<<4096, 256, 0, stream>>>(th, offs, csr, dinv, b2, agg, S1, SS1, n);

    // layer 3
    k_mmf<<<(n + 63) / 64, 256, 0, stream>>>(agg, h, S1, SS1, g2, bt2, wt3, dinv, th, n);
    k_agg<<<4096, 256, 0, stream>>>(th, offs, csr, dinv, b3, agg, S2, SS2, n);

    // head (BN3 finalize+apply+relu+residual + GEMM + head-BN stats)
    k_mmh<<<(n + 63) / 64, 256, 0, stream>>>(agg, h, S2, SS2, g3, bt3, wtf, bf1, tf, SH, SSH, n);

    // final (head-BN finalize fused)
    k_final<<<(n + 255) / 256, 256, 0, stream>>>(tf, SH, SSH, gf, btf, Wf2, bf2, out, n);
}

// Round 12
// 511.292 us; speedup vs baseline: 1.8725x; 1.0430x over previous
//
#include <hip/hip_runtime.h>
#include <hip/hip_fp16.h>
#include <math.h>

#define HID 128
#define EPS 1e-5f
#define BK 64          // dst nodes per bucket
#define MAXNBK 2048    // supports n <= 131072
#define NSTRIPE 16     // BN-stats atomic striping
#define PADK 136       // fp16 LDS row stride: 68 words % 32 = 4 -> conflict-free MFMA frag reads

typedef _Float16 half8 __attribute__((ext_vector_type(8)));
typedef float f32x4 __attribute__((ext_vector_type(4)));

// ---------------- bucketed graph preprocessing ----------------
// btmp entry: (src << 6) | (dst & 63)

__global__ __launch_bounds__(256) void k_bhist(const int* __restrict__ dst, int* __restrict__ bcount,
                                               int e, int nbk) {
    __shared__ int hist[MAXNBK];
    for (int i = threadIdx.x; i < nbk; i += 256) hist[i] = 0;
    __syncthreads();
    int base = blockIdx.x * 4096;
    int end = min(base + 4096, e);
    for (int i = base + threadIdx.x; i < end; i += 256) atomicAdd(&hist[dst[i] >> 6], 1);
    __syncthreads();
    for (int i = threadIdx.x; i < nbk; i += 256) {
        int c = hist[i];
        if (c) atomicAdd(&bcount[i * 16], c);
    }
}

__global__ __launch_bounds__(1024) void k_bscan(const int* __restrict__ bcount, int* __restrict__ boffs,
                                                int* __restrict__ bcur, int nbk, int e) {
    __shared__ int lds[1024];
    int tid = threadIdx.x;
    int i0 = 2 * tid, i1 = 2 * tid + 1;
    int a = (i0 < nbk) ? bcount[i0 * 16] : 0;
    int b = (i1 < nbk) ? bcount[i1 * 16] : 0;
    lds[tid] = a + b;
    __syncthreads();
    for (int off = 1; off < 1024; off <<= 1) {
        int v = (tid >= off) ? lds[tid - off] : 0;
        __syncthreads();
        lds[tid] += v;
        __syncthreads();
    }
    int excl = lds[tid] - (a + b);
    if (i0 < nbk) { boffs[i0] = excl;     bcur[i0 * 16] = excl; }
    if (i1 < nbk) { boffs[i1] = excl + a; bcur[i1 * 16] = excl + a; }
    if (tid == 1023) boffs[nbk] = e;
}

__global__ __launch_bounds__(1024) void k_bscatter(const int* __restrict__ src, const int* __restrict__ dst,
                                                   int* __restrict__ bcur, int* __restrict__ btmp,
                                                   int e, int nbk) {
    __shared__ int hist[MAXNBK];
    int tid = threadIdx.x;
    for (int i = tid; i < nbk; i += 1024) hist[i] = 0;
    __syncthreads();
    int per = (e + gridDim.x - 1) / gridDim.x;
    int base = blockIdx.x * per;
    int end = min(base + per, e);
    for (int i = base + tid; i < end; i += 1024) atomicAdd(&hist[dst[i] >> 6], 1);
    __syncthreads();
    for (int i = tid; i < nbk; i += 1024) {
        int c = hist[i];
        hist[i] = c ? atomicAdd(&bcur[i * 16], c) : 0;
    }
    __syncthreads();
    for (int i = base + tid; i < end; i += 1024) {
        int d = dst[i];
        int pos = atomicAdd(&hist[d >> 6], 1);          // LDS int atomic (native)
        btmp[pos] = (src[i] << 6) | (d & 63);
    }
}

__global__ __launch_bounds__(256) void k_bsort(const int* __restrict__ btmp, const int* __restrict__ boffs,
                                               int* __restrict__ csr, int* __restrict__ offs,
                                               float* __restrict__ dinv, int n, int etot) {
    __shared__ int cnt[BK];
    __shared__ int cur[BK];
    int b = blockIdx.x, tid = threadIdx.x;
    if (tid < BK) cnt[tid] = 0;
    __syncthreads();
    int e0 = boffs[b], e1 = boffs[b + 1];
    for (int i = e0 + tid; i < e1; i += 256) atomicAdd(&cnt[btmp[i] & 63], 1);
    __syncthreads();
    if (tid == 0) {
        int run = 0;
        for (int d = 0; d < BK; ++d) { cur[d] = run; run += cnt[d]; }
    }
    __syncthreads();
    if (tid < BK) {
        int node = b * BK + tid;
        if (node < n) {
            offs[node] = e0 + cur[tid];
            dinv[node] = rsqrtf((float)(cnt[tid] + 1));  // +1 self-loop
        }
    }
    if (b == 0 && tid == 0) offs[n] = etot;
    __syncthreads();
    for (int i = e0 + tid; i < e1; i += 256) {
        int p = btmp[i];
        int pos = e0 + atomicAdd(&cur[p & 63], 1);
        csr[pos] = p >> 6;
    }
}

// ---------------- weight transpose to fp16 ----------------

__global__ void k_prepw(const float* __restrict__ W, _Float16* __restrict__ Wt) {
    int idx = blockIdx.x * 256 + threadIdx.x;   // 128*128
    int k = idx >> 7, nn = idx & 127;
    Wt[nn * 128 + k] = (_Float16)W[k * 128 + nn];
}

__global__ void k_prepwf(const float* __restrict__ W, _Float16* __restrict__ Wt) {
    int idx = blockIdx.x * 256 + threadIdx.x;   // 128*32
    int k = idx >> 5, nn = idx & 31;
    Wt[nn * 128 + k] = (_Float16)W[k * 32 + nn];
}

// ---------------- MFMA GEMM layer 1 with fused embed -----------------------------------

__global__ __launch_bounds__(256) void k_mm1(const float* __restrict__ x, const float* __restrict__ We,
                                             const float* __restrict__ be, const _Float16* __restrict__ Wt,
                                             const float* __restrict__ dinv, __half2* __restrict__ th,
                                             float* __restrict__ h, int n) {
    __shared__ __attribute__((aligned(16))) _Float16 Ah[64][PADK];
    __shared__ __attribute__((aligned(16))) _Float16 Bh[128][PADK];
    __shared__ float W0s[128], W1s[128], bes[128];
    int tid = threadIdx.x;
    int nb = blockIdx.x * 64;
    if (tid < 128) { W0s[tid] = We[tid]; W1s[tid] = We[128 + tid]; bes[tid] = be[tid]; }
    __syncthreads();
    float4* h4 = (float4*)h;
    const float2* x2 = (const float2*)x;
#pragma unroll
    for (int r = 0; r < 8; ++r) {
        int idx = r * 256 + tid;
        int ni = idx >> 5, k4 = idx & 31;
        int node = nb + ni;
        float4 v = make_float4(0.f, 0.f, 0.f, 0.f);
        if (node < n) {
            float2 xx = x2[node];
            float4 w0 = *((const float4*)&W0s[k4 * 4]);
            float4 w1 = *((const float4*)&W1s[k4 * 4]);
            float4 bb = *((const float4*)&bes[k4 * 4]);
            v.x = fmaxf(xx.x * w0.x + xx.y * w1.x + bb.x, 0.f);
            v.y = fmaxf(xx.x * w0.y + xx.y * w1.y + bb.y, 0.f);
            v.z = fmaxf(xx.x * w0.z + xx.y * w1.z + bb.z, 0.f);
            v.w = fmaxf(xx.x * w0.w + xx.y * w1.w + bb.w, 0.f);
            h4[(size_t)node * 32 + k4] = v;   // materialize h for layer-2 residual
        }
        union { __half2 h2[2]; uint2 u; } pk;
        pk.h2[0] = __floats2half2_rn(v.x, v.y);
        pk.h2[1] = __floats2half2_rn(v.z, v.w);
        *(uint2*)&Ah[ni][k4 * 4] = pk.u;
    }
    const uint4* wt4 = (const uint4*)Wt;
#pragma unroll
    for (int r = 0; r < 8; ++r) {
        int idx = r * 256 + tid;
        int row = idx >> 4, ch = idx & 15;
        *(uint4*)&Bh[row][ch * 8] = wt4[row * 16 + ch];
    }
    __syncthreads();
    int lane = tid & 63, w = tid >> 6;
    int mrow = lane & 15, quad = lane >> 4;
    f32x4 acc[8];
#pragma unroll
    for (int t = 0; t < 8; ++t) acc[t] = (f32x4){0.f, 0.f, 0.f, 0.f};
#pragma unroll
    for (int kc = 0; kc < 4; ++kc) {
        half8 av = *(half8*)&Ah[w * 16 + mrow][kc * 32 + quad * 8];
#pragma unroll
        for (int t = 0; t < 8; ++t) {
            half8 bv = *(half8*)&Bh[t * 16 + mrow][kc * 32 + quad * 8];
            acc[t] = __builtin_amdgcn_mfma_f32_16x16x32_f16(av, bv, acc[t], 0, 0, 0);
        }
    }
    float dv[4];
#pragma unroll
    for (int r = 0; r < 4; ++r) {
        int node = nb + w * 16 + quad * 4 + r;
        dv[r] = (node < n) ? dinv[node] : 0.f;
    }
    __syncthreads();   // Ah reads done; reuse as output repack tile
#pragma unroll
    for (int t = 0; t < 8; ++t)
#pragma unroll
        for (int r = 0; r < 4; ++r)
            Ah[w * 16 + quad * 4 + r][t * 16 + mrow] = (_Float16)(acc[t][r] * dv[r]);
    __syncthreads();
#pragma unroll
    for (int it = 0; it < 4; ++it) {
        int idx = it * 256 + tid;
        int row = idx >> 4, ch = idx & 15;
        int node = nb + row;
        if (node < n)
            ((uint4*)th)[(size_t)node * 16 + ch] = *(uint4*)&Ah[row][ch * 8];
    }
}

// ---------------- MFMA GEMM fused with BN-finalize+apply+ReLU+residual (layers 2,3) ----

__global__ __launch_bounds__(256) void k_mmf(const float* __restrict__ agg, float* __restrict__ h,
                                             const float* __restrict__ S, const float* __restrict__ SS,
                                             const float* __restrict__ g, const float* __restrict__ bt,
                                             const _Float16* __restrict__ Wt, const float* __restrict__ dinv,
                                             __half2* __restrict__ th, int n) {
    __shared__ __attribute__((aligned(16))) _Float16 Ah[64][PADK];
    __shared__ __attribute__((aligned(16))) _Float16 Bh[128][PADK];
    __shared__ float As[128], Cs[128];
    int tid = threadIdx.x;
    int nb = blockIdx.x * 64;
    if (tid < 128) {
        float s = 0.f, q = 0.f;
#pragma unroll
        for (int k = 0; k < NSTRIPE; ++k) { s += S[k * 128 + tid]; q += SS[k * 128 + tid]; }
        float mu = s / (float)n;
        float var = q / (float)n - mu * mu;
        float inv = rsqrtf(var + EPS);
        As[tid] = g[tid] * inv;
        Cs[tid] = bt[tid] - mu * g[tid] * inv;
    }
    __syncthreads();
    const float4* a4p = (const float4*)agg;
    float4* h4 = (float4*)h;
#pragma unroll
    for (int r = 0; r < 8; ++r) {
        int idx = r * 256 + tid;
        int ni = idx >> 5, k4 = idx & 31;
        int node = nb + ni;
        float4 v = make_float4(0.f, 0.f, 0.f, 0.f);
        if (node < n) {
            float4 a = a4p[(size_t)node * 32 + k4];
            float4 ho = h4[(size_t)node * 32 + k4];
            float4 aa = *((const float4*)&As[k4 * 4]);
            float4 cc = *((const float4*)&Cs[k4 * 4]);
            v.x = fmaxf(a.x * aa.x + cc.x, 0.f) + ho.x;
            v.y = fmaxf(a.y * aa.y + cc.y, 0.f) + ho.y;
            v.z = fmaxf(a.z * aa.z + cc.z, 0.f) + ho.z;
            v.w = fmaxf(a.w * aa.w + cc.w, 0.f) + ho.w;
            h4[(size_t)node * 32 + k4] = v;   // in-place: element owned by one thread
        }
        union { __half2 h2[2]; uint2 u; } pk;
        pk.h2[0] = __floats2half2_rn(v.x, v.y);
        pk.h2[1] = __floats2half2_rn(v.z, v.w);
        *(uint2*)&Ah[ni][k4 * 4] = pk.u;
    }
    const uint4* wt4 = (const uint4*)Wt;
#pragma unroll
    for (int r = 0; r < 8; ++r) {
        int idx = r * 256 + tid;
        int row = idx >> 4, ch = idx & 15;
        *(uint4*)&Bh[row][ch * 8] = wt4[row * 16 + ch];
    }
    __syncthreads();
    int lane = tid & 63, w = tid >> 6;
    int mrow = lane & 15, quad = lane >> 4;
    f32x4 acc[8];
#pragma unroll
    for (int t = 0; t < 8; ++t) acc[t] = (f32x4){0.f, 0.f, 0.f, 0.f};
#pragma unroll
    for (int kc = 0; kc < 4; ++kc) {
        half8 av = *(half8*)&Ah[w * 16 + mrow][kc * 32 + quad * 8];
#pragma unroll
        for (int t = 0; t < 8; ++t) {
            half8 bv = *(half8*)&Bh[t * 16 + mrow][kc * 32 + quad * 8];
            acc[t] = __builtin_amdgcn_mfma_f32_16x16x32_f16(av, bv, acc[t], 0, 0, 0);
        }
    }
    float dv[4];
#pragma unroll
    for (int r = 0; r < 4; ++r) {
        int node = nb + w * 16 + quad * 4 + r;
        dv[r] = (node < n) ? dinv[node] : 0.f;
    }
    __syncthreads();
#pragma unroll
    for (int t = 0; t < 8; ++t)
#pragma unroll
        for (int r = 0; r < 4; ++r)
            Ah[w * 16 + quad * 4 + r][t * 16 + mrow] = (_Float16)(acc[t][r] * dv[r]);
    __syncthreads();
#pragma unroll
    for (int it = 0; it < 4; ++it) {
        int idx = it * 256 + tid;
        int row = idx >> 4, ch = idx & 15;
        int node = nb + row;
        if (node < n)
            ((uint4*)th)[(size_t)node * 16 + ch] = *(uint4*)&Ah[row][ch * 8];
    }
}

// ---------------- MFMA head GEMM: BN-finalize+apply+ReLU+residual -> @Wf1+bf1 + stats --

__global__ __launch_bounds__(256) void k_mmh(const float* __restrict__ agg, const float* __restrict__ h,
                                             const float* __restrict__ Sin, const float* __restrict__ SSin,
                                             const float* __restrict__ g, const float* __restrict__ bt,
                                             const _Float16* __restrict__ Wt, const float* __restrict__ bias,
                                             float* __restrict__ tf,
                                             float* __restrict__ S, float* __restrict__ SS, int n) {
    __shared__ __attribute__((aligned(16))) _Float16 Ah[64][PADK];
    __shared__ __attribute__((aligned(16))) _Float16 Bh[32][PADK];
    __shared__ float Ds[64][36];
    __shared__ float As[128], Cs[128];
    __shared__ float sredS[4][8][4], sredQ[4][8][4];
    int tid = threadIdx.x;
    int nb = blockIdx.x * 64;
    if (tid < 128) {
        float s = 0.f, q = 0.f;
#pragma unroll
        for (int k = 0; k < NSTRIPE; ++k) { s += Sin[k * 128 + tid]; q += SSin[k * 128 + tid]; }
        float mu = s / (float)n;
        float var = q / (float)n - mu * mu;
        float inv = rsqrtf(var + EPS);
        As[tid] = g[tid] * inv;
        Cs[tid] = bt[tid] - mu * g[tid] * inv;
    }
    __syncthreads();
    const float4* a4p = (const float4*)agg;
    const float4* h4 = (const float4*)h;
#pragma unroll
    for (int r = 0; r < 8; ++r) {
        int idx = r * 256 + tid;
        int ni = idx >> 5, k4 = idx & 31;
        int node = nb + ni;
        float4 v = make_float4(0.f, 0.f, 0.f, 0.f);
        if (node < n) {
            float4 a = a4p[(size_t)node * 32 + k4];
            float4 ho = h4[(size_t)node * 32 + k4];
            float4 aa = *((const float4*)&As[k4 * 4]);
            float4 cc = *((const float4*)&Cs[k4 * 4]);
            v.x = fmaxf(a.x * aa.x + cc.x, 0.f) + ho.x;
            v.y = fmaxf(a.y * aa.y + cc.y, 0.f) + ho.y;
            v.z = fmaxf(a.z * aa.z + cc.z, 0.f) + ho.z;
            v.w = fmaxf(a.w * aa.w + cc.w, 0.f) + ho.w;
        }
        union { __half2 h2[2]; uint2 u; } pk;
        pk.h2[0] = __floats2half2_rn(v.x, v.y);
        pk.h2[1] = __floats2half2_rn(v.z, v.w);
        *(uint2*)&Ah[ni][k4 * 4] = pk.u;
    }
    const uint4* wt4 = (const uint4*)Wt;
#pragma unroll
    for (int r = 0; r < 2; ++r) {
        int idx = r * 256 + tid;
        int row = idx >> 4, ch = idx & 15;
        *(uint4*)&Bh[row][ch * 8] = wt4[row * 16 + ch];
    }
    __syncthreads();
    int lane = tid & 63, w = tid >> 6;
    int mrow = lane & 15, quad = lane >> 4;
    f32x4 acc[2];
    acc[0] = (f32x4){0.f, 0.f, 0.f, 0.f};
    acc[1] = (f32x4){0.f, 0.f, 0.f, 0.f};
#pragma unroll
    for (int kc = 0; kc < 4; ++kc) {
        half8 av = *(half8*)&Ah[w * 16 + mrow][kc * 32 + quad * 8];
#pragma unroll
        for (int t = 0; t < 2; ++t) {
            half8 bv = *(half8*)&Bh[t * 16 + mrow][kc * 32 + quad * 8];
            acc[t] = __builtin_amdgcn_mfma_f32_16x16x32_f16(av, bv, acc[t], 0, 0, 0);
        }
    }
#pragma unroll
    for (int t = 0; t < 2; ++t)
#pragma unroll
        for (int r = 0; r < 4; ++r)
            Ds[w * 16 + quad * 4 + r][t * 16 + mrow] = acc[t][r];
    __syncthreads();
    float ps0 = 0.f, ps1 = 0.f, ps2 = 0.f, ps3 = 0.f;
    float pq0 = 0.f, pq1 = 0.f, pq2 = 0.f, pq3 = 0.f;
    int c4 = tid & 7;
    float4 bb = ((const float4*)bias)[c4];
#pragma unroll
    for (int it = 0; it < 2; ++it) {
        int idx = it * 256 + tid;
        int row = idx >> 3;
        int node = nb + row;
        if (node < n) {
            float v0 = Ds[row][c4 * 4 + 0] + bb.x;
            float v1 = Ds[row][c4 * 4 + 1] + bb.y;
            float v2 = Ds[row][c4 * 4 + 2] + bb.z;
            float v3 = Ds[row][c4 * 4 + 3] + bb.w;
            *((float4*)&tf[(size_t)node * 32 + c4 * 4]) = make_float4(v0, v1, v2, v3);
            ps0 += v0; ps1 += v1; ps2 += v2; ps3 += v3;
            pq0 += v0 * v0; pq1 += v1 * v1; pq2 += v2 * v2; pq3 += v3 * v3;
        }
    }
#pragma unroll
    for (int off = 8; off < 64; off <<= 1) {
        ps0 += __shfl_down(ps0, off); ps1 += __shfl_down(ps1, off);
        ps2 += __shfl_down(ps2, off); ps3 += __shfl_down(ps3, off);
        pq0 += __shfl_down(pq0, off); pq1 += __shfl_down(pq1, off);
        pq2 += __shfl_down(pq2, off); pq3 += __shfl_down(pq3, off);
    }
    if (lane < 8) {
        sredS[w][lane][0] = ps0; sredS[w][lane][1] = ps1; sredS[w][lane][2] = ps2; sredS[w][lane][3] = ps3;
        sredQ[w][lane][0] = pq0; sredQ[w][lane][1] = pq1; sredQ[w][lane][2] = pq2; sredQ[w][lane][3] = pq3;
    }
    __syncthreads();
    if (tid < 32) {
        int cc4 = tid >> 2, j = tid & 3;
        float s = sredS[0][cc4][j] + sredS[1][cc4][j] + sredS[2][cc4][j] + sredS[3][cc4][j];
        float q = sredQ[0][cc4][j] + sredQ[1][cc4][j] + sredQ[2][cc4][j] + sredQ[3][cc4][j];
        int stripe = (blockIdx.x & (NSTRIPE - 1)) * 128;
        atomicAdd(&S[stripe + tid], s);
        atomicAdd(&SS[stripe + tid], q);
    }
}

// ---------------- aggregation + fused BN stats (R10 dual-edge version — proven best) ---
// Lane l loads 8 B (4 feats) of edge (e + (l>>5)): 2 edge rows per wave-instr, VGPR 32,
// occupancy ~74%. R11's 16B quad variant regressed (52 VGPR -> 38% occ).

__global__ __launch_bounds__(256) void k_agg(const __half2* __restrict__ t, const int* __restrict__ offs,
                                             const int* __restrict__ csr, const float* __restrict__ dinv,
                                             const float* __restrict__ bias, float* __restrict__ out,
                                             float* __restrict__ S, float* __restrict__ SS, int n) {
    __shared__ float ls[4][128];
    __shared__ float lss[4][128];
    int tid = threadIdx.x;
    int lane = tid & 63, w = tid >> 6;
    int sub = lane >> 5, fl = lane & 31;
    const uint2* t4 = (const uint2*)t;
    float4 bb = ((const float4*)bias)[fl];
    float s0 = 0.f, s1 = 0.f, s2 = 0.f, s3 = 0.f;
    float q0 = 0.f, q1 = 0.f, q2 = 0.f, q3 = 0.f;
    float selfm = (sub == 0) ? 1.f : 0.f;
    int ngrp = (n + 3) >> 2;
    for (int grp = blockIdx.x; grp < ngrp; grp += gridDim.x) {
        int node = grp * 4 + w;
        if (node < n) {
            uint2 rv = t4[(size_t)node * 32 + fl];
            float2 f0 = __half22float2(*(__half2*)&rv.x);
            float2 f1 = __half22float2(*(__half2*)&rv.y);
            float a0 = f0.x * selfm, a1 = f0.y * selfm, a2 = f1.x * selfm, a3 = f1.y * selfm;
            int e0 = offs[node], e1 = offs[node + 1];
            for (int e = e0; e < e1; e += 8) {
                int i0 = e + sub, i1 = e + 2 + sub, i2 = e + 4 + sub, i3 = e + 6 + sub;
                int c0 = csr[min(i0, e1 - 1)];
                int c1 = csr[min(i1, e1 - 1)];
                int c2 = csr[min(i2, e1 - 1)];
                int c3 = csr[min(i3, e1 - 1)];
                uint2 r0 = t4[(size_t)c0 * 32 + fl];
                uint2 r1 = t4[(size_t)c1 * 32 + fl];
                uint2 r2 = t4[(size_t)c2 * 32 + fl];
                uint2 r3 = t4[(size_t)c3 * 32 + fl];
                float m0 = (i0 < e1) ? 1.f : 0.f;
                float m1 = (i1 < e1) ? 1.f : 0.f;
                float m2 = (i2 < e1) ? 1.f : 0.f;
                float m3 = (i3 < e1) ? 1.f : 0.f;
                float2 g0 = __half22float2(*(__half2*)&r0.x), g1 = __half22float2(*(__half2*)&r0.y);
                a0 += m0 * g0.x; a1 += m0 * g0.y; a2 += m0 * g1.x; a3 += m0 * g1.y;
                g0 = __half22float2(*(__half2*)&r1.x); g1 = __half22float2(*(__half2*)&r1.y);
                a0 += m1 * g0.x; a1 += m1 * g0.y; a2 += m1 * g1.x; a3 += m1 * g1.y;
                g0 = __half22float2(*(__half2*)&r2.x); g1 = __half22float2(*(__half2*)&r2.y);
                a0 += m2 * g0.x; a1 += m2 * g0.y; a2 += m2 * g1.x; a3 += m2 * g1.y;
                g0 = __half22float2(*(__half2*)&r3.x); g1 = __half22float2(*(__half2*)&r3.y);
                a0 += m3 * g0.x; a1 += m3 * g0.y; a2 += m3 * g1.x; a3 += m3 * g1.y;
            }
            a0 += __shfl_down(a0, 32);
            a1 += __shfl_down(a1, 32);
            a2 += __shfl_down(a2, 32);
            a3 += __shfl_down(a3, 32);
            if (sub == 0) {
                float di = dinv[node];
                float v0 = a0 * di + bb.x, v1 = a1 * di + bb.y;
                float v2 = a2 * di + bb.z, v3 = a3 * di + bb.w;
                ((float4*)out)[(size_t)node * 32 + fl] = make_float4(v0, v1, v2, v3);
                s0 += v0; s1 += v1; s2 += v2; s3 += v3;
                q0 += v0 * v0; q1 += v1 * v1; q2 += v2 * v2; q3 += v3 * v3;
            }
        }
    }
    if (sub == 0) {
        ((float4*)&ls[w][0])[fl] = make_float4(s0, s1, s2, s3);
        ((float4*)&lss[w][0])[fl] = make_float4(q0, q1, q2, q3);
    }
    __syncthreads();
    if (tid < 128) {
        float s = ls[0][tid] + ls[1][tid] + ls[2][tid] + ls[3][tid];
        float q = lss[0][tid] + lss[1][tid] + lss[2][tid] + lss[3][tid];
        int stripe = (blockIdx.x & (NSTRIPE - 1)) * 128;
        atomicAdd(&S[stripe + tid], s);
        atomicAdd(&SS[stripe + tid], q);
    }
}

// ---------------- final: out = tanh(relu(bn(tf)) @ Wf2 + bf2), BN-finalize fused -------

__global__ __launch_bounds__(256) void k_final(const float* __restrict__ tf,
                                               const float* __restrict__ S, const float* __restrict__ SS,
                                               const float* __restrict__ gf, const float* __restrict__ btf,
                                               const float* __restrict__ Wf2, const float* __restrict__ bf2,
                                               float* __restrict__ out, int n) {
    __shared__ float Af[32], Cf[32];
    int tid = threadIdx.x;
    if (tid < 32) {
        float s = 0.f, q = 0.f;
#pragma unroll
        for (int k = 0; k < NSTRIPE; ++k) { s += S[k * 128 + tid]; q += SS[k * 128 + tid]; }
        float mu = s / (float)n;
        float var = q / (float)n - mu * mu;
        float inv = rsqrtf(var + EPS);
        Af[tid] = gf[tid] * inv;
        Cf[tid] = btf[tid] - mu * gf[tid] * inv;
    }
    __syncthreads();
    int node = blockIdx.x * 256 + tid;
    if (node >= n) return;
    float o0 = bf2[0], o1 = bf2[1];
    const float4* t4 = (const float4*)(tf + (size_t)node * 32);
#pragma unroll
    for (int q = 0; q < 8; ++q) {
        float4 v = t4[q];
        float vv[4] = {v.x, v.y, v.z, v.w};
#pragma unroll
        for (int r = 0; r < 4; ++r) {
            int j = q * 4 + r;
            float f = fmaxf(vv[r] * Af[j] + Cf[j], 0.f);
            o0 += f * Wf2[2 * j];
            o1 += f * Wf2[2 * j + 1];
        }
    }
    out[2 * node] = tanhf(o0);
    out[2 * node + 1] = tanhf(o1);
}

// ---------------- launch ----------------

extern "C" void kernel_launch(void* const* d_in, const int* in_sizes, int n_in,
                              void* d_out, int out_size, void* d_ws, size_t ws_size,
                              hipStream_t stream) {
    const float* x   = (const float*)d_in[0];
    const int*   ei  = (const int*)d_in[1];
    const float* We  = (const float*)d_in[2];
    const float* be  = (const float*)d_in[3];
    const float* W1  = (const float*)d_in[4];
    const float* b1  = (const float*)d_in[5];
    const float* g1  = (const float*)d_in[6];
    const float* bt1 = (const float*)d_in[7];
    const float* W2  = (const float*)d_in[8];
    const float* b2  = (const float*)d_in[9];
    const float* g2  = (const float*)d_in[10];
    const float* bt2 = (const float*)d_in[11];
    const float* W3  = (const float*)d_in[12];
    const float* b3  = (const float*)d_in[13];
    const float* g3  = (const float*)d_in[14];
    const float* bt3 = (const float*)d_in[15];
    const float* Wf1 = (const float*)d_in[16];
    const float* bf1 = (const float*)d_in[17];
    const float* gf  = (const float*)d_in[18];
    const float* btf = (const float*)d_in[19];
    const float* Wf2 = (const float*)d_in[20];
    const float* bf2 = (const float*)d_in[21];
    float* out = (float*)d_out;

    const int n = in_sizes[0] / 2;      // x is [N,2]
    const int e = in_sizes[1] / 2;      // edge_index is [2,E]
    const int* srcp = ei;
    const int* dstp = ei + e;
    const int nbk = (n + BK - 1) / BK;

    char* p = (char*)d_ws;
    auto alloc = [&](size_t bytes) { void* r = (void*)p; p += (bytes + 255) & ~(size_t)255; return r; };
    int*       bcount = (int*)alloc((size_t)nbk * 16 * 4);
    int*       boffs  = (int*)alloc((size_t)(nbk + 1) * 4);
    int*       bcur   = (int*)alloc((size_t)nbk * 16 * 4);
    int*       btmp   = (int*)alloc((size_t)e * 4);
    int*       csr    = (int*)alloc((size_t)e * 4);
    int*       offs   = (int*)alloc((size_t)(n + 1) * 4);
    float*     dinv   = (float*)alloc((size_t)n * 4);
    float*     h      = (float*)alloc((size_t)n * HID * 4);
    __half2*   th     = (__half2*)alloc((size_t)n * HID * 2);
    float*     agg    = (float*)alloc((size_t)n * HID * 4);
    float*     tf     = (float*)alloc((size_t)n * 32 * 4);
    float*     bnAll  = (float*)alloc(8 * NSTRIPE * 128 * 4);   // S0..S2,SH | SS0..SS2,SSH
    _Float16*  wt1    = (_Float16*)alloc(128 * 128 * 2);
    _Float16*  wt2    = (_Float16*)alloc(128 * 128 * 2);
    _Float16*  wt3    = (_Float16*)alloc(128 * 128 * 2);
    _Float16*  wtf    = (_Float16*)alloc(32 * 128 * 2);

    float* S0 = bnAll;             float* SS0 = bnAll + 4 * NSTRIPE * 128;
    float* S1 = S0 + NSTRIPE*128;  float* SS1 = SS0 + NSTRIPE*128;
    float* S2 = S1 + NSTRIPE*128;  float* SS2 = SS1 + NSTRIPE*128;
    float* SH = S2 + NSTRIPE*128;  float* SSH = SS2 + NSTRIPE*128;

    hipMemsetAsync(bcount, 0, (size_t)nbk * 16 * 4, stream);
    hipMemsetAsync(bnAll, 0, 8 * NSTRIPE * 128 * 4, stream);
    k_bhist<<<(e + 4095) / 4096, 256, 0, stream>>>(dstp, bcount, e, nbk);
    k_bscan<<<1, 1024, 0, stream>>>(bcount, boffs, bcur, nbk, e);
    k_bscatter<<<256, 1024, 0, stream>>>(srcp, dstp, bcur, btmp, e, nbk);
    k_bsort<<<nbk, 256, 0, stream>>>(btmp, boffs, csr, offs, dinv, n, e);
    k_prepw<<<64, 256, 0, stream>>>(W1, wt1);
    k_prepw<<<64, 256, 0, stream>>>(W2, wt2);
    k_prepw<<<64, 256, 0, stream>>>(W3, wt3);
    k_prepwf<<<16, 256, 0, stream>>>(Wf1, wtf);

    // layer 1 (embed fused into GEMM staging)
    k_mm1<<<(n + 63) / 64, 256, 0, stream>>>(x, We, be, wt1, dinv, th, h, n);
    k_agg<<<4096, 256, 0, stream>>>(th, offs, csr, dinv, b1, agg, S0, SS0, n);

    // layer 2 (BN1 finalize+apply+relu+residual fused into GEMM)
    k_mmf<<<(n + 63) / 64, 256, 0, stream>>>(agg, h, S0, SS0, g1, bt1, wt2, dinv, th, n);
    k_agg<<<4096, 256, 0, stream>>>(th, offs, csr, dinv, b2, agg, S1, SS1, n);

    // layer 3
    k_mmf<<<(n + 63) / 64, 256, 0, stream>>>(agg, h, S1, SS1, g2, bt2, wt3, dinv, th, n);
    k_agg<<<4096, 256, 0, stream>>>(th, offs, csr, dinv, b3, agg, S2, SS2, n);

    // head (BN3 finalize+apply+relu+residual + GEMM + head-BN stats)
    k_mmh<<<(n + 63) / 64, 256, 0, stream>>>(agg, h, S2, SS2, g3, bt3, wtf, bf1, tf, SH, SSH, n);

    // final (head-BN finalize fused)
    k_final<<<(n + 255) / 256, 256, 0, stream>>>(tf, SH, SSH, gf, btf, Wf2, bf2, out, n);
}

// Round 13
// 473.587 us; speedup vs baseline: 2.0215x; 1.0796x over previous
//
#include <hip/hip_runtime.h>
#include <hip/hip_fp16.h>
#include <math.h>

#define HID 128
#define EPS 1e-5f
#define BK 64          // dst nodes per bucket
#define MAXNBK 2048    // supports n <= 131072
#define NSTRIPE 16     // BN-stats atomic striping
#define PADK 136       // fp16 LDS row stride: 68 words % 32 = 4 -> conflict-free MFMA frag reads

typedef _Float16 half8 __attribute__((ext_vector_type(8)));
typedef float f32x4 __attribute__((ext_vector_type(4)));

// ---------------- bucketed graph preprocessing ----------------
// btmp entry: (src << 6) | (dst & 63)

__global__ __launch_bounds__(256) void k_bhist(const int* __restrict__ dst, int* __restrict__ bcount,
                                               int e, int nbk) {
    __shared__ int hist[MAXNBK];
    for (int i = threadIdx.x; i < nbk; i += 256) hist[i] = 0;
    __syncthreads();
    int base = blockIdx.x * 4096;
    int end = min(base + 4096, e);
    for (int i = base + threadIdx.x; i < end; i += 256) atomicAdd(&hist[dst[i] >> 6], 1);
    __syncthreads();
    for (int i = threadIdx.x; i < nbk; i += 256) {
        int c = hist[i];
        if (c) atomicAdd(&bcount[i * 16], c);
    }
}

__global__ __launch_bounds__(1024) void k_bscan(const int* __restrict__ bcount, int* __restrict__ boffs,
                                                int* __restrict__ bcur, int nbk, int e) {
    __shared__ int lds[1024];
    int tid = threadIdx.x;
    int i0 = 2 * tid, i1 = 2 * tid + 1;
    int a = (i0 < nbk) ? bcount[i0 * 16] : 0;
    int b = (i1 < nbk) ? bcount[i1 * 16] : 0;
    lds[tid] = a + b;
    __syncthreads();
    for (int off = 1; off < 1024; off <<= 1) {
        int v = (tid >= off) ? lds[tid - off] : 0;
        __syncthreads();
        lds[tid] += v;
        __syncthreads();
    }
    int excl = lds[tid] - (a + b);
    if (i0 < nbk) { boffs[i0] = excl;     bcur[i0 * 16] = excl; }
    if (i1 < nbk) { boffs[i1] = excl + a; bcur[i1 * 16] = excl + a; }
    if (tid == 1023) boffs[nbk] = e;
}

__global__ __launch_bounds__(1024) void k_bscatter(const int* __restrict__ src, const int* __restrict__ dst,
                                                   int* __restrict__ bcur, int* __restrict__ btmp,
                                                   int e, int nbk) {
    __shared__ int hist[MAXNBK];
    int tid = threadIdx.x;
    for (int i = tid; i < nbk; i += 1024) hist[i] = 0;
    __syncthreads();
    int per = (e + gridDim.x - 1) / gridDim.x;
    int base = blockIdx.x * per;
    int end = min(base + per, e);
    for (int i = base + tid; i < end; i += 1024) atomicAdd(&hist[dst[i] >> 6], 1);
    __syncthreads();
    for (int i = tid; i < nbk; i += 1024) {
        int c = hist[i];
        hist[i] = c ? atomicAdd(&bcur[i * 16], c) : 0;
    }
    __syncthreads();
    for (int i = base + tid; i < end; i += 1024) {
        int d = dst[i];
        int pos = atomicAdd(&hist[d >> 6], 1);          // LDS int atomic (native)
        btmp[pos] = (src[i] << 6) | (d & 63);
    }
}

__global__ __launch_bounds__(256) void k_bsort(const int* __restrict__ btmp, const int* __restrict__ boffs,
                                               int* __restrict__ csr, int* __restrict__ offs,
                                               float* __restrict__ dinv, int n, int etot) {
    __shared__ int cnt[BK];
    __shared__ int cur[BK];
    int b = blockIdx.x, tid = threadIdx.x;
    if (tid < BK) cnt[tid] = 0;
    __syncthreads();
    int e0 = boffs[b], e1 = boffs[b + 1];
    for (int i = e0 + tid; i < e1; i += 256) atomicAdd(&cnt[btmp[i] & 63], 1);
    __syncthreads();
    if (tid == 0) {
        int run = 0;
        for (int d = 0; d < BK; ++d) { cur[d] = run; run += cnt[d]; }
    }
    __syncthreads();
    if (tid < BK) {
        int node = b * BK + tid;
        if (node < n) {
            offs[node] = e0 + cur[tid];
            dinv[node] = rsqrtf((float)(cnt[tid] + 1));  // +1 self-loop
        }
    }
    if (b == 0 && tid == 0) offs[n] = etot;
    __syncthreads();
    for (int i = e0 + tid; i < e1; i += 256) {
        int p = btmp[i];
        int pos = e0 + atomicAdd(&cur[p & 63], 1);
        csr[pos] = p >> 6;
    }
}

// ---------------- weight transpose to fp16 ----------------

__global__ void k_prepw(const float* __restrict__ W, _Float16* __restrict__ Wt) {
    int idx = blockIdx.x * 256 + threadIdx.x;   // 128*128
    int k = idx >> 7, nn = idx & 127;
    Wt[nn * 128 + k] = (_Float16)W[k * 128 + nn];
}

__global__ void k_prepwf(const float* __restrict__ W, _Float16* __restrict__ Wt) {
    int idx = blockIdx.x * 256 + threadIdx.x;   // 128*32
    int k = idx >> 5, nn = idx & 31;
    Wt[nn * 128 + k] = (_Float16)W[k * 32 + nn];
}

// ---------------- MFMA GEMM layer 1 with fused embed -----------------------------------
// h = relu(x @ We + be) computed in staging, written FP16 (halves h traffic everywhere),
// th = fp16(dinv * (h @ W1)).

__global__ __launch_bounds__(256) void k_mm1(const float* __restrict__ x, const float* __restrict__ We,
                                             const float* __restrict__ be, const _Float16* __restrict__ Wt,
                                             const float* __restrict__ dinv, __half2* __restrict__ th,
                                             __half2* __restrict__ h, int n) {
    __shared__ __attribute__((aligned(16))) _Float16 Ah[64][PADK];
    __shared__ __attribute__((aligned(16))) _Float16 Bh[128][PADK];
    __shared__ float W0s[128], W1s[128], bes[128];
    int tid = threadIdx.x;
    int nb = blockIdx.x * 64;
    if (tid < 128) { W0s[tid] = We[tid]; W1s[tid] = We[128 + tid]; bes[tid] = be[tid]; }
    __syncthreads();
    uint2* h2p = (uint2*)h;
    const float2* x2 = (const float2*)x;
#pragma unroll
    for (int r = 0; r < 8; ++r) {
        int idx = r * 256 + tid;
        int ni = idx >> 5, k4 = idx & 31;
        int node = nb + ni;
        float4 v = make_float4(0.f, 0.f, 0.f, 0.f);
        union { __half2 h2[2]; uint2 u; } pk;
        if (node < n) {
            float2 xx = x2[node];
            float4 w0 = *((const float4*)&W0s[k4 * 4]);
            float4 w1 = *((const float4*)&W1s[k4 * 4]);
            float4 bb = *((const float4*)&bes[k4 * 4]);
            v.x = fmaxf(xx.x * w0.x + xx.y * w1.x + bb.x, 0.f);
            v.y = fmaxf(xx.x * w0.y + xx.y * w1.y + bb.y, 0.f);
            v.z = fmaxf(xx.x * w0.z + xx.y * w1.z + bb.z, 0.f);
            v.w = fmaxf(xx.x * w0.w + xx.y * w1.w + bb.w, 0.f);
            pk.h2[0] = __floats2half2_rn(v.x, v.y);
            pk.h2[1] = __floats2half2_rn(v.z, v.w);
            h2p[(size_t)node * 32 + k4] = pk.u;   // h stored fp16 for layer-2 residual
        } else {
            pk.h2[0] = __floats2half2_rn(0.f, 0.f);
            pk.h2[1] = __floats2half2_rn(0.f, 0.f);
        }
        *(uint2*)&Ah[ni][k4 * 4] = pk.u;
    }
    const uint4* wt4 = (const uint4*)Wt;
#pragma unroll
    for (int r = 0; r < 8; ++r) {
        int idx = r * 256 + tid;
        int row = idx >> 4, ch = idx & 15;
        *(uint4*)&Bh[row][ch * 8] = wt4[row * 16 + ch];
    }
    __syncthreads();
    int lane = tid & 63, w = tid >> 6;
    int mrow = lane & 15, quad = lane >> 4;
    f32x4 acc[8];
#pragma unroll
    for (int t = 0; t < 8; ++t) acc[t] = (f32x4){0.f, 0.f, 0.f, 0.f};
#pragma unroll
    for (int kc = 0; kc < 4; ++kc) {
        half8 av = *(half8*)&Ah[w * 16 + mrow][kc * 32 + quad * 8];
#pragma unroll
        for (int t = 0; t < 8; ++t) {
            half8 bv = *(half8*)&Bh[t * 16 + mrow][kc * 32 + quad * 8];
            acc[t] = __builtin_amdgcn_mfma_f32_16x16x32_f16(av, bv, acc[t], 0, 0, 0);
        }
    }
    float dv[4];
#pragma unroll
    for (int r = 0; r < 4; ++r) {
        int node = nb + w * 16 + quad * 4 + r;
        dv[r] = (node < n) ? dinv[node] : 0.f;
    }
    __syncthreads();   // Ah reads done; reuse as output repack tile
#pragma unroll
    for (int t = 0; t < 8; ++t)
#pragma unroll
        for (int r = 0; r < 4; ++r)
            Ah[w * 16 + quad * 4 + r][t * 16 + mrow] = (_Float16)(acc[t][r] * dv[r]);
    __syncthreads();
#pragma unroll
    for (int it = 0; it < 4; ++it) {
        int idx = it * 256 + tid;
        int row = idx >> 4, ch = idx & 15;
        int node = nb + row;
        if (node < n)
            ((uint4*)th)[(size_t)node * 16 + ch] = *(uint4*)&Ah[row][ch * 8];
    }
}

// ---------------- MFMA GEMM fused with BN-finalize+apply+ReLU+residual (layers 2,3) ----
// agg (fp16) and h (fp16) read, h updated in-place fp16, BN math in fp32.

__global__ __launch_bounds__(256) void k_mmf(const __half2* __restrict__ agg, __half2* __restrict__ h,
                                             const float* __restrict__ S, const float* __restrict__ SS,
                                             const float* __restrict__ g, const float* __restrict__ bt,
                                             const _Float16* __restrict__ Wt, const float* __restrict__ dinv,
                                             __half2* __restrict__ th, int n) {
    __shared__ __attribute__((aligned(16))) _Float16 Ah[64][PADK];
    __shared__ __attribute__((aligned(16))) _Float16 Bh[128][PADK];
    __shared__ float As[128], Cs[128];
    int tid = threadIdx.x;
    int nb = blockIdx.x * 64;
    if (tid < 128) {
        float s = 0.f, q = 0.f;
#pragma unroll
        for (int k = 0; k < NSTRIPE; ++k) { s += S[k * 128 + tid]; q += SS[k * 128 + tid]; }
        float mu = s / (float)n;
        float var = q / (float)n - mu * mu;
        float inv = rsqrtf(var + EPS);
        As[tid] = g[tid] * inv;
        Cs[tid] = bt[tid] - mu * g[tid] * inv;
    }
    __syncthreads();
    const uint2* a2p = (const uint2*)agg;
    uint2* h2p = (uint2*)h;
#pragma unroll
    for (int r = 0; r < 8; ++r) {
        int idx = r * 256 + tid;
        int ni = idx >> 5, k4 = idx & 31;
        int node = nb + ni;
        union { __half2 h2[2]; uint2 u; } pk;
        if (node < n) {
            uint2 au = a2p[(size_t)node * 32 + k4];
            uint2 hu = h2p[(size_t)node * 32 + k4];
            float2 a01 = __half22float2(*(__half2*)&au.x);
            float2 a23 = __half22float2(*(__half2*)&au.y);
            float2 h01 = __half22float2(*(__half2*)&hu.x);
            float2 h23 = __half22float2(*(__half2*)&hu.y);
            float4 aa = *((const float4*)&As[k4 * 4]);
            float4 cc = *((const float4*)&Cs[k4 * 4]);
            float v0 = fmaxf(a01.x * aa.x + cc.x, 0.f) + h01.x;
            float v1 = fmaxf(a01.y * aa.y + cc.y, 0.f) + h01.y;
            float v2 = fmaxf(a23.x * aa.z + cc.z, 0.f) + h23.x;
            float v3 = fmaxf(a23.y * aa.w + cc.w, 0.f) + h23.y;
            pk.h2[0] = __floats2half2_rn(v0, v1);
            pk.h2[1] = __floats2half2_rn(v2, v3);
            h2p[(size_t)node * 32 + k4] = pk.u;   // in-place: element owned by one thread
        } else {
            pk.h2[0] = __floats2half2_rn(0.f, 0.f);
            pk.h2[1] = __floats2half2_rn(0.f, 0.f);
        }
        *(uint2*)&Ah[ni][k4 * 4] = pk.u;
    }
    const uint4* wt4 = (const uint4*)Wt;
#pragma unroll
    for (int r = 0; r < 8; ++r) {
        int idx = r * 256 + tid;
        int row = idx >> 4, ch = idx & 15;
        *(uint4*)&Bh[row][ch * 8] = wt4[row * 16 + ch];
    }
    __syncthreads();
    int lane = tid & 63, w = tid >> 6;
    int mrow = lane & 15, quad = lane >> 4;
    f32x4 acc[8];
#pragma unroll
    for (int t = 0; t < 8; ++t) acc[t] = (f32x4){0.f, 0.f, 0.f, 0.f};
#pragma unroll
    for (int kc = 0; kc < 4; ++kc) {
        half8 av = *(half8*)&Ah[w * 16 + mrow][kc * 32 + quad * 8];
#pragma unroll
        for (int t = 0; t < 8; ++t) {
            half8 bv = *(half8*)&Bh[t * 16 + mrow][kc * 32 + quad * 8];
            acc[t] = __builtin_amdgcn_mfma_f32_16x16x32_f16(av, bv, acc[t], 0, 0, 0);
        }
    }
    float dv[4];
#pragma unroll
    for (int r = 0; r < 4; ++r) {
        int node = nb + w * 16 + quad * 4 + r;
        dv[r] = (node < n) ? dinv[node] : 0.f;
    }
    __syncthreads();
#pragma unroll
    for (int t = 0; t < 8; ++t)
#pragma unroll
        for (int r = 0; r < 4; ++r)
            Ah[w * 16 + quad * 4 + r][t * 16 + mrow] = (_Float16)(acc[t][r] * dv[r]);
    __syncthreads();
#pragma unroll
    for (int it = 0; it < 4; ++it) {
        int idx = it * 256 + tid;
        int row = idx >> 4, ch = idx & 15;
        int node = nb + row;
        if (node < n)
            ((uint4*)th)[(size_t)node * 16 + ch] = *(uint4*)&Ah[row][ch * 8];
    }
}

// ---------------- MFMA head GEMM: BN-finalize+apply+ReLU+residual -> @Wf1+bf1 + stats --

__global__ __launch_bounds__(256) void k_mmh(const __half2* __restrict__ agg, const __half2* __restrict__ h,
                                             const float* __restrict__ Sin, const float* __restrict__ SSin,
                                             const float* __restrict__ g, const float* __restrict__ bt,
                                             const _Float16* __restrict__ Wt, const float* __restrict__ bias,
                                             float* __restrict__ tf,
                                             float* __restrict__ S, float* __restrict__ SS, int n) {
    __shared__ __attribute__((aligned(16))) _Float16 Ah[64][PADK];
    __shared__ __attribute__((aligned(16))) _Float16 Bh[32][PADK];
    __shared__ float Ds[64][36];
    __shared__ float As[128], Cs[128];
    __shared__ float sredS[4][8][4], sredQ[4][8][4];
    int tid = threadIdx.x;
    int nb = blockIdx.x * 64;
    if (tid < 128) {
        float s = 0.f, q = 0.f;
#pragma unroll
        for (int k = 0; k < NSTRIPE; ++k) { s += Sin[k * 128 + tid]; q += SSin[k * 128 + tid]; }
        float mu = s / (float)n;
        float var = q / (float)n - mu * mu;
        float inv = rsqrtf(var + EPS);
        As[tid] = g[tid] * inv;
        Cs[tid] = bt[tid] - mu * g[tid] * inv;
    }
    __syncthreads();
    const uint2* a2p = (const uint2*)agg;
    const uint2* h2p = (const uint2*)h;
#pragma unroll
    for (int r = 0; r < 8; ++r) {
        int idx = r * 256 + tid;
        int ni = idx >> 5, k4 = idx & 31;
        int node = nb + ni;
        union { __half2 h2[2]; uint2 u; } pk;
        if (node < n) {
            uint2 au = a2p[(size_t)node * 32 + k4];
            uint2 hu = h2p[(size_t)node * 32 + k4];
            float2 a01 = __half22float2(*(__half2*)&au.x);
            float2 a23 = __half22float2(*(__half2*)&au.y);
            float2 h01 = __half22float2(*(__half2*)&hu.x);
            float2 h23 = __half22float2(*(__half2*)&hu.y);
            float4 aa = *((const float4*)&As[k4 * 4]);
            float4 cc = *((const float4*)&Cs[k4 * 4]);
            float v0 = fmaxf(a01.x * aa.x + cc.x, 0.f) + h01.x;
            float v1 = fmaxf(a01.y * aa.y + cc.y, 0.f) + h01.y;
            float v2 = fmaxf(a23.x * aa.z + cc.z, 0.f) + h23.x;
            float v3 = fmaxf(a23.y * aa.w + cc.w, 0.f) + h23.y;
            pk.h2[0] = __floats2half2_rn(v0, v1);
            pk.h2[1] = __floats2half2_rn(v2, v3);
        } else {
            pk.h2[0] = __floats2half2_rn(0.f, 0.f);
            pk.h2[1] = __floats2half2_rn(0.f, 0.f);
        }
        *(uint2*)&Ah[ni][k4 * 4] = pk.u;
    }
    const uint4* wt4 = (const uint4*)Wt;
#pragma unroll
    for (int r = 0; r < 2; ++r) {
        int idx = r * 256 + tid;
        int row = idx >> 4, ch = idx & 15;
        *(uint4*)&Bh[row][ch * 8] = wt4[row * 16 + ch];
    }
    __syncthreads();
    int lane = tid & 63, w = tid >> 6;
    int mrow = lane & 15, quad = lane >> 4;
    f32x4 acc[2];
    acc[0] = (f32x4){0.f, 0.f, 0.f, 0.f};
    acc[1] = (f32x4){0.f, 0.f, 0.f, 0.f};
#pragma unroll
    for (int kc = 0; kc < 4; ++kc) {
        half8 av = *(half8*)&Ah[w * 16 + mrow][kc * 32 + quad * 8];
#pragma unroll
        for (int t = 0; t < 2; ++t) {
            half8 bv = *(half8*)&Bh[t * 16 + mrow][kc * 32 + quad * 8];
            acc[t] = __builtin_amdgcn_mfma_f32_16x16x32_f16(av, bv, acc[t], 0, 0, 0);
        }
    }
#pragma unroll
    for (int t = 0; t < 2; ++t)
#pragma unroll
        for (int r = 0; r < 4; ++r)
            Ds[w * 16 + quad * 4 + r][t * 16 + mrow] = acc[t][r];
    __syncthreads();
    float ps0 = 0.f, ps1 = 0.f, ps2 = 0.f, ps3 = 0.f;
    float pq0 = 0.f, pq1 = 0.f, pq2 = 0.f, pq3 = 0.f;
    int c4 = tid & 7;
    float4 bb = ((const float4*)bias)[c4];
#pragma unroll
    for (int it = 0; it < 2; ++it) {
        int idx = it * 256 + tid;
        int row = idx >> 3;
        int node = nb + row;
        if (node < n) {
            float v0 = Ds[row][c4 * 4 + 0] + bb.x;
            float v1 = Ds[row][c4 * 4 + 1] + bb.y;
            float v2 = Ds[row][c4 * 4 + 2] + bb.z;
            float v3 = Ds[row][c4 * 4 + 3] + bb.w;
            *((float4*)&tf[(size_t)node * 32 + c4 * 4]) = make_float4(v0, v1, v2, v3);
            ps0 += v0; ps1 += v1; ps2 += v2; ps3 += v3;
            pq0 += v0 * v0; pq1 += v1 * v1; pq2 += v2 * v2; pq3 += v3 * v3;
        }
    }
#pragma unroll
    for (int off = 8; off < 64; off <<= 1) {
        ps0 += __shfl_down(ps0, off); ps1 += __shfl_down(ps1, off);
        ps2 += __shfl_down(ps2, off); ps3 += __shfl_down(ps3, off);
        pq0 += __shfl_down(pq0, off); pq1 += __shfl_down(pq1, off);
        pq2 += __shfl_down(pq2, off); pq3 += __shfl_down(pq3, off);
    }
    if (lane < 8) {
        sredS[w][lane][0] = ps0; sredS[w][lane][1] = ps1; sredS[w][lane][2] = ps2; sredS[w][lane][3] = ps3;
        sredQ[w][lane][0] = pq0; sredQ[w][lane][1] = pq1; sredQ[w][lane][2] = pq2; sredQ[w][lane][3] = pq3;
    }
    __syncthreads();
    if (tid < 32) {
        int cc4 = tid >> 2, j = tid & 3;
        float s = sredS[0][cc4][j] + sredS[1][cc4][j] + sredS[2][cc4][j] + sredS[3][cc4][j];
        float q = sredQ[0][cc4][j] + sredQ[1][cc4][j] + sredQ[2][cc4][j] + sredQ[3][cc4][j];
        int stripe = (blockIdx.x & (NSTRIPE - 1)) * 128;
        atomicAdd(&S[stripe + tid], s);
        atomicAdd(&SS[stripe + tid], q);
    }
}

// ---------------- aggregation + fused BN stats (R10 dual-edge, out now fp16) ----------

__global__ __launch_bounds__(256) void k_agg(const __half2* __restrict__ t, const int* __restrict__ offs,
                                             const int* __restrict__ csr, const float* __restrict__ dinv,
                                             const float* __restrict__ bias, __half2* __restrict__ out,
                                             float* __restrict__ S, float* __restrict__ SS, int n) {
    __shared__ float ls[4][128];
    __shared__ float lss[4][128];
    int tid = threadIdx.x;
    int lane = tid & 63, w = tid >> 6;
    int sub = lane >> 5, fl = lane & 31;
    const uint2* t4 = (const uint2*)t;
    float4 bb = ((const float4*)bias)[fl];
    float s0 = 0.f, s1 = 0.f, s2 = 0.f, s3 = 0.f;
    float q0 = 0.f, q1 = 0.f, q2 = 0.f, q3 = 0.f;
    float selfm = (sub == 0) ? 1.f : 0.f;
    int ngrp = (n + 3) >> 2;
    for (int grp = blockIdx.x; grp < ngrp; grp += gridDim.x) {
        int node = grp * 4 + w;
        if (node < n) {
            uint2 rv = t4[(size_t)node * 32 + fl];
            float2 f0 = __half22float2(*(__half2*)&rv.x);
            float2 f1 = __half22float2(*(__half2*)&rv.y);
            float a0 = f0.x * selfm, a1 = f0.y * selfm, a2 = f1.x * selfm, a3 = f1.y * selfm;
            int e0 = offs[node], e1 = offs[node + 1];
            for (int e = e0; e < e1; e += 8) {
                int i0 = e + sub, i1 = e + 2 + sub, i2 = e + 4 + sub, i3 = e + 6 + sub;
                int c0 = csr[min(i0, e1 - 1)];
                int c1 = csr[min(i1, e1 - 1)];
                int c2 = csr[min(i2, e1 - 1)];
                int c3 = csr[min(i3, e1 - 1)];
                uint2 r0 = t4[(size_t)c0 * 32 + fl];
                uint2 r1 = t4[(size_t)c1 * 32 + fl];
                uint2 r2 = t4[(size_t)c2 * 32 + fl];
                uint2 r3 = t4[(size_t)c3 * 32 + fl];
                float m0 = (i0 < e1) ? 1.f : 0.f;
                float m1 = (i1 < e1) ? 1.f : 0.f;
                float m2 = (i2 < e1) ? 1.f : 0.f;
                float m3 = (i3 < e1) ? 1.f : 0.f;
                float2 g0 = __half22float2(*(__half2*)&r0.x), g1 = __half22float2(*(__half2*)&r0.y);
                a0 += m0 * g0.x; a1 += m0 * g0.y; a2 += m0 * g1.x; a3 += m0 * g1.y;
                g0 = __half22float2(*(__half2*)&r1.x); g1 = __half22float2(*(__half2*)&r1.y);
                a0 += m1 * g0.x; a1 += m1 * g0.y; a2 += m1 * g1.x; a3 += m1 * g1.y;
                g0 = __half22float2(*(__half2*)&r2.x); g1 = __half22float2(*(__half2*)&r2.y);
                a0 += m2 * g0.x; a1 += m2 * g0.y; a2 += m2 * g1.x; a3 += m2 * g1.y;
                g0 = __half22float2(*(__half2*)&r3.x); g1 = __half22float2(*(__half2*)&r3.y);
                a0 += m3 * g0.x; a1 += m3 * g0.y; a2 += m3 * g1.x; a3 += m3 * g1.y;
            }
            a0 += __shfl_down(a0, 32);
            a1 += __shfl_down(a1, 32);
            a2 += __shfl_down(a2, 32);
            a3 += __shfl_down(a3, 32);
            if (sub == 0) {
                float di = dinv[node];
                float v0 = a0 * di + bb.x, v1 = a1 * di + bb.y;
                float v2 = a2 * di + bb.z, v3 = a3 * di + bb.w;
                union { __half2 h2[2]; uint2 u; } pk;
                pk.h2[0] = __floats2half2_rn(v0, v1);
                pk.h2[1] = __floats2half2_rn(v2, v3);
                ((uint2*)out)[(size_t)node * 32 + fl] = pk.u;
                s0 += v0; s1 += v1; s2 += v2; s3 += v3;
                q0 += v0 * v0; q1 += v1 * v1; q2 += v2 * v2; q3 += v3 * v3;
            }
        }
    }
    if (sub == 0) {
        ((float4*)&ls[w][0])[fl] = make_float4(s0, s1, s2, s3);
        ((float4*)&lss[w][0])[fl] = make_float4(q0, q1, q2, q3);
    }
    __syncthreads();
    if (tid < 128) {
        float s = ls[0][tid] + ls[1][tid] + ls[2][tid] + ls[3][tid];
        float q = lss[0][tid] + lss[1][tid] + lss[2][tid] + lss[3][tid];
        int stripe = (blockIdx.x & (NSTRIPE - 1)) * 128;
        atomicAdd(&S[stripe + tid], s);
        atomicAdd(&SS[stripe + tid], q);
    }
}

// ---------------- final: out = tanh(relu(bn(tf)) @ Wf2 + bf2), BN-finalize fused -------

__global__ __launch_bounds__(256) void k_final(const float* __restrict__ tf,
                                               const float* __restrict__ S, const float* __restrict__ SS,
                                               const float* __restrict__ gf, const float* __restrict__ btf,
                                               const float* __restrict__ Wf2, const float* __restrict__ bf2,
                                               float* __restrict__ out, int n) {
    __shared__ float Af[32], Cf[32];
    int tid = threadIdx.x;
    if (tid < 32) {
        float s = 0.f, q = 0.f;
#pragma unroll
        for (int k = 0; k < NSTRIPE; ++k) { s += S[k * 128 + tid]; q += SS[k * 128 + tid]; }
        float mu = s / (float)n;
        float var = q / (float)n - mu * mu;
        float inv = rsqrtf(var + EPS);
        Af[tid] = gf[tid] * inv;
        Cf[tid] = btf[tid] - mu * gf[tid] * inv;
    }
    __syncthreads();
    int node = blockIdx.x * 256 + tid;
    if (node >= n) return;
    float o0 = bf2[0], o1 = bf2[1];
    const float4* t4 = (const float4*)(tf + (size_t)node * 32);
#pragma unroll
    for (int q = 0; q < 8; ++q) {
        float4 v = t4[q];
        float vv[4] = {v.x, v.y, v.z, v.w};
#pragma unroll
        for (int r = 0; r < 4; ++r) {
            int j = q * 4 + r;
            float f = fmaxf(vv[r] * Af[j] + Cf[j], 0.f);
            o0 += f * Wf2[2 * j];
            o1 += f * Wf2[2 * j + 1];
        }
    }
    out[2 * node] = tanhf(o0);
    out[2 * node + 1] = tanhf(o1);
}

// ---------------- launch ----------------

extern "C" void kernel_launch(void* const* d_in, const int* in_sizes, int n_in,
                              void* d_out, int out_size, void* d_ws, size_t ws_size,
                              hipStream_t stream) {
    const float* x   = (const float*)d_in[0];
    const int*   ei  = (const int*)d_in[1];
    const float* We  = (const float*)d_in[2];
    const float* be  = (const float*)d_in[3];
    const float* W1  = (const float*)d_in[4];
    const float* b1  = (const float*)d_in[5];
    const float* g1  = (const float*)d_in[6];
    const float* bt1 = (const float*)d_in[7];
    const float* W2  = (const float*)d_in[8];
    const float* b2  = (const float*)d_in[9];
    const float* g2  = (const float*)d_in[10];
    const float* bt2 = (const float*)d_in[11];
    const float* W3  = (const float*)d_in[12];
    const float* b3  = (const float*)d_in[13];
    const float* g3  = (const float*)d_in[14];
    const float* bt3 = (const float*)d_in[15];
    const float* Wf1 = (const float*)d_in[16];
    const float* bf1 = (const float*)d_in[17];
    const float* gf  = (const float*)d_in[18];
    const float* btf = (const float*)d_in[19];
    const float* Wf2 = (const float*)d_in[20];
    const float* bf2 = (const float*)d_in[21];
    float* out = (float*)d_out;

    const int n = in_sizes[0] / 2;      // x is [N,2]
    const int e = in_sizes[1] / 2;      // edge_index is [2,E]
    const int* srcp = ei;
    const int* dstp = ei + e;
    const int nbk = (n + BK - 1) / BK;

    char* p = (char*)d_ws;
    auto alloc = [&](size_t bytes) { void* r = (void*)p; p += (bytes + 255) & ~(size_t)255; return r; };
    int*       bcount = (int*)alloc((size_t)nbk * 16 * 4);
    int*       boffs  = (int*)alloc((size_t)(nbk + 1) * 4);
    int*       bcur   = (int*)alloc((size_t)nbk * 16 * 4);
    int*       btmp   = (int*)alloc((size_t)e * 4);
    int*       csr    = (int*)alloc((size_t)e * 4);
    int*       offs   = (int*)alloc((size_t)(n + 1) * 4);
    float*     dinv   = (float*)alloc((size_t)n * 4);
    __half2*   h      = (__half2*)alloc((size_t)n * HID * 2);
    __half2*   th     = (__half2*)alloc((size_t)n * HID * 2);
    __half2*   agg    = (__half2*)alloc((size_t)n * HID * 2);
    float*     tf     = (float*)alloc((size_t)n * 32 * 4);
    float*     bnAll  = (float*)alloc(8 * NSTRIPE * 128 * 4);   // S0..S2,SH | SS0..SS2,SSH
    _Float16*  wt1    = (_Float16*)alloc(128 * 128 * 2);
    _Float16*  wt2    = (_Float16*)alloc(128 * 128 * 2);
    _Float16*  wt3    = (_Float16*)alloc(128 * 128 * 2);
    _Float16*  wtf    = (_Float16*)alloc(32 * 128 * 2);

    float* S0 = bnAll;             float* SS0 = bnAll + 4 * NSTRIPE * 128;
    float* S1 = S0 + NSTRIPE*128;  float* SS1 = SS0 + NSTRIPE*128;
    float* S2 = S1 + NSTRIPE*128;  float* SS2 = SS1 + NSTRIPE*128;
    float* SH = S2 + NSTRIPE*128;  float* SSH = SS2 + NSTRIPE*128;

    hipMemsetAsync(bcount, 0, (size_t)nbk * 16 * 4, stream);
    hipMemsetAsync(bnAll, 0, 8 * NSTRIPE * 128 * 4, stream);
    k_bhist<<<(e + 4095) / 4096, 256, 0, stream>>>(dstp, bcount, e, nbk);
    k_bscan<<<1, 1024, 0, stream>>>(bcount, boffs, bcur, nbk, e);
    k_bscatter<<<256, 1024, 0, stream>>>(srcp, dstp, bcur, btmp, e, nbk);
    k_bsort<<<nbk, 256, 0, stream>>>(btmp, boffs, csr, offs, dinv, n, e);
    k_prepw<<<64, 256, 0, stream>>>(W1, wt1);
    k_prepw<<<64, 256, 0, stream>>>(W2, wt2);
    k_prepw<<<64, 256, 0, stream>>>(W3, wt3);
    k_prepwf<<<16, 256, 0, stream>>>(Wf1, wtf);

    // layer 1 (embed fused into GEMM staging; h written fp16)
    k_mm1<<<(n + 63) / 64, 256, 0, stream>>>(x, We, be, wt1, dinv, th, h, n);
    k_agg<<<4096, 256, 0, stream>>>(th, offs, csr, dinv, b1, agg, S0, SS0, n);

    // layer 2 (BN1 finalize+apply+relu+residual fused into GEMM)
    k_mmf<<<(n + 63) / 64, 256, 0, stream>>>(agg, h, S0, SS0, g1, bt1, wt2, dinv, th, n);
    k_agg<<<4096, 256, 0, stream>>>(th, offs, csr, dinv, b2, agg, S1, SS1, n);

    // layer 3
    k_mmf<<<(n + 63) / 64, 256, 0, stream>>>(agg, h, S1, SS1, g2, bt2, wt3, dinv, th, n);
    k_agg<<<4096, 256, 0, stream>>>(th, offs, csr, dinv, b3, agg, S2, SS2, n);

    // head (BN3 finalize+apply+relu+residual + GEMM + head-BN stats)
    k_mmh<<<(n + 63) / 64, 256, 0, stream>>>(agg, h, S2, SS2, g3, bt3, wtf, bf1, tf, SH, SSH, n);

    // final (head-BN finalize fused)
    k_final<<<(n + 255) / 256, 256, 0, stream>>>(tf, SH, SSH, gf, btf, Wf2, bf2, out, n);
}